// Round 18
// baseline (479.008 us; speedup 1.0000x reference)
//
#include <hip/hip_runtime.h>
#include <hip/hip_bf16.h>
#include <math.h>

// Problem constants (fixed by the reference)
#define NB   64     // batch
#define CIN  64     // input channels
#define DIMD 128    // q/k/e channels
#define TT   120    // time
#define VV   25     // joints
#define HH   8      // heads
#define DHD  16     // DIM/H
#define WW   3      // temporal window
#define UU   75     // W*V
#define TC2  12     // t-chunk in MFMA attention kernel (120 = 10*12)
#define TCO  4      // t-chunk in output kernel (120 = 4*30)

typedef __hip_bfloat16 bf16;
typedef float        f32x4  __attribute__((ext_vector_type(4)));
typedef unsigned int u32x4  __attribute__((ext_vector_type(4)));
typedef unsigned int u32x2  __attribute__((ext_vector_type(2)));
typedef __bf16       bf16x8 __attribute__((ext_vector_type(8)));

__device__ __forceinline__ float b2f(bf16 v)  { return __bfloat162float(v); }
__device__ __forceinline__ bf16  f2b(float v) { return __float2bfloat16(v); }

__device__ __forceinline__ unsigned short f2bu(float f) {
  unsigned u = __builtin_bit_cast(unsigned, f);
  return (unsigned short)((u + 0x7fffu + ((u >> 16) & 1u)) >> 16);  // RNE
}
__device__ __forceinline__ float bfu(unsigned short s) {
  unsigned u = ((unsigned)s) << 16;
  return __builtin_bit_cast(float, u);
}
__device__ __forceinline__ unsigned pack2(float a, float b) {
  return ((unsigned)f2bu(b) << 16) | (unsigned)f2bu(a);
}

// BUILTIN MFMA (R11 lesson: asm-wrapped MFMA is invisible to the GCN hazard
// recognizer -> missing MFMA->VALU wait-states -> silent corruption).
__device__ __forceinline__ f32x4 mfma_bf16(u32x4 a, u32x4 b, f32x4 d) {
  return __builtin_amdgcn_mfma_f32_16x16x32_bf16(
      __builtin_bit_cast(bf16x8, a), __builtin_bit_cast(bf16x8, b), d, 0, 0, 0);
}

// ---------------------------------------------------------------------------
// Pre-pack kernel (R17-verbatim): weights -> fragment-ordered bf16 tensors.
// ---------------------------------------------------------------------------
__global__ __launch_bounds__(256) void k_pack_w(
    const float* __restrict__ Wo, const float* __restrict__ g_o,
    const float* __restrict__ v_o,
    const float* __restrict__ Wd, const float* __restrict__ g_d,
    const float* __restrict__ v_d,
    const float* __restrict__ Wq, const float* __restrict__ Wk,
    const float* __restrict__ We, const float* __restrict__ beta,
    unsigned short* __restrict__ woF, unsigned short* __restrict__ wdF,
    unsigned short* __restrict__ wqF, unsigned short* __restrict__ wkF,
    unsigned short* __restrict__ weF)
{
  const int i = blockIdx.x * 256 + threadIdx.x;   // grid covers 98304
  if (i < 65536) {                                 // woF
    const int j = i & 7, d = (i >> 3) & 127, kg = (i >> 10) & 3;
    const int ks = (i >> 12) & 1, h = (i >> 13) & 7;
    const float sc = g_o[d] * rsqrtf(v_o[d] + 1e-5f);
    woF[i] = f2bu(sc * Wo[d * 512 + h * 64 + ks * 32 + kg * 8 + j]);
  } else {
    const int r = i - 65536;                       // 0..32767
    const int which = r >> 13;                     // 0=wd 1=wq 2=wk 3=we
    const int l = r & 8191;
    const int j = l & 7, d = (l >> 3) & 127, kg = (l >> 10) & 3;
    const int ks = (l >> 12) & 1;
    const int c = ks * 32 + kg * 8 + j;
    if (which == 0) {
      const float sc = g_d[d] * rsqrtf(v_d[d] + 1e-5f);
      wdF[l] = f2bu(sc * Wd[d * 64 + c]);
    } else if (which == 1) {
      wqF[l] = f2bu(Wq[d * 64 + c]);
    } else if (which == 2) {
      wkF[l] = f2bu(Wk[d * 64 + c]);
    } else {
      weF[l] = f2bu(beta[0] * We[d * 64 + c]);
    }
  }
}

// ---------------------------------------------------------------------------
// Fused A+B v8: phase1 register-hop-select; phase1b MFMA (yC tile + GlT).
//   region A: xf (bf16 x) -> yTG after phase1
//   yC[t][c][u] bf16 pitch 32, XOR-swz by (c&7)<<4 (write+read both swz)
// ---------------------------------------------------------------------------
__global__ __launch_bounds__(256, 3) void k_qke_mfma8(
    const float* __restrict__ x,
    const unsigned short* __restrict__ wqF, const float* __restrict__ bq,
    const unsigned short* __restrict__ wkF, const float* __restrict__ bk,
    const unsigned short* __restrict__ weF, const float* __restrict__ be,
    const float* __restrict__ G,  const float* __restrict__ beta,
    const float* __restrict__ se_pe, const int* __restrict__ dis,
    bf16* __restrict__ qy, bf16* __restrict__ kkp)
{
  const int n = blockIdx.x / 30, t0 = (blockIdx.x % 30) * 4;
  __shared__ alignas(16) char uA[14336];                 // xf | yTG
  __shared__ alignas(16) unsigned short yC[4][64][32];   // 16,384  [t][c][u] swz
  __shared__ alignas(16) unsigned short yT[112][64];     // 14,336  [tv][c] swz
  __shared__ alignas(16) unsigned short GlT[32][32];     //  2,048  [v][u] swz
  __shared__ alignas(16) float spl[5][64];               //  1,280
  __shared__ alignas(16) int   dml[25][25];              //  2,500
  __shared__ alignas(16) float gsum[32];                 //    128
  __shared__ alignas(16) float biasb[384];               //  1,536  bq|bk|be

  unsigned short* xf = (unsigned short*)uA;              // [(t*64+c)*26+v]
  char* yTG = uA;                                        // [112] x 128B swz

  const int tid = threadIdx.x;
  // ---- phase 0: stage ----
  {
    const float* xb = x + (size_t)n * 192000 + t0 * 25;  // x[n][c][t0+t][v]
    for (int i = tid; i < 6400; i += 256) {
      const int c = i / 100, j = i % 100, t = j / 25, v = j % 25;
      xf[(t * 64 + c) * 26 + v] = f2bu(xb[c * 3000 + j]);
    }
  }
  for (int i = tid; i < 320; i += 256) spl[i / 64][i % 64] = se_pe[i];
  for (int i = tid; i < 625; i += 256) dml[i / 25][i % 25] = dis[i];
  for (int i = tid; i < 1024; i += 256) {                // GlT[v][u]=G[u][v], swz
    const int v = i >> 5, u = i & 31;
    const float g = (v < 25 && u < 25) ? G[u * 25 + v] : 0.f;
    *(unsigned short*)((char*)GlT + v * 64 + ((u * 2) ^ ((v & 7) << 4))) =
        f2bu(g);
  }
  if (tid < 25) {
    float s = 0.f;
    for (int u = 0; u < 25; ++u) s += G[u * 25 + tid];
    gsum[tid] = s;
  }
  for (int i = tid; i < 384; i += 256)
    biasb[i] = (i < 128) ? bq[i] : (i < 256 ? bk[i - 128] : be[i - 256]);
  for (int i = tid; i < 12 * 64; i += 256)               // yT junk rows -> 0
    yT[100 + (i >> 6)][i & 63] = 0;
  __syncthreads();

  const int lane = tid & 63, wid = tid >> 6;
  const int m16 = lane & 15, kg = lane >> 4;

  #define LOAD_PFRAGS(af, Fsrc)                                                \
    _Pragma("unroll")                                                          \
    for (int mt = 0; mt < 2; ++mt) {                                           \
      const int d_ = wid * 32 + mt * 16 + m16;                                 \
      _Pragma("unroll")                                                        \
      for (int ks = 0; ks < 2; ++ks)                                           \
        af[mt][ks] = *(const u32x4*)((Fsrc) +                                  \
                      (((ks * 4 + kg) * 128 + d_) << 3));                      \
    }

  // ---- phase 1 (register-hop-select): y = x + pe + struct-enc ----
  float acc1[25];
  {
    const int c = tid & 63, t = tid >> 6;
    const float s0 = spl[0][c], s1 = spl[1][c], s2 = spl[2][c],
                s3 = spl[3][c], s4 = spl[4][c];
    const float dv = expf(-(float)(c & ~1) * (logf(10000.0f) / 64.0f));
    #pragma unroll
    for (int v = 0; v < 25; ++v)
      acc1[v] = bfu(xf[(t * 64 + c) * 26 + v]) +
                ((c & 1) ? cosf((float)v * dv) : sinf((float)v * dv));
    for (int u = 0; u < 25; ++u) {
      const float xu = bfu(xf[(t * 64 + c) * 26 + u]);
      #pragma unroll
      for (int v = 0; v < 25; ++v) {
        const int m = dml[u][v];       // wave-uniform -> LDS broadcast
        const float s = m == 0 ? s0 : m == 1 ? s1 : m == 2 ? s2
                      : m == 3 ? s3 : s4;
        acc1[v] = fmaf(xu, s, acc1[v]);
      }
    }
    // write yT (swz) — xf still live for other threads? No: each thread read
    // only its own (c,t) rows, all reads done above; yT is a separate buffer.
    #pragma unroll
    for (int v = 0; v < 25; ++v) {
      const int tv = t * 25 + v;
      *(unsigned short*)((char*)yT + tv * 128 + ((c * 2) ^ ((tv & 7) << 4))) =
          f2bu(acc1[v]);
    }
  }
  __syncthreads();   // xf DEAD (region A becomes yTG); acc1 in registers

  // ---- phase 1c: dump registers -> yC (swz); zero pads + yTG junk ----
  {
    const int c = tid & 63, t = tid >> 6;
    char* rowp = (char*)&yC[t][c][0];
    #pragma unroll
    for (int v = 0; v < 25; ++v)
      *(unsigned short*)(rowp + ((v * 2) ^ ((c & 7) << 4))) = f2bu(acc1[v]);
    #pragma unroll
    for (int v = 25; v < 32; ++v)
      *(unsigned short*)(rowp + ((v * 2) ^ ((c & 7) << 4))) = 0;
  }
  for (int i = tid; i < 12 * 64; i += 256)
    *(unsigned short*)(yTG + (100 + (i >> 6)) * 128 + ((i & 63) * 2)) = 0;
  __syncthreads();   // yC ready

  // ---- phase 1b (MFMA): yTG = y @ G  (wave wid handles t = wid) ----
  {
    const int t = wid;
    u32x4 bg[2];
    #pragma unroll
    for (int ntv = 0; ntv < 2; ++ntv) {
      const int v = ntv * 16 + m16;
      bg[ntv] = *(const u32x4*)((const char*)GlT + v * 64 +
                                ((kg * 16) ^ ((v & 7) << 4)));
    }
    #pragma unroll
    for (int mtile = 0; mtile < 4; ++mtile) {
      const int cr = mtile * 16 + m16;
      const u32x4 a = *(const u32x4*)((const char*)&yC[t][cr][0] +
                                      ((kg * 16) ^ ((cr & 7) << 4)));
      #pragma unroll
      for (int ntv = 0; ntv < 2; ++ntv) {
        f32x4 d = (f32x4)0.f;
        d = mfma_bf16(a, bg[ntv], d);
        const int v = ntv * 16 + m16;
        if (v < 25) {
          const int tv = t * 25 + v;
          #pragma unroll
          for (int i = 0; i < 4; ++i) {
            const int cc = mtile * 16 + kg * 4 + i;
            *(unsigned short*)(yTG + tv * 128 + ((cc * 2) ^ ((tv & 7) << 4))) =
                f2bu(d[i]);
          }
        }
      }
    }
  }
  __syncthreads();   // yTG ready — LAST barrier; GEMMs are straight-line

  bf16* qyb = qy  + (size_t)n * 384000 + t0 * 25;
  bf16* kkb = kkp + (size_t)n * 384000 + t0 * 25;
  const float betav = beta[0];

  // ---- q-GEMM ----
  {
    u32x4 aq[2][2];
    LOAD_PFRAGS(aq, wqF);
    for (int nt = 0; nt < 7; ++nt) {
      const int tv = nt * 16 + m16;
      const u32x4 b0 = *(const u32x4*)((const char*)yT + tv * 128 +
                        (((kg * 8) * 2) ^ ((tv & 7) << 4)));
      const u32x4 b1 = *(const u32x4*)((const char*)yT + tv * 128 +
                        (((32 + kg * 8) * 2) ^ ((tv & 7) << 4)));
      #pragma unroll
      for (int mt = 0; mt < 2; ++mt) {
        f32x4 acc = (f32x4)0.f;
        acc = mfma_bf16(aq[mt][0], b0, acc);
        acc = mfma_bf16(aq[mt][1], b1, acc);
        if (tv < 100) {
          const int dr = wid * 32 + mt * 16 + kg * 4;
          #pragma unroll
          for (int i2 = 0; i2 < 4; ++i2)
            qyb[(size_t)(dr + i2) * 3000 + tv] = f2b(acc[i2] + biasb[dr + i2]);
        }
      }
    }
  }

  // ---- k-GEMM into persistent kacc ----
  f32x4 kacc[2][7];
  #pragma unroll
  for (int mt = 0; mt < 2; ++mt)
    #pragma unroll
    for (int nt = 0; nt < 7; ++nt) kacc[mt][nt] = (f32x4)0.f;
  {
    u32x4 ak[2][2];
    LOAD_PFRAGS(ak, wkF);
    for (int nt = 0; nt < 7; ++nt) {
      const int tv = nt * 16 + m16;
      const u32x4 b0 = *(const u32x4*)((const char*)yT + tv * 128 +
                        (((kg * 8) * 2) ^ ((tv & 7) << 4)));
      const u32x4 b1 = *(const u32x4*)((const char*)yT + tv * 128 +
                        (((32 + kg * 8) * 2) ^ ((tv & 7) << 4)));
      #pragma unroll
      for (int mt = 0; mt < 2; ++mt) {
        kacc[mt][nt] = mfma_bf16(ak[mt][0], b0, kacc[mt][nt]);
        kacc[mt][nt] = mfma_bf16(ak[mt][1], b1, kacc[mt][nt]);
      }
    }
  }

  // ---- e-GEMM (beta pre-folded in weF) on yTG, accumulate, store kk ----
  {
    u32x4 ae[2][2];
    LOAD_PFRAGS(ae, weF);
    for (int nt = 0; nt < 7; ++nt) {
      const int tv = nt * 16 + m16;
      const u32x4 b0 = *(const u32x4*)(yTG + tv * 128 +
                        (((kg * 8) * 2) ^ ((tv & 7) << 4)));
      const u32x4 b1 = *(const u32x4*)(yTG + tv * 128 +
                        (((32 + kg * 8) * 2) ^ ((tv & 7) << 4)));
      #pragma unroll
      for (int mt = 0; mt < 2; ++mt) {
        kacc[mt][nt] = mfma_bf16(ae[mt][0], b0, kacc[mt][nt]);
        kacc[mt][nt] = mfma_bf16(ae[mt][1], b1, kacc[mt][nt]);
        if (tv < 100) {
          const int vv = tv % 25;
          const int dr = wid * 32 + mt * 16 + kg * 4;
          #pragma unroll
          for (int i2 = 0; i2 < 4; ++i2)
            kkb[(size_t)(dr + i2) * 3000 + tv] =
                f2b(kacc[mt][nt][i2] + biasb[128 + dr + i2] +
                    betav * biasb[256 + dr + i2] * gsum[vv]);
        }
      }
    }
  }
  #undef LOAD_PFRAGS
}

// ---------------------------------------------------------------------------
// Kernel C v2 (R17-verbatim, passing): MFMA attention -> padded attP
// ---------------------------------------------------------------------------
__global__ __launch_bounds__(256) void k_att_mfma(
    const bf16* __restrict__ qy, const bf16* __restrict__ kkp,
    const float* __restrict__ bq, const float* __restrict__ disg,
    const float* __restrict__ att0, const float* __restrict__ alpha,
    unsigned short* __restrict__ attP)
{
  const int n = blockIdx.x / HH, h = blockIdx.x % HH;
  __shared__ alignas(16) unsigned short qsA[80][200];  // [u][k] bf16 bits
  __shared__ alignas(16) unsigned short ksB[32][200];  // [v][k] bf16 bits
  __shared__ alignas(16) float att_s[80][28];
  __shared__ float mxv[32], smv[32];
  const int tid = threadIdx.x;
  const int lane = tid & 63, wid = tid >> 6;
  const int m16 = lane & 15, kg = lane >> 4;

  const unsigned short* qyb =
      (const unsigned short*)(qy + ((size_t)(n * DIMD + h * DHD)) * TT * VV);
  const unsigned short* kkb =
      (const unsigned short*)(kkp + ((size_t)(n * DIMD + h * DHD)) * TT * VV);

  f32x4 acc[3];
  #pragma unroll
  for (int s = 0; s < 3; ++s) acc[s] = (f32x4)0.f;

  for (int c = 0; c < 10; ++c) {
    const int t0 = c * TC2;
    __syncthreads();   // prev chunk's frag reads drained
    for (int it = tid; it < 416; it += 256) {
      if (it < 224) {
        const int dh = it / 14, j = it % 14, tq = t0 + j - 1;
        unsigned short vals[25];
        if (tq >= 0 && tq < TT) {
          const unsigned short* src = qyb + ((size_t)dh * TT + tq) * VV;
          #pragma unroll
          for (int u = 0; u < 25; ++u) vals[u] = src[u];
        } else {
          const unsigned short bqv = f2bu(bq[h * DHD + dh]);
          #pragma unroll
          for (int u = 0; u < 25; ++u) vals[u] = bqv;
        }
        #pragma unroll
        for (int w = 0; w < 3; ++w) {
          const int tt = tq - t0 - w + 1;
          if (tt >= 0 && tt < TC2) {
            const int col = tt * 16 + dh;
            #pragma unroll
            for (int u = 0; u < 25; ++u) qsA[w * 25 + u][col] = vals[u];
          }
        }
      } else {
        const int r = it - 224, dh = r / TC2, tt = r % TC2;
        const unsigned short* src = kkb + ((size_t)dh * TT + t0 + tt) * VV;
        const int col = tt * 16 + dh;
        #pragma unroll
        for (int v = 0; v < 25; ++v) ksB[v][col] = src[v];
      }
    }
    __syncthreads();   // tiles ready
    #pragma unroll
    for (int s = 0; s < 3; ++s) {
      const int tidx = wid + 4 * s;
      if (tidx < 10) {
        const int mtile = tidx >> 1, ntile = tidx & 1;
        #pragma unroll
        for (int ks = 0; ks < 6; ++ks) {
          const u32x4 a = *(const u32x4*)&qsA[mtile * 16 + m16][ks * 32 + kg * 8];
          const u32x4 b = *(const u32x4*)&ksB[ntile * 16 + m16][ks * 32 + kg * 8];
          acc[s] = mfma_bf16(a, b, acc[s]);
        }
      }
    }
  }
  __syncthreads();
  #pragma unroll
  for (int s = 0; s < 3; ++s) {
    const int tidx = wid + 4 * s;
    if (tidx < 10) {
      const int mtile = tidx >> 1, ntile = tidx & 1;
      const int v = ntile * 16 + m16;
      if (v < VV) {
        #pragma unroll
        for (int i = 0; i < 4; ++i)
          att_s[mtile * 16 + kg * 4 + i][v] = acc[s][i];
      }
    }
  }
  __syncthreads();
  const float inv = 1.0f / (float)(DHD * TT);
  for (int i = tid; i < UU * VV; i += 256) {
    const int u = i / VV, v = i % VV;
    const bool m = disg[(h * VV + u % VV) * VV + v] > 0.f;
    att_s[u][v] = m ? att_s[u][v] * inv : -9e15f;
  }
  __syncthreads();
  if (tid < VV) {
    float mx = -INFINITY;
    for (int u = 0; u < UU; ++u) mx = fmaxf(mx, att_s[u][tid]);
    float sm = 0.f;
    for (int u = 0; u < UU; ++u) sm += expf(att_s[u][tid] - mx);
    mxv[tid] = mx; smv[tid] = sm;
  }
  __syncthreads();
  const float al = alpha[0];
  unsigned* dst = (unsigned*)(attP + ((size_t)(n * HH + h) * 32) * 104);
  for (int i = tid; i < 1664; i += 256) {     // 32 x 52 u32 (= 104 u16)
    const int vc = i / 52, u0 = (i % 52) * 2;
    unsigned val = 0u;
    if (vc < VV) {
      float f0 = 0.f, f1 = 0.f;
      if (u0 < UU)
        f0 = expf(att_s[u0][vc] - mxv[vc]) / smv[vc] * al
             + att0[(h * VV + u0 % VV) * VV + vc];
      if (u0 + 1 < UU)
        f1 = expf(att_s[u0 + 1][vc] - mxv[vc]) / smv[vc] * al
             + att0[(h * VV + (u0 + 1) % VV) * VV + vc];
      val = pack2(f0, f1);
    }
    dst[i] = val;
  }
}

// ---------------------------------------------------------------------------
// Kernel D v6 (R17-verbatim, passing)
// ---------------------------------------------------------------------------
__global__ __launch_bounds__(256) void k_out_mfma6(
    const float* __restrict__ x, const unsigned short* __restrict__ attP,
    const unsigned short* __restrict__ woF, const unsigned short* __restrict__ wdF,
    const float* __restrict__ b_o,
    const float* __restrict__ g_o, const float* __restrict__ be_o,
    const float* __restrict__ m_o, const float* __restrict__ v_o,
    const float* __restrict__ b_d,
    const float* __restrict__ g_d, const float* __restrict__ be_d,
    const float* __restrict__ m_d, const float* __restrict__ v_d,
    float* __restrict__ out)
{
  const int n = blockIdx.x / 30, t0 = (blockIdx.x % 30) * TCO;
  __shared__ alignas(16) char uB[28672];                   // xu2 | xsl2[2]
  __shared__ alignas(16) unsigned short attB[2][32][104];  // 13,312 B dbuf
  unsigned short* xu2 = (unsigned short*)uB;               // [(tr*64+c)*104+u]
  const int tid = threadIdx.x;
  const int lane = tid & 63, wid = tid >> 6;
  const int m16 = lane & 15, kg = lane >> 4;

  #define XSLB(b) (uB + (b) * 14336)            // [112] rows x 128B swz

  #define STAGE_XU(tb)                                                         \
    for (int i = tid; i < 2 * 64 * 48; i += 256) {                             \
      const int u0 = (i % 48) * 2, c = (i / 48) & 63, tr = i / (48 * 64);      \
      float f0 = 0.f, f1 = 0.f;                                                \
      if (u0 < UU) {                                                           \
        const int w = u0 / VV, up = u0 % VV, ts = t0 + (tb) + tr + w - 1;      \
        if (ts >= 0 && ts < TT) f0 = x[((n * 64 + c) * TT + ts) * VV + up];    \
      }                                                                        \
      if (u0 + 1 < UU) {                                                       \
        const int u = u0 + 1, w = u / VV, up = u % VV;                         \
        const int ts = t0 + (tb) + tr + w - 1;                                 \
        if (ts >= 0 && ts < TT) f1 = x[((n * 64 + c) * TT + ts) * VV + up];    \
      }                                                                        \
      *(unsigned*)(xu2 + (tr * 64 + c) * 104 + u0) = pack2(f0, f1);            \
    }

  #define STAGE_ATT(hh, buf)                                                   \
    {                                                                          \
      const u32x4* srcv =                                                      \
          (const u32x4*)(attP + ((size_t)(n * HH + (hh)) * 32) * 104);         \
      u32x4* dstv = (u32x4*)&attB[buf][0][0];                                  \
      for (int i = tid; i < 416; i += 256) dstv[i] = srcv[i];                  \
    }

  // ---- prologue: A-frags from xu2 in two 2-t chunks ----
  STAGE_XU(0);
  __syncthreads();
  u32x4 af[4][3];
  if (wid < 2) {
    #pragma unroll
    for (int mt = 0; mt < 4; ++mt)
      #pragma unroll
      for (int ks = 0; ks < 3; ++ks)
        af[mt][ks] = *(const u32x4*)(xu2 + (wid * 64 + mt * 16 + m16) * 104 +
                                     ks * 32 + kg * 8);
  }
  __syncthreads();   // chunk-1 reads drained before overwrite
  STAGE_XU(2);
  STAGE_ATT(0, 0);
  __syncthreads();
  if (wid >= 2) {
    #pragma unroll
    for (int mt = 0; mt < 4; ++mt)
      #pragma unroll
      for (int ks = 0; ks < 3; ++ks)
        af[mt][ks] = *(const u32x4*)(xu2 + ((wid - 2) * 64 + mt * 16 + m16) * 104 +
                                     ks * 32 + kg * 8);
  }
  __syncthreads();   // FENCE: all xu2 reads drained; uB becomes xsl2
  for (int i = tid; i < 2 * 12 * 64; i += 256) {
    const int b = i / (12 * 64), r = i % (12 * 64);
    *(unsigned short*)(XSLB(b) + (100 + (r >> 6)) * 128 + ((r & 63) * 2)) = 0;
  }

  f32x4 acc2[2][7];
  #pragma unroll
  for (int mt = 0; mt < 2; ++mt)
    #pragma unroll
    for (int nt = 0; nt < 7; ++nt) acc2[mt][nt] = (f32x4)0.f;

  for (int h = 0; h <= HH; ++h) {
    const int pb = h & 1;
    char* xs = XSLB(pb);
    u32x4 a2[2][2];
    #pragma unroll
    for (int mt = 0; mt < 2; ++mt) {
      const int d = wid * 32 + mt * 16 + m16;
      #pragma unroll
      for (int ks = 0; ks < 2; ++ks) {
        const unsigned short* src = (h < HH)
            ? (woF + ((((h * 2 + ks) * 4 + kg) * 128 + d) << 3))
            : (wdF + ((((ks) * 4 + kg) * 128 + d) << 3));
        a2[mt][ks] = *(const u32x4*)src;
      }
    }
    if (h + 1 < HH) { STAGE_ATT(h + 1, (h + 1) & 1); }
    f32x4 a1[4][2];
    if (h < HH) {
      u32x4 bfr[2][3];
      #pragma unroll
      for (int nt = 0; nt < 2; ++nt)
        #pragma unroll
        for (int ks = 0; ks < 3; ++ks)
          bfr[nt][ks] =
              *(const u32x4*)&attB[pb][nt * 16 + m16][ks * 32 + kg * 8];
      #pragma unroll
      for (int mt = 0; mt < 4; ++mt)
        #pragma unroll
        for (int nt = 0; nt < 2; ++nt) {
          a1[mt][nt] = (f32x4)0.f;
          #pragma unroll
          for (int ks = 0; ks < 3; ++ks)
            a1[mt][nt] = mfma_bf16(af[mt][ks], bfr[nt][ks], a1[mt][nt]);
        }
    }
    if (h < HH) {
      #pragma unroll
      for (int mt = 0; mt < 4; ++mt)
        #pragma unroll
        for (int nt = 0; nt < 2; ++nt) {
          const int v = nt * 16 + m16;
          if (v < VV) {
            const int tv = wid * VV + v;
            const int c0 = mt * 16 + kg * 4;
            u32x2 pk;
            pk[0] = pack2(a1[mt][nt][0], a1[mt][nt][1]);
            pk[1] = pack2(a1[mt][nt][2], a1[mt][nt][3]);
            char* p = xs + tv * 128 + ((c0 * 2) ^ ((tv & 7) << 4));
            *(u32x2*)p = pk;
          }
        }
    } else {
      for (int i = tid; i < 6400; i += 256) {
        const int c = i / 100, j = i % 100;
        const float f = x[((size_t)(n * 64 + c) * TT + t0) * VV + j];
        *(unsigned short*)(xs + j * 128 + ((c * 2) ^ ((j & 7) << 4))) =
            f2bu(f);
      }
    }
    __syncthreads();   // single barrier: xs writes(pb) -> reads(pb)
    #pragma unroll
    for (int nt = 0; nt < 7; ++nt) {
      const int tv = nt * 16 + m16;
      const u32x4 b0 = *(const u32x4*)(xs + tv * 128 +
                        (((kg * 8) * 2) ^ ((tv & 7) << 4)));
      const u32x4 b1 = *(const u32x4*)(xs + tv * 128 +
                        (((32 + kg * 8) * 2) ^ ((tv & 7) << 4)));
      #pragma unroll
      for (int mt = 0; mt < 2; ++mt) {
        acc2[mt][nt] = mfma_bf16(a2[mt][0], b0, acc2[mt][nt]);
        acc2[mt][nt] = mfma_bf16(a2[mt][1], b1, acc2[mt][nt]);
      }
    }
  }

  #pragma unroll
  for (int mt = 0; mt < 2; ++mt) {
    float cc[4];
    #pragma unroll
    for (int i = 0; i < 4; ++i) {
      const int d = wid * 32 + mt * 16 + kg * 4 + i;
      const float so2 = g_o[d] * rsqrtf(v_o[d] + 1e-5f);
      const float sd2 = g_d[d] * rsqrtf(v_d[d] + 1e-5f);
      cc[i] = b_o[d] * so2 + be_o[d] - m_o[d] * so2
            + b_d[d] * sd2 + be_d[d] - m_d[d] * sd2;
    }
    #pragma unroll
    for (int nt = 0; nt < 7; ++nt) {
      const int tv = nt * 16 + m16;
      if (tv < 100) {
        const int t = t0 + tv / VV, v = tv % VV;
        #pragma unroll
        for (int i = 0; i < 4; ++i) {
          const int d = wid * 32 + mt * 16 + kg * 4 + i;
          const float z = acc2[mt][nt][i] + cc[i];
          out[((n * DIMD + d) * TT + t) * VV + v] = (z >= 0.f) ? z : 0.1f * z;
        }
      }
    }
  }
  #undef STAGE_XU
  #undef STAGE_ATT
  #undef XSLB
}

// ---------------------------------------------------------------------------
extern "C" void kernel_launch(void* const* d_in, const int* in_sizes, int n_in,
                              void* d_out, int out_size, void* d_ws, size_t ws_size,
                              hipStream_t stream)
{
  (void)in_sizes; (void)n_in; (void)out_size; (void)ws_size;
  const float* x     = (const float*)d_in[0];
  const float* Wq    = (const float*)d_in[1];
  const float* bq    = (const float*)d_in[2];
  const float* Wk    = (const float*)d_in[3];
  const float* bk    = (const float*)d_in[4];
  const float* We    = (const float*)d_in[5];
  const float* be    = (const float*)d_in[6];
  const float* G     = (const float*)d_in[7];
  const float* sepe  = (const float*)d_in[8];
  const float* att0  = (const float*)d_in[9];
  const float* alpha = (const float*)d_in[10];
  const float* beta  = (const float*)d_in[11];
  const float* Wo    = (const float*)d_in[12];
  const float* b_o   = (const float*)d_in[13];
  const float* g_o   = (const float*)d_in[14];
  const float* be_o  = (const float*)d_in[15];
  const float* m_o   = (const float*)d_in[16];
  const float* v_o   = (const float*)d_in[17];
  const float* Wd    = (const float*)d_in[18];
  const float* b_d   = (const float*)d_in[19];
  const float* g_d   = (const float*)d_in[20];
  const float* be_d  = (const float*)d_in[21];
  const float* m_d   = (const float*)d_in[22];
  const float* v_d   = (const float*)d_in[23];
  const int*   dism  = (const int*)d_in[24];
  const float* disg  = (const float*)d_in[25];

  // Workspace: qy @0 (49.152 MB), kk @49,152,000, attP @98,304,000 (3.41 MB),
  // packed weights @101,711,872: woF 131072B, wdF/wqF/wkF/weF 16384B each.
  char* ws = (char*)d_ws;
  bf16* qy   = (bf16*)(ws);
  bf16* kkp  = (bf16*)(ws + 49152000);
  unsigned short* attP = (unsigned short*)(ws + 98304000);
  unsigned short* woF  = (unsigned short*)(ws + 101711872);
  unsigned short* wdF  = (unsigned short*)(ws + 101842944);
  unsigned short* wqF  = (unsigned short*)(ws + 101859328);
  unsigned short* wkF  = (unsigned short*)(ws + 101875712);
  unsigned short* weF  = (unsigned short*)(ws + 101892096);

  k_pack_w<<<384, 256, 0, stream>>>(Wo, g_o, v_o, Wd, g_d, v_d,
                                    Wq, Wk, We, beta,
                                    woF, wdF, wqF, wkF, weF);
  k_qke_mfma8<<<NB * 30, 256, 0, stream>>>(x, wqF, bq, wkF, bk, weF, be,
                                           G, beta, sepe, dism, qy, kkp);
  k_att_mfma<<<NB * HH, 256, 0, stream>>>(qy, kkp, bq, disg, att0, alpha, attP);
  k_out_mfma6<<<NB * 30, 256, 0, stream>>>(x, attP, woF, wdF,
                                           b_o, g_o, be_o, m_o, v_o,
                                           b_d, g_d, be_d, m_d, v_d,
                                           (float*)d_out);
}

// Round 19
// 478.353 us; speedup vs baseline: 1.0014x; 1.0014x over previous
//
#include <hip/hip_runtime.h>
#include <hip/hip_bf16.h>
#include <math.h>

// Problem constants (fixed by the reference)
#define NB   64     // batch
#define CIN  64     // input channels
#define DIMD 128    // q/k/e channels
#define TT   120    // time
#define VV   25     // joints
#define HH   8      // heads
#define DHD  16     // DIM/H
#define WW   3      // temporal window
#define UU   75     // W*V
#define TC2  12     // t-chunk in MFMA attention kernel (120 = 10*12)
#define TCO  4      // t-chunk in output kernel (120 = 4*30)

typedef __hip_bfloat16 bf16;
typedef float        f32x4  __attribute__((ext_vector_type(4)));
typedef unsigned int u32x4  __attribute__((ext_vector_type(4)));
typedef unsigned int u32x2  __attribute__((ext_vector_type(2)));
typedef __bf16       bf16x8 __attribute__((ext_vector_type(8)));

__device__ __forceinline__ float b2f(bf16 v)  { return __bfloat162float(v); }
__device__ __forceinline__ bf16  f2b(float v) { return __float2bfloat16(v); }

__device__ __forceinline__ unsigned short f2bu(float f) {
  unsigned u = __builtin_bit_cast(unsigned, f);
  return (unsigned short)((u + 0x7fffu + ((u >> 16) & 1u)) >> 16);  // RNE
}
__device__ __forceinline__ float bfu(unsigned short s) {
  unsigned u = ((unsigned)s) << 16;
  return __builtin_bit_cast(float, u);
}
__device__ __forceinline__ unsigned pack2(float a, float b) {
  return ((unsigned)f2bu(b) << 16) | (unsigned)f2bu(a);
}

// BUILTIN MFMA (R11 lesson: asm-wrapped MFMA is invisible to the GCN hazard
// recognizer -> missing MFMA->VALU wait-states -> silent corruption).
__device__ __forceinline__ f32x4 mfma_bf16(u32x4 a, u32x4 b, f32x4 d) {
  return __builtin_amdgcn_mfma_f32_16x16x32_bf16(
      __builtin_bit_cast(bf16x8, a), __builtin_bit_cast(bf16x8, b), d, 0, 0, 0);
}

// ---------------------------------------------------------------------------
// Pre-pack kernel (R17-verbatim): weights -> fragment-ordered bf16 tensors.
// ---------------------------------------------------------------------------
__global__ __launch_bounds__(256) void k_pack_w(
    const float* __restrict__ Wo, const float* __restrict__ g_o,
    const float* __restrict__ v_o,
    const float* __restrict__ Wd, const float* __restrict__ g_d,
    const float* __restrict__ v_d,
    const float* __restrict__ Wq, const float* __restrict__ Wk,
    const float* __restrict__ We, const float* __restrict__ beta,
    unsigned short* __restrict__ woF, unsigned short* __restrict__ wdF,
    unsigned short* __restrict__ wqF, unsigned short* __restrict__ wkF,
    unsigned short* __restrict__ weF)
{
  const int i = blockIdx.x * 256 + threadIdx.x;   // grid covers 98304
  if (i < 65536) {                                 // woF
    const int j = i & 7, d = (i >> 3) & 127, kg = (i >> 10) & 3;
    const int ks = (i >> 12) & 1, h = (i >> 13) & 7;
    const float sc = g_o[d] * rsqrtf(v_o[d] + 1e-5f);
    woF[i] = f2bu(sc * Wo[d * 512 + h * 64 + ks * 32 + kg * 8 + j]);
  } else {
    const int r = i - 65536;                       // 0..32767
    const int which = r >> 13;                     // 0=wd 1=wq 2=wk 3=we
    const int l = r & 8191;
    const int j = l & 7, d = (l >> 3) & 127, kg = (l >> 10) & 3;
    const int ks = (l >> 12) & 1;
    const int c = ks * 32 + kg * 8 + j;
    if (which == 0) {
      const float sc = g_d[d] * rsqrtf(v_d[d] + 1e-5f);
      wdF[l] = f2bu(sc * Wd[d * 64 + c]);
    } else if (which == 1) {
      wqF[l] = f2bu(Wq[d * 64 + c]);
    } else if (which == 2) {
      wkF[l] = f2bu(Wk[d * 64 + c]);
    } else {
      weF[l] = f2bu(beta[0] * We[d * 64 + c]);
    }
  }
}

// ---------------------------------------------------------------------------
// Fused A+B v8b: = R18's passing algorithm with the liveness fix — yC dump
// happens INSIDE phase 1 (acc1 never crosses a barrier; no spill).
// ---------------------------------------------------------------------------
__global__ __launch_bounds__(256, 3) void k_qke_mfma8b(
    const float* __restrict__ x,
    const unsigned short* __restrict__ wqF, const float* __restrict__ bq,
    const unsigned short* __restrict__ wkF, const float* __restrict__ bk,
    const unsigned short* __restrict__ weF, const float* __restrict__ be,
    const float* __restrict__ G,  const float* __restrict__ beta,
    const float* __restrict__ se_pe, const int* __restrict__ dis,
    bf16* __restrict__ qy, bf16* __restrict__ kkp)
{
  const int n = blockIdx.x / 30, t0 = (blockIdx.x % 30) * 4;
  __shared__ alignas(16) char uA[14336];                 // xf | yTG
  __shared__ alignas(16) unsigned short yC[4][64][32];   // 16,384  [t][c][u] swz
  __shared__ alignas(16) unsigned short yT[112][64];     // 14,336  [tv][c] swz
  __shared__ alignas(16) unsigned short GlT[32][32];     //  2,048  [v][u] swz
  __shared__ alignas(16) float spl[5][64];               //  1,280
  __shared__ alignas(16) int   dml[25][25];              //  2,500
  __shared__ alignas(16) float gsum[32];                 //    128
  __shared__ alignas(16) float biasb[384];               //  1,536  bq|bk|be

  unsigned short* xf = (unsigned short*)uA;              // [(t*64+c)*26+v]
  char* yTG = uA;                                        // [112] x 128B swz

  const int tid = threadIdx.x;
  // ---- phase 0: stage ----
  {
    const float* xb = x + (size_t)n * 192000 + t0 * 25;  // x[n][c][t0+t][v]
    for (int i = tid; i < 6400; i += 256) {
      const int c = i / 100, j = i % 100, t = j / 25, v = j % 25;
      xf[(t * 64 + c) * 26 + v] = f2bu(xb[c * 3000 + j]);
    }
  }
  for (int i = tid; i < 320; i += 256) spl[i / 64][i % 64] = se_pe[i];
  for (int i = tid; i < 625; i += 256) dml[i / 25][i % 25] = dis[i];
  for (int i = tid; i < 1024; i += 256) {                // GlT[v][u]=G[u][v], swz
    const int v = i >> 5, u = i & 31;
    const float g = (v < 25 && u < 25) ? G[u * 25 + v] : 0.f;
    *(unsigned short*)((char*)GlT + v * 64 + ((u * 2) ^ ((v & 7) << 4))) =
        f2bu(g);
  }
  if (tid < 25) {
    float s = 0.f;
    for (int u = 0; u < 25; ++u) s += G[u * 25 + tid];
    gsum[tid] = s;
  }
  for (int i = tid; i < 384; i += 256)
    biasb[i] = (i < 128) ? bq[i] : (i < 256 ? bk[i - 128] : be[i - 256]);
  for (int i = tid; i < 12 * 64; i += 256)               // yT junk rows -> 0
    yT[100 + (i >> 6)][i & 63] = 0;
  __syncthreads();

  const int lane = tid & 63, wid = tid >> 6;
  const int m16 = lane & 15, kg = lane >> 4;

  #define LOAD_PFRAGS(af, Fsrc)                                                \
    _Pragma("unroll")                                                          \
    for (int mt = 0; mt < 2; ++mt) {                                           \
      const int d_ = wid * 32 + mt * 16 + m16;                                 \
      _Pragma("unroll")                                                        \
      for (int ks = 0; ks < 2; ++ks)                                           \
        af[mt][ks] = *(const u32x4*)((Fsrc) +                                  \
                      (((ks * 4 + kg) * 128 + d_) << 3));                      \
    }

  // ---- phase 1 (register-hop-select): y = x + pe + struct-enc.
  //      acc1 lives only inside this block: yT AND yC written here. ----
  {
    float acc1[25];
    const int c = tid & 63, t = tid >> 6;
    const float s0 = spl[0][c], s1 = spl[1][c], s2 = spl[2][c],
                s3 = spl[3][c], s4 = spl[4][c];
    const float dv = expf(-(float)(c & ~1) * (logf(10000.0f) / 64.0f));
    #pragma unroll
    for (int v = 0; v < 25; ++v)
      acc1[v] = bfu(xf[(t * 64 + c) * 26 + v]) +
                ((c & 1) ? cosf((float)v * dv) : sinf((float)v * dv));
    for (int u = 0; u < 25; ++u) {
      const float xu = bfu(xf[(t * 64 + c) * 26 + u]);
      #pragma unroll
      for (int v = 0; v < 25; ++v) {
        const int m = dml[u][v];       // wave-uniform -> LDS broadcast
        const float s = m == 0 ? s0 : m == 1 ? s1 : m == 2 ? s2
                      : m == 3 ? s3 : s4;
        acc1[v] = fmaf(xu, s, acc1[v]);
      }
    }
    char* rowp = (char*)&yC[t][c][0];
    #pragma unroll
    for (int v = 0; v < 25; ++v) {
      const unsigned short yb = f2bu(acc1[v]);
      const int tv = t * 25 + v;
      *(unsigned short*)((char*)yT + tv * 128 + ((c * 2) ^ ((tv & 7) << 4))) = yb;
      *(unsigned short*)(rowp + ((v * 2) ^ ((c & 7) << 4))) = yb;
    }
    #pragma unroll
    for (int v = 25; v < 32; ++v)
      *(unsigned short*)(rowp + ((v * 2) ^ ((c & 7) << 4))) = 0;
  }
  __syncthreads();   // xf DEAD (region A becomes yTG); yC + yT ready

  // ---- phase 1b (MFMA): yTG = y @ G  (wave wid handles t = wid) ----
  for (int i = tid; i < 12 * 64; i += 256)
    *(unsigned short*)(yTG + (100 + (i >> 6)) * 128 + ((i & 63) * 2)) = 0;
  {
    const int t = wid;
    u32x4 bg[2];
    #pragma unroll
    for (int ntv = 0; ntv < 2; ++ntv) {
      const int v = ntv * 16 + m16;
      bg[ntv] = *(const u32x4*)((const char*)GlT + v * 64 +
                                ((kg * 16) ^ ((v & 7) << 4)));
    }
    #pragma unroll
    for (int mtile = 0; mtile < 4; ++mtile) {
      const int cr = mtile * 16 + m16;
      const u32x4 a = *(const u32x4*)((const char*)&yC[t][cr][0] +
                                      ((kg * 16) ^ ((cr & 7) << 4)));
      #pragma unroll
      for (int ntv = 0; ntv < 2; ++ntv) {
        f32x4 d = (f32x4)0.f;
        d = mfma_bf16(a, bg[ntv], d);
        const int v = ntv * 16 + m16;
        if (v < 25) {
          const int tv = t * 25 + v;
          #pragma unroll
          for (int i = 0; i < 4; ++i) {
            const int cc = mtile * 16 + kg * 4 + i;
            *(unsigned short*)(yTG + tv * 128 + ((cc * 2) ^ ((tv & 7) << 4))) =
                f2bu(d[i]);
          }
        }
      }
    }
  }
  __syncthreads();   // yTG ready — LAST barrier; GEMMs are straight-line

  bf16* qyb = qy  + (size_t)n * 384000 + t0 * 25;
  bf16* kkb = kkp + (size_t)n * 384000 + t0 * 25;
  const float betav = beta[0];

  // ---- q-GEMM ----
  {
    u32x4 aq[2][2];
    LOAD_PFRAGS(aq, wqF);
    for (int nt = 0; nt < 7; ++nt) {
      const int tv = nt * 16 + m16;
      const u32x4 b0 = *(const u32x4*)((const char*)yT + tv * 128 +
                        (((kg * 8) * 2) ^ ((tv & 7) << 4)));
      const u32x4 b1 = *(const u32x4*)((const char*)yT + tv * 128 +
                        (((32 + kg * 8) * 2) ^ ((tv & 7) << 4)));
      #pragma unroll
      for (int mt = 0; mt < 2; ++mt) {
        f32x4 acc = (f32x4)0.f;
        acc = mfma_bf16(aq[mt][0], b0, acc);
        acc = mfma_bf16(aq[mt][1], b1, acc);
        if (tv < 100) {
          const int dr = wid * 32 + mt * 16 + kg * 4;
          #pragma unroll
          for (int i2 = 0; i2 < 4; ++i2)
            qyb[(size_t)(dr + i2) * 3000 + tv] = f2b(acc[i2] + biasb[dr + i2]);
        }
      }
    }
  }

  // ---- k-GEMM into persistent kacc ----
  f32x4 kacc[2][7];
  #pragma unroll
  for (int mt = 0; mt < 2; ++mt)
    #pragma unroll
    for (int nt = 0; nt < 7; ++nt) kacc[mt][nt] = (f32x4)0.f;
  {
    u32x4 ak[2][2];
    LOAD_PFRAGS(ak, wkF);
    for (int nt = 0; nt < 7; ++nt) {
      const int tv = nt * 16 + m16;
      const u32x4 b0 = *(const u32x4*)((const char*)yT + tv * 128 +
                        (((kg * 8) * 2) ^ ((tv & 7) << 4)));
      const u32x4 b1 = *(const u32x4*)((const char*)yT + tv * 128 +
                        (((32 + kg * 8) * 2) ^ ((tv & 7) << 4)));
      #pragma unroll
      for (int mt = 0; mt < 2; ++mt) {
        kacc[mt][nt] = mfma_bf16(ak[mt][0], b0, kacc[mt][nt]);
        kacc[mt][nt] = mfma_bf16(ak[mt][1], b1, kacc[mt][nt]);
      }
    }
  }

  // ---- e-GEMM (beta pre-folded in weF) on yTG, accumulate, store kk ----
  {
    u32x4 ae[2][2];
    LOAD_PFRAGS(ae, weF);
    for (int nt = 0; nt < 7; ++nt) {
      const int tv = nt * 16 + m16;
      const u32x4 b0 = *(const u32x4*)(yTG + tv * 128 +
                        (((kg * 8) * 2) ^ ((tv & 7) << 4)));
      const u32x4 b1 = *(const u32x4*)(yTG + tv * 128 +
                        (((32 + kg * 8) * 2) ^ ((tv & 7) << 4)));
      #pragma unroll
      for (int mt = 0; mt < 2; ++mt) {
        kacc[mt][nt] = mfma_bf16(ae[mt][0], b0, kacc[mt][nt]);
        kacc[mt][nt] = mfma_bf16(ae[mt][1], b1, kacc[mt][nt]);
        if (tv < 100) {
          const int vv = tv % 25;
          const int dr = wid * 32 + mt * 16 + kg * 4;
          #pragma unroll
          for (int i2 = 0; i2 < 4; ++i2)
            kkb[(size_t)(dr + i2) * 3000 + tv] =
                f2b(kacc[mt][nt][i2] + biasb[128 + dr + i2] +
                    betav * biasb[256 + dr + i2] * gsum[vv]);
        }
      }
    }
  }
  #undef LOAD_PFRAGS
}

// ---------------------------------------------------------------------------
// Kernel C v2 (R17-verbatim, passing): MFMA attention -> padded attP
// ---------------------------------------------------------------------------
__global__ __launch_bounds__(256) void k_att_mfma(
    const bf16* __restrict__ qy, const bf16* __restrict__ kkp,
    const float* __restrict__ bq, const float* __restrict__ disg,
    const float* __restrict__ att0, const float* __restrict__ alpha,
    unsigned short* __restrict__ attP)
{
  const int n = blockIdx.x / HH, h = blockIdx.x % HH;
  __shared__ alignas(16) unsigned short qsA[80][200];  // [u][k] bf16 bits
  __shared__ alignas(16) unsigned short ksB[32][200];  // [v][k] bf16 bits
  __shared__ alignas(16) float att_s[80][28];
  __shared__ float mxv[32], smv[32];
  const int tid = threadIdx.x;
  const int lane = tid & 63, wid = tid >> 6;
  const int m16 = lane & 15, kg = lane >> 4;

  const unsigned short* qyb =
      (const unsigned short*)(qy + ((size_t)(n * DIMD + h * DHD)) * TT * VV);
  const unsigned short* kkb =
      (const unsigned short*)(kkp + ((size_t)(n * DIMD + h * DHD)) * TT * VV);

  f32x4 acc[3];
  #pragma unroll
  for (int s = 0; s < 3; ++s) acc[s] = (f32x4)0.f;

  for (int c = 0; c < 10; ++c) {
    const int t0 = c * TC2;
    __syncthreads();   // prev chunk's frag reads drained
    for (int it = tid; it < 416; it += 256) {
      if (it < 224) {
        const int dh = it / 14, j = it % 14, tq = t0 + j - 1;
        unsigned short vals[25];
        if (tq >= 0 && tq < TT) {
          const unsigned short* src = qyb + ((size_t)dh * TT + tq) * VV;
          #pragma unroll
          for (int u = 0; u < 25; ++u) vals[u] = src[u];
        } else {
          const unsigned short bqv = f2bu(bq[h * DHD + dh]);
          #pragma unroll
          for (int u = 0; u < 25; ++u) vals[u] = bqv;
        }
        #pragma unroll
        for (int w = 0; w < 3; ++w) {
          const int tt = tq - t0 - w + 1;
          if (tt >= 0 && tt < TC2) {
            const int col = tt * 16 + dh;
            #pragma unroll
            for (int u = 0; u < 25; ++u) qsA[w * 25 + u][col] = vals[u];
          }
        }
      } else {
        const int r = it - 224, dh = r / TC2, tt = r % TC2;
        const unsigned short* src = kkb + ((size_t)dh * TT + t0 + tt) * VV;
        const int col = tt * 16 + dh;
        #pragma unroll
        for (int v = 0; v < 25; ++v) ksB[v][col] = src[v];
      }
    }
    __syncthreads();   // tiles ready
    #pragma unroll
    for (int s = 0; s < 3; ++s) {
      const int tidx = wid + 4 * s;
      if (tidx < 10) {
        const int mtile = tidx >> 1, ntile = tidx & 1;
        #pragma unroll
        for (int ks = 0; ks < 6; ++ks) {
          const u32x4 a = *(const u32x4*)&qsA[mtile * 16 + m16][ks * 32 + kg * 8];
          const u32x4 b = *(const u32x4*)&ksB[ntile * 16 + m16][ks * 32 + kg * 8];
          acc[s] = mfma_bf16(a, b, acc[s]);
        }
      }
    }
  }
  __syncthreads();
  #pragma unroll
  for (int s = 0; s < 3; ++s) {
    const int tidx = wid + 4 * s;
    if (tidx < 10) {
      const int mtile = tidx >> 1, ntile = tidx & 1;
      const int v = ntile * 16 + m16;
      if (v < VV) {
        #pragma unroll
        for (int i = 0; i < 4; ++i)
          att_s[mtile * 16 + kg * 4 + i][v] = acc[s][i];
      }
    }
  }
  __syncthreads();
  const float inv = 1.0f / (float)(DHD * TT);
  for (int i = tid; i < UU * VV; i += 256) {
    const int u = i / VV, v = i % VV;
    const bool m = disg[(h * VV + u % VV) * VV + v] > 0.f;
    att_s[u][v] = m ? att_s[u][v] * inv : -9e15f;
  }
  __syncthreads();
  if (tid < VV) {
    float mx = -INFINITY;
    for (int u = 0; u < UU; ++u) mx = fmaxf(mx, att_s[u][tid]);
    float sm = 0.f;
    for (int u = 0; u < UU; ++u) sm += expf(att_s[u][tid] - mx);
    mxv[tid] = mx; smv[tid] = sm;
  }
  __syncthreads();
  const float al = alpha[0];
  unsigned* dst = (unsigned*)(attP + ((size_t)(n * HH + h) * 32) * 104);
  for (int i = tid; i < 1664; i += 256) {     // 32 x 52 u32 (= 104 u16)
    const int vc = i / 52, u0 = (i % 52) * 2;
    unsigned val = 0u;
    if (vc < VV) {
      float f0 = 0.f, f1 = 0.f;
      if (u0 < UU)
        f0 = expf(att_s[u0][vc] - mxv[vc]) / smv[vc] * al
             + att0[(h * VV + u0 % VV) * VV + vc];
      if (u0 + 1 < UU)
        f1 = expf(att_s[u0 + 1][vc] - mxv[vc]) / smv[vc] * al
             + att0[(h * VV + (u0 + 1) % VV) * VV + vc];
      val = pack2(f0, f1);
    }
    dst[i] = val;
  }
}

// ---------------------------------------------------------------------------
// Kernel D v6 (R17-verbatim, passing)
// ---------------------------------------------------------------------------
__global__ __launch_bounds__(256) void k_out_mfma6(
    const float* __restrict__ x, const unsigned short* __restrict__ attP,
    const unsigned short* __restrict__ woF, const unsigned short* __restrict__ wdF,
    const float* __restrict__ b_o,
    const float* __restrict__ g_o, const float* __restrict__ be_o,
    const float* __restrict__ m_o, const float* __restrict__ v_o,
    const float* __restrict__ b_d,
    const float* __restrict__ g_d, const float* __restrict__ be_d,
    const float* __restrict__ m_d, const float* __restrict__ v_d,
    float* __restrict__ out)
{
  const int n = blockIdx.x / 30, t0 = (blockIdx.x % 30) * TCO;
  __shared__ alignas(16) char uB[28672];                   // xu2 | xsl2[2]
  __shared__ alignas(16) unsigned short attB[2][32][104];  // 13,312 B dbuf
  unsigned short* xu2 = (unsigned short*)uB;               // [(tr*64+c)*104+u]
  const int tid = threadIdx.x;
  const int lane = tid & 63, wid = tid >> 6;
  const int m16 = lane & 15, kg = lane >> 4;

  #define XSLB(b) (uB + (b) * 14336)            // [112] rows x 128B swz

  #define STAGE_XU(tb)                                                         \
    for (int i = tid; i < 2 * 64 * 48; i += 256) {                             \
      const int u0 = (i % 48) * 2, c = (i / 48) & 63, tr = i / (48 * 64);      \
      float f0 = 0.f, f1 = 0.f;                                                \
      if (u0 < UU) {                                                           \
        const int w = u0 / VV, up = u0 % VV, ts = t0 + (tb) + tr + w - 1;      \
        if (ts >= 0 && ts < TT) f0 = x[((n * 64 + c) * TT + ts) * VV + up];    \
      }                                                                        \
      if (u0 + 1 < UU) {                                                       \
        const int u = u0 + 1, w = u / VV, up = u % VV;                         \
        const int ts = t0 + (tb) + tr + w - 1;                                 \
        if (ts >= 0 && ts < TT) f1 = x[((n * 64 + c) * TT + ts) * VV + up];    \
      }                                                                        \
      *(unsigned*)(xu2 + (tr * 64 + c) * 104 + u0) = pack2(f0, f1);            \
    }

  #define STAGE_ATT(hh, buf)                                                   \
    {                                                                          \
      const u32x4* srcv =                                                      \
          (const u32x4*)(attP + ((size_t)(n * HH + (hh)) * 32) * 104);         \
      u32x4* dstv = (u32x4*)&attB[buf][0][0];                                  \
      for (int i = tid; i < 416; i += 256) dstv[i] = srcv[i];                  \
    }

  // ---- prologue: A-frags from xu2 in two 2-t chunks ----
  STAGE_XU(0);
  __syncthreads();
  u32x4 af[4][3];
  if (wid < 2) {
    #pragma unroll
    for (int mt = 0; mt < 4; ++mt)
      #pragma unroll
      for (int ks = 0; ks < 3; ++ks)
        af[mt][ks] = *(const u32x4*)(xu2 + (wid * 64 + mt * 16 + m16) * 104 +
                                     ks * 32 + kg * 8);
  }
  __syncthreads();   // chunk-1 reads drained before overwrite
  STAGE_XU(2);
  STAGE_ATT(0, 0);
  __syncthreads();
  if (wid >= 2) {
    #pragma unroll
    for (int mt = 0; mt < 4; ++mt)
      #pragma unroll
      for (int ks = 0; ks < 3; ++ks)
        af[mt][ks] = *(const u32x4*)(xu2 + ((wid - 2) * 64 + mt * 16 + m16) * 104 +
                                     ks * 32 + kg * 8);
  }
  __syncthreads();   // FENCE: all xu2 reads drained; uB becomes xsl2
  for (int i = tid; i < 2 * 12 * 64; i += 256) {
    const int b = i / (12 * 64), r = i % (12 * 64);
    *(unsigned short*)(XSLB(b) + (100 + (r >> 6)) * 128 + ((r & 63) * 2)) = 0;
  }

  f32x4 acc2[2][7];
  #pragma unroll
  for (int mt = 0; mt < 2; ++mt)
    #pragma unroll
    for (int nt = 0; nt < 7; ++nt) acc2[mt][nt] = (f32x4)0.f;

  for (int h = 0; h <= HH; ++h) {
    const int pb = h & 1;
    char* xs = XSLB(pb);
    u32x4 a2[2][2];
    #pragma unroll
    for (int mt = 0; mt < 2; ++mt) {
      const int d = wid * 32 + mt * 16 + m16;
      #pragma unroll
      for (int ks = 0; ks < 2; ++ks) {
        const unsigned short* src = (h < HH)
            ? (woF + ((((h * 2 + ks) * 4 + kg) * 128 + d) << 3))
            : (wdF + ((((ks) * 4 + kg) * 128 + d) << 3));
        a2[mt][ks] = *(const u32x4*)src;
      }
    }
    if (h + 1 < HH) { STAGE_ATT(h + 1, (h + 1) & 1); }
    f32x4 a1[4][2];
    if (h < HH) {
      u32x4 bfr[2][3];
      #pragma unroll
      for (int nt = 0; nt < 2; ++nt)
        #pragma unroll
        for (int ks = 0; ks < 3; ++ks)
          bfr[nt][ks] =
              *(const u32x4*)&attB[pb][nt * 16 + m16][ks * 32 + kg * 8];
      #pragma unroll
      for (int mt = 0; mt < 4; ++mt)
        #pragma unroll
        for (int nt = 0; nt < 2; ++nt) {
          a1[mt][nt] = (f32x4)0.f;
          #pragma unroll
          for (int ks = 0; ks < 3; ++ks)
            a1[mt][nt] = mfma_bf16(af[mt][ks], bfr[nt][ks], a1[mt][nt]);
        }
    }
    if (h < HH) {
      #pragma unroll
      for (int mt = 0; mt < 4; ++mt)
        #pragma unroll
        for (int nt = 0; nt < 2; ++nt) {
          const int v = nt * 16 + m16;
          if (v < VV) {
            const int tv = wid * VV + v;
            const int c0 = mt * 16 + kg * 4;
            u32x2 pk;
            pk[0] = pack2(a1[mt][nt][0], a1[mt][nt][1]);
            pk[1] = pack2(a1[mt][nt][2], a1[mt][nt][3]);
            char* p = xs + tv * 128 + ((c0 * 2) ^ ((tv & 7) << 4));
            *(u32x2*)p = pk;
          }
        }
    } else {
      for (int i = tid; i < 6400; i += 256) {
        const int c = i / 100, j = i % 100;
        const float f = x[((size_t)(n * 64 + c) * TT + t0) * VV + j];
        *(unsigned short*)(xs + j * 128 + ((c * 2) ^ ((j & 7) << 4))) =
            f2bu(f);
      }
    }
    __syncthreads();   // single barrier: xs writes(pb) -> reads(pb)
    #pragma unroll
    for (int nt = 0; nt < 7; ++nt) {
      const int tv = nt * 16 + m16;
      const u32x4 b0 = *(const u32x4*)(xs + tv * 128 +
                        (((kg * 8) * 2) ^ ((tv & 7) << 4)));
      const u32x4 b1 = *(const u32x4*)(xs + tv * 128 +
                        (((32 + kg * 8) * 2) ^ ((tv & 7) << 4)));
      #pragma unroll
      for (int mt = 0; mt < 2; ++mt) {
        acc2[mt][nt] = mfma_bf16(a2[mt][0], b0, acc2[mt][nt]);
        acc2[mt][nt] = mfma_bf16(a2[mt][1], b1, acc2[mt][nt]);
      }
    }
  }

  #pragma unroll
  for (int mt = 0; mt < 2; ++mt) {
    float cc[4];
    #pragma unroll
    for (int i = 0; i < 4; ++i) {
      const int d = wid * 32 + mt * 16 + kg * 4 + i;
      const float so2 = g_o[d] * rsqrtf(v_o[d] + 1e-5f);
      const float sd2 = g_d[d] * rsqrtf(v_d[d] + 1e-5f);
      cc[i] = b_o[d] * so2 + be_o[d] - m_o[d] * so2
            + b_d[d] * sd2 + be_d[d] - m_d[d] * sd2;
    }
    #pragma unroll
    for (int nt = 0; nt < 7; ++nt) {
      const int tv = nt * 16 + m16;
      if (tv < 100) {
        const int t = t0 + tv / VV, v = tv % VV;
        #pragma unroll
        for (int i = 0; i < 4; ++i) {
          const int d = wid * 32 + mt * 16 + kg * 4 + i;
          const float z = acc2[mt][nt][i] + cc[i];
          out[((n * DIMD + d) * TT + t) * VV + v] = (z >= 0.f) ? z : 0.1f * z;
        }
      }
    }
  }
  #undef STAGE_XU
  #undef STAGE_ATT
  #undef XSLB
}

// ---------------------------------------------------------------------------
extern "C" void kernel_launch(void* const* d_in, const int* in_sizes, int n_in,
                              void* d_out, int out_size, void* d_ws, size_t ws_size,
                              hipStream_t stream)
{
  (void)in_sizes; (void)n_in; (void)out_size; (void)ws_size;
  const float* x     = (const float*)d_in[0];
  const float* Wq    = (const float*)d_in[1];
  const float* bq    = (const float*)d_in[2];
  const float* Wk    = (const float*)d_in[3];
  const float* bk    = (const float*)d_in[4];
  const float* We    = (const float*)d_in[5];
  const float* be    = (const float*)d_in[6];
  const float* G     = (const float*)d_in[7];
  const float* sepe  = (const float*)d_in[8];
  const float* att0  = (const float*)d_in[9];
  const float* alpha = (const float*)d_in[10];
  const float* beta  = (const float*)d_in[11];
  const float* Wo    = (const float*)d_in[12];
  const float* b_o   = (const float*)d_in[13];
  const float* g_o   = (const float*)d_in[14];
  const float* be_o  = (const float*)d_in[15];
  const float* m_o   = (const float*)d_in[16];
  const float* v_o   = (const float*)d_in[17];
  const float* Wd    = (const float*)d_in[18];
  const float* b_d   = (const float*)d_in[19];
  const float* g_d   = (const float*)d_in[20];
  const float* be_d  = (const float*)d_in[21];
  const float* m_d   = (const float*)d_in[22];
  const float* v_d   = (const float*)d_in[23];
  const int*   dism  = (const int*)d_in[24];
  const float* disg  = (const float*)d_in[25];

  // Workspace: qy @0 (49.152 MB), kk @49,152,000, attP @98,304,000 (3.41 MB),
  // packed weights @101,711,872: woF 131072B, wdF/wqF/wkF/weF 16384B each.
  char* ws = (char*)d_ws;
  bf16* qy   = (bf16*)(ws);
  bf16* kkp  = (bf16*)(ws + 49152000);
  unsigned short* attP = (unsigned short*)(ws + 98304000);
  unsigned short* woF  = (unsigned short*)(ws + 101711872);
  unsigned short* wdF  = (unsigned short*)(ws + 101842944);
  unsigned short* wqF  = (unsigned short*)(ws + 101859328);
  unsigned short* wkF  = (unsigned short*)(ws + 101875712);
  unsigned short* weF  = (unsigned short*)(ws + 101892096);

  k_pack_w<<<384, 256, 0, stream>>>(Wo, g_o, v_o, Wd, g_d, v_d,
                                    Wq, Wk, We, beta,
                                    woF, wdF, wqF, wkF, weF);
  k_qke_mfma8b<<<NB * 30, 256, 0, stream>>>(x, wqF, bq, wkF, bk, weF, be,
                                            G, beta, sepe, dism, qy, kkp);
  k_att_mfma<<<NB * HH, 256, 0, stream>>>(qy, kkp, bq, disg, att0, alpha, attP);
  k_out_mfma6<<<NB * 30, 256, 0, stream>>>(x, attP, woF, wdF,
                                           b_o, g_o, be_o, m_o, v_o,
                                           b_d, g_d, be_d, m_d, v_d,
                                           (float*)d_out);
}

// Round 20
// 429.694 us; speedup vs baseline: 1.1148x; 1.1132x over previous
//
#include <hip/hip_runtime.h>
#include <hip/hip_bf16.h>
#include <math.h>

// Problem constants (fixed by the reference)
#define NB   64     // batch
#define CIN  64     // input channels
#define DIMD 128    // q/k/e channels
#define TT   120    // time
#define VV   25     // joints
#define HH   8      // heads
#define DHD  16     // DIM/H
#define WW   3      // temporal window
#define UU   75     // W*V
#define TC2  12     // t-chunk in MFMA attention kernel (120 = 10*12)
#define TCO  4      // t-chunk in output kernel (120 = 4*30)

typedef __hip_bfloat16 bf16;
typedef float        f32x4  __attribute__((ext_vector_type(4)));
typedef unsigned int u32x4  __attribute__((ext_vector_type(4)));
typedef unsigned int u32x2  __attribute__((ext_vector_type(2)));
typedef __bf16       bf16x8 __attribute__((ext_vector_type(8)));

__device__ __forceinline__ float b2f(bf16 v)  { return __bfloat162float(v); }
__device__ __forceinline__ bf16  f2b(float v) { return __float2bfloat16(v); }

__device__ __forceinline__ unsigned short f2bu(float f) {
  unsigned u = __builtin_bit_cast(unsigned, f);
  return (unsigned short)((u + 0x7fffu + ((u >> 16) & 1u)) >> 16);  // RNE
}
__device__ __forceinline__ float bfu(unsigned short s) {
  unsigned u = ((unsigned)s) << 16;
  return __builtin_bit_cast(float, u);
}
__device__ __forceinline__ unsigned pack2(float a, float b) {
  return ((unsigned)f2bu(b) << 16) | (unsigned)f2bu(a);
}

// BUILTIN MFMA (R11 lesson: asm-wrapped MFMA is invisible to the GCN hazard
// recognizer -> missing MFMA->VALU wait-states -> silent corruption).
__device__ __forceinline__ f32x4 mfma_bf16(u32x4 a, u32x4 b, f32x4 d) {
  return __builtin_amdgcn_mfma_f32_16x16x32_bf16(
      __builtin_bit_cast(bf16x8, a), __builtin_bit_cast(bf16x8, b), d, 0, 0, 0);
}

// ---------------------------------------------------------------------------
// Pre-pack kernel (R17-verbatim): weights -> fragment-ordered bf16 tensors.
// ---------------------------------------------------------------------------
__global__ __launch_bounds__(256) void k_pack_w(
    const float* __restrict__ Wo, const float* __restrict__ g_o,
    const float* __restrict__ v_o,
    const float* __restrict__ Wd, const float* __restrict__ g_d,
    const float* __restrict__ v_d,
    const float* __restrict__ Wq, const float* __restrict__ Wk,
    const float* __restrict__ We, const float* __restrict__ beta,
    unsigned short* __restrict__ woF, unsigned short* __restrict__ wdF,
    unsigned short* __restrict__ wqF, unsigned short* __restrict__ wkF,
    unsigned short* __restrict__ weF)
{
  const int i = blockIdx.x * 256 + threadIdx.x;   // grid covers 98304
  if (i < 65536) {                                 // woF
    const int j = i & 7, d = (i >> 3) & 127, kg = (i >> 10) & 3;
    const int ks = (i >> 12) & 1, h = (i >> 13) & 7;
    const float sc = g_o[d] * rsqrtf(v_o[d] + 1e-5f);
    woF[i] = f2bu(sc * Wo[d * 512 + h * 64 + ks * 32 + kg * 8 + j]);
  } else {
    const int r = i - 65536;                       // 0..32767
    const int which = r >> 13;                     // 0=wd 1=wq 2=wk 3=we
    const int l = r & 8191;
    const int j = l & 7, d = (l >> 3) & 127, kg = (l >> 10) & 3;
    const int ks = (l >> 12) & 1;
    const int c = ks * 32 + kg * 8 + j;
    if (which == 0) {
      const float sc = g_d[d] * rsqrtf(v_d[d] + 1e-5f);
      wdF[l] = f2bu(sc * Wd[d * 64 + c]);
    } else if (which == 1) {
      wqF[l] = f2bu(Wq[d * 64 + c]);
    } else if (which == 2) {
      wkF[l] = f2bu(Wk[d * 64 + c]);
    } else {
      weF[l] = f2bu(beta[0] * We[d * 64 + c]);
    }
  }
}

// ---------------------------------------------------------------------------
// Fused A+B v7t: R17's verified phases; epilogue stores in [n][tv][d] layout
// (packed u32x2 of 4 consecutive d) — coalesced, no write amplification.
// ---------------------------------------------------------------------------
__global__ __launch_bounds__(256, 3) void k_qke_mfma7t(
    const float* __restrict__ x,
    const unsigned short* __restrict__ wqF, const float* __restrict__ bq,
    const unsigned short* __restrict__ wkF, const float* __restrict__ bk,
    const unsigned short* __restrict__ weF, const float* __restrict__ be,
    const float* __restrict__ G,  const float* __restrict__ beta,
    const float* __restrict__ se_pe, const int* __restrict__ dis,
    unsigned short* __restrict__ qyT, unsigned short* __restrict__ kkT)
{
  const int n = blockIdx.x / 30, t0 = (blockIdx.x % 30) * 4;
  __shared__ alignas(16) char uA[26624];                 // xl | yTG
  __shared__ alignas(16) unsigned short yT[112][64];     // [tv][c] swz
  __shared__ alignas(16) float spl[5][64];
  __shared__ alignas(16) int   dml[25][25];
  __shared__ alignas(16) float Gl[25][26];
  __shared__ alignas(16) float gsum[32];
  __shared__ alignas(16) float biasb[384];               // bq|bk|be

  float* xl  = (float*)uA;                               // [4][64][26] f32
  char*  yTG = uA;                                       // [112] x 128B swz
  #define XL(t, c, v) xl[(((t) * 64 + (c)) * 26) + (v)]

  const int tid = threadIdx.x;
  {
    const float* xb = x + (size_t)n * 192000 + t0 * 25;  // x[n][c][t0+t][v]
    for (int i = tid; i < 6400; i += 256) {
      const int c = i / 100, j = i % 100, t = j / 25, v = j % 25;
      XL(t, c, v) = xb[c * 3000 + j];
    }
  }
  for (int i = tid; i < 320; i += 256) spl[i / 64][i % 64] = se_pe[i];
  for (int i = tid; i < 625; i += 256) dml[i / 25][i % 25] = dis[i];
  for (int i = tid; i < 625; i += 256) Gl[i / 25][i % 25] = G[i];
  if (tid < 25) {
    float s = 0.f;
    for (int u = 0; u < 25; ++u) s += G[u * 25 + tid];
    gsum[tid] = s;
  }
  for (int i = tid; i < 384; i += 256)
    biasb[i] = (i < 128) ? bq[i] : (i < 256 ? bk[i - 128] : be[i - 256]);
  for (int i = tid; i < 12 * 64; i += 256)               // yT junk rows -> 0
    yT[100 + (i >> 6)][i & 63] = 0;
  __syncthreads();

  const int lane = tid & 63, wid = tid >> 6;
  const int m16 = lane & 15, kg = lane >> 4;

  #define LOAD_PFRAGS(af, Fsrc)                                                \
    _Pragma("unroll")                                                          \
    for (int mt = 0; mt < 2; ++mt) {                                           \
      const int d_ = wid * 32 + mt * 16 + m16;                                 \
      _Pragma("unroll")                                                        \
      for (int ks = 0; ks < 2; ++ks)                                           \
        af[mt][ks] = *(const u32x4*)((Fsrc) +                                  \
                      (((ks * 4 + kg) * 128 + d_) << 3));                      \
    }

  // ---- phase 1 (R17-verbatim): yT = x + pe + struct-enc ----
  for (int idx = tid; idx < 6400; idx += 256) {
    const int c = idx & 63, tv = idx >> 6;
    const int t = tv / 25, v = tv % 25;
    const float dv = expf(-(float)(c & ~1) * (logf(10000.0f) / 64.0f));
    float acc = XL(t, c, v) +
                ((c & 1) ? cosf((float)v * dv) : sinf((float)v * dv));
    #pragma unroll
    for (int u = 0; u < 25; ++u)
      acc = fmaf(XL(t, c, u), spl[dml[u][v]][c], acc);
    *(unsigned short*)((char*)yT + tv * 128 + ((c * 2) ^ ((tv & 7) << 4))) =
        f2bu(acc);
  }
  __syncthreads();   // yT ready; xl DEAD (uA becomes yTG)

  // ---- phase 1b (R17-verbatim): yTG = y @ G ----
  for (int i = tid; i < 12 * 64; i += 256)
    *(unsigned short*)(yTG + (100 + (i >> 6)) * 128 + ((i & 63) * 2)) = 0;
  for (int idx = tid; idx < 6400; idx += 256) {
    const int c = idx & 63, tv = idx >> 6;
    const int t = tv / 25, v = tv % 25;
    float acc = 0.f;
    #pragma unroll
    for (int u = 0; u < 25; ++u) {
      const int ru = t * 25 + u;
      const float yv = bfu(*(const unsigned short*)((const char*)yT + ru * 128 +
                            ((c * 2) ^ ((ru & 7) << 4))));
      acc = fmaf(yv, Gl[u][v], acc);
    }
    *(unsigned short*)(yTG + tv * 128 + ((c * 2) ^ ((tv & 7) << 4))) =
        f2bu(acc);
  }
  __syncthreads();   // yTG ready — LAST barrier; GEMMs are straight-line

  unsigned short* qyb = qyT + (size_t)n * 384000 + (size_t)t0 * 25 * 128;
  unsigned short* kkb = kkT + (size_t)n * 384000 + (size_t)t0 * 25 * 128;
  const float betav = beta[0];

  // ---- q-GEMM (packed [tv][d] store) ----
  {
    u32x4 aq[2][2];
    LOAD_PFRAGS(aq, wqF);
    for (int nt = 0; nt < 7; ++nt) {
      const int tv = nt * 16 + m16;
      const u32x4 b0 = *(const u32x4*)((const char*)yT + tv * 128 +
                        (((kg * 8) * 2) ^ ((tv & 7) << 4)));
      const u32x4 b1 = *(const u32x4*)((const char*)yT + tv * 128 +
                        (((32 + kg * 8) * 2) ^ ((tv & 7) << 4)));
      #pragma unroll
      for (int mt = 0; mt < 2; ++mt) {
        f32x4 acc = (f32x4)0.f;
        acc = mfma_bf16(aq[mt][0], b0, acc);
        acc = mfma_bf16(aq[mt][1], b1, acc);
        if (tv < 100) {
          const int dr = wid * 32 + mt * 16 + kg * 4;
          u32x2 pk;
          pk[0] = pack2(acc[0] + biasb[dr],     acc[1] + biasb[dr + 1]);
          pk[1] = pack2(acc[2] + biasb[dr + 2], acc[3] + biasb[dr + 3]);
          *(u32x2*)(qyb + tv * 128 + dr) = pk;
        }
      }
    }
  }

  // ---- k-GEMM into persistent kacc ----
  f32x4 kacc[2][7];
  #pragma unroll
  for (int mt = 0; mt < 2; ++mt)
    #pragma unroll
    for (int nt = 0; nt < 7; ++nt) kacc[mt][nt] = (f32x4)0.f;
  {
    u32x4 ak[2][2];
    LOAD_PFRAGS(ak, wkF);
    for (int nt = 0; nt < 7; ++nt) {
      const int tv = nt * 16 + m16;
      const u32x4 b0 = *(const u32x4*)((const char*)yT + tv * 128 +
                        (((kg * 8) * 2) ^ ((tv & 7) << 4)));
      const u32x4 b1 = *(const u32x4*)((const char*)yT + tv * 128 +
                        (((32 + kg * 8) * 2) ^ ((tv & 7) << 4)));
      #pragma unroll
      for (int mt = 0; mt < 2; ++mt) {
        kacc[mt][nt] = mfma_bf16(ak[mt][0], b0, kacc[mt][nt]);
        kacc[mt][nt] = mfma_bf16(ak[mt][1], b1, kacc[mt][nt]);
      }
    }
  }

  // ---- e-GEMM (beta pre-folded in weF) on yTG, accumulate, store kk ----
  {
    u32x4 ae[2][2];
    LOAD_PFRAGS(ae, weF);
    for (int nt = 0; nt < 7; ++nt) {
      const int tv = nt * 16 + m16;
      const u32x4 b0 = *(const u32x4*)(yTG + tv * 128 +
                        (((kg * 8) * 2) ^ ((tv & 7) << 4)));
      const u32x4 b1 = *(const u32x4*)(yTG + tv * 128 +
                        (((32 + kg * 8) * 2) ^ ((tv & 7) << 4)));
      #pragma unroll
      for (int mt = 0; mt < 2; ++mt) {
        kacc[mt][nt] = mfma_bf16(ae[mt][0], b0, kacc[mt][nt]);
        kacc[mt][nt] = mfma_bf16(ae[mt][1], b1, kacc[mt][nt]);
        if (tv < 100) {
          const int vv = tv % 25;
          const int dr = wid * 32 + mt * 16 + kg * 4;
          const float g = gsum[vv];
          u32x2 pk;
          pk[0] = pack2(
              kacc[mt][nt][0] + biasb[128 + dr]     + betav * biasb[256 + dr]     * g,
              kacc[mt][nt][1] + biasb[128 + dr + 1] + betav * biasb[256 + dr + 1] * g);
          pk[1] = pack2(
              kacc[mt][nt][2] + biasb[128 + dr + 2] + betav * biasb[256 + dr + 2] * g,
              kacc[mt][nt][3] + biasb[128 + dr + 3] + betav * biasb[256 + dr + 3] * g);
          *(u32x2*)(kkb + tv * 128 + dr) = pk;
        }
      }
    }
  }
  #undef LOAD_PFRAGS
  #undef XL
}

// ---------------------------------------------------------------------------
// Kernel C v3: staging from [n][tv][d] layout — per source row: 2 u32x4
// global loads + 2 b128 LDS writes (contiguous). MFMA core R16-verified.
// ---------------------------------------------------------------------------
__global__ __launch_bounds__(256) void k_att_mfma2(
    const unsigned short* __restrict__ qyT, const unsigned short* __restrict__ kkT,
    const float* __restrict__ bq, const float* __restrict__ disg,
    const float* __restrict__ att0, const float* __restrict__ alpha,
    unsigned short* __restrict__ attP)
{
  const int n = blockIdx.x / HH, h = blockIdx.x % HH;
  __shared__ alignas(16) unsigned short qsA[80][200];  // [u][k] bf16 bits
  __shared__ alignas(16) unsigned short ksB[32][200];  // [v][k] bf16 bits
  __shared__ alignas(16) float att_s[80][28];
  __shared__ float mxv[32], smv[32];
  const int tid = threadIdx.x;
  const int lane = tid & 63, wid = tid >> 6;
  const int m16 = lane & 15, kg = lane >> 4;

  const unsigned short* qb = qyT + (size_t)n * 384000 + h * 16;
  const unsigned short* kb = kkT + (size_t)n * 384000 + h * 16;

  // packed bq row (16 bf16 of bq[h*16 + 0..15]) for t-pad fill
  u32x4 bqp0, bqp1;
  {
    unsigned tmp[8];
    #pragma unroll
    for (int j = 0; j < 8; ++j)
      tmp[j] = pack2(bq[h * 16 + 2 * j], bq[h * 16 + 2 * j + 1]);
    bqp0[0] = tmp[0]; bqp0[1] = tmp[1]; bqp0[2] = tmp[2]; bqp0[3] = tmp[3];
    bqp1[0] = tmp[4]; bqp1[1] = tmp[5]; bqp1[2] = tmp[6]; bqp1[3] = tmp[7];
  }

  f32x4 acc[3];
  #pragma unroll
  for (int s = 0; s < 3; ++s) acc[s] = (f32x4)0.f;

  for (int c = 0; c < 10; ++c) {
    const int t0 = c * TC2;
    __syncthreads();   // prev chunk's frag reads drained
    // 350 q-rows (tqi 0..13 x u' 0..24) + 300 k-rows (tt 0..11 x v 0..24)
    for (int it = tid; it < 650; it += 256) {
      if (it < 350) {
        const int tqi = it / 25, u = it % 25;
        const int tq = t0 + tqi - 1;
        u32x4 r0, r1;
        if (tq >= 0 && tq < TT) {
          const unsigned short* src = qb + (size_t)(tq * 25 + u) * 128;
          r0 = *(const u32x4*)src;
          r1 = *(const u32x4*)(src + 8);
        } else {
          r0 = bqp0; r1 = bqp1;
        }
        #pragma unroll
        for (int w = 0; w < 3; ++w) {
          const int tt = tqi - w;
          if (tt >= 0 && tt < TC2) {
            unsigned short* dst = &qsA[w * 25 + u][tt * 16];
            *(u32x4*)dst = r0;
            *(u32x4*)(dst + 8) = r1;
          }
        }
      } else {
        const int j = it - 350, tt = j / 25, v = j % 25;
        const unsigned short* src = kb + (size_t)((t0 + tt) * 25 + v) * 128;
        unsigned short* dst = &ksB[v][tt * 16];
        *(u32x4*)dst = *(const u32x4*)src;
        *(u32x4*)(dst + 8) = *(const u32x4*)(src + 8);
      }
    }
    __syncthreads();   // tiles ready
    #pragma unroll
    for (int s = 0; s < 3; ++s) {
      const int tidx = wid + 4 * s;
      if (tidx < 10) {
        const int mtile = tidx >> 1, ntile = tidx & 1;
        #pragma unroll
        for (int ks = 0; ks < 6; ++ks) {
          const u32x4 a = *(const u32x4*)&qsA[mtile * 16 + m16][ks * 32 + kg * 8];
          const u32x4 b = *(const u32x4*)&ksB[ntile * 16 + m16][ks * 32 + kg * 8];
          acc[s] = mfma_bf16(a, b, acc[s]);
        }
      }
    }
  }
  __syncthreads();
  #pragma unroll
  for (int s = 0; s < 3; ++s) {
    const int tidx = wid + 4 * s;
    if (tidx < 10) {
      const int mtile = tidx >> 1, ntile = tidx & 1;
      const int v = ntile * 16 + m16;
      if (v < VV) {
        #pragma unroll
        for (int i = 0; i < 4; ++i)
          att_s[mtile * 16 + kg * 4 + i][v] = acc[s][i];
      }
    }
  }
  __syncthreads();
  const float inv = 1.0f / (float)(DHD * TT);
  for (int i = tid; i < UU * VV; i += 256) {
    const int u = i / VV, v = i % VV;
    const bool m = disg[(h * VV + u % VV) * VV + v] > 0.f;
    att_s[u][v] = m ? att_s[u][v] * inv : -9e15f;
  }
  __syncthreads();
  if (tid < VV) {
    float mx = -INFINITY;
    for (int u = 0; u < UU; ++u) mx = fmaxf(mx, att_s[u][tid]);
    float sm = 0.f;
    for (int u = 0; u < UU; ++u) sm += expf(att_s[u][tid] - mx);
    mxv[tid] = mx; smv[tid] = sm;
  }
  __syncthreads();
  const float al = alpha[0];
  unsigned* dst = (unsigned*)(attP + ((size_t)(n * HH + h) * 32) * 104);
  for (int i = tid; i < 1664; i += 256) {     // 32 x 52 u32 (= 104 u16)
    const int vc = i / 52, u0 = (i % 52) * 2;
    unsigned val = 0u;
    if (vc < VV) {
      float f0 = 0.f, f1 = 0.f;
      if (u0 < UU)
        f0 = expf(att_s[u0][vc] - mxv[vc]) / smv[vc] * al
             + att0[(h * VV + u0 % VV) * VV + vc];
      if (u0 + 1 < UU)
        f1 = expf(att_s[u0 + 1][vc] - mxv[vc]) / smv[vc] * al
             + att0[(h * VV + (u0 + 1) % VV) * VV + vc];
      val = pack2(f0, f1);
    }
    dst[i] = val;
  }
}

// ---------------------------------------------------------------------------
// Kernel D v6 (R17-verbatim, passing)
// ---------------------------------------------------------------------------
__global__ __launch_bounds__(256) void k_out_mfma6(
    const float* __restrict__ x, const unsigned short* __restrict__ attP,
    const unsigned short* __restrict__ woF, const unsigned short* __restrict__ wdF,
    const float* __restrict__ b_o,
    const float* __restrict__ g_o, const float* __restrict__ be_o,
    const float* __restrict__ m_o, const float* __restrict__ v_o,
    const float* __restrict__ b_d,
    const float* __restrict__ g_d, const float* __restrict__ be_d,
    const float* __restrict__ m_d, const float* __restrict__ v_d,
    float* __restrict__ out)
{
  const int n = blockIdx.x / 30, t0 = (blockIdx.x % 30) * TCO;
  __shared__ alignas(16) char uB[28672];                   // xu2 | xsl2[2]
  __shared__ alignas(16) unsigned short attB[2][32][104];  // 13,312 B dbuf
  unsigned short* xu2 = (unsigned short*)uB;               // [(tr*64+c)*104+u]
  const int tid = threadIdx.x;
  const int lane = tid & 63, wid = tid >> 6;
  const int m16 = lane & 15, kg = lane >> 4;

  #define XSLB(b) (uB + (b) * 14336)            // [112] rows x 128B swz

  #define STAGE_XU(tb)                                                         \
    for (int i = tid; i < 2 * 64 * 48; i += 256) {                             \
      const int u0 = (i % 48) * 2, c = (i / 48) & 63, tr = i / (48 * 64);      \
      float f0 = 0.f, f1 = 0.f;                                                \
      if (u0 < UU) {                                                           \
        const int w = u0 / VV, up = u0 % VV, ts = t0 + (tb) + tr + w - 1;      \
        if (ts >= 0 && ts < TT) f0 = x[((n * 64 + c) * TT + ts) * VV + up];    \
      }                                                                        \
      if (u0 + 1 < UU) {                                                       \
        const int u = u0 + 1, w = u / VV, up = u % VV;                         \
        const int ts = t0 + (tb) + tr + w - 1;                                 \
        if (ts >= 0 && ts < TT) f1 = x[((n * 64 + c) * TT + ts) * VV + up];    \
      }                                                                        \
      *(unsigned*)(xu2 + (tr * 64 + c) * 104 + u0) = pack2(f0, f1);            \
    }

  #define STAGE_ATT(hh, buf)                                                   \
    {                                                                          \
      const u32x4* srcv =                                                      \
          (const u32x4*)(attP + ((size_t)(n * HH + (hh)) * 32) * 104);         \
      u32x4* dstv = (u32x4*)&attB[buf][0][0];                                  \
      for (int i = tid; i < 416; i += 256) dstv[i] = srcv[i];                  \
    }

  // ---- prologue: A-frags from xu2 in two 2-t chunks ----
  STAGE_XU(0);
  __syncthreads();
  u32x4 af[4][3];
  if (wid < 2) {
    #pragma unroll
    for (int mt = 0; mt < 4; ++mt)
      #pragma unroll
      for (int ks = 0; ks < 3; ++ks)
        af[mt][ks] = *(const u32x4*)(xu2 + (wid * 64 + mt * 16 + m16) * 104 +
                                     ks * 32 + kg * 8);
  }
  __syncthreads();   // chunk-1 reads drained before overwrite
  STAGE_XU(2);
  STAGE_ATT(0, 0);
  __syncthreads();
  if (wid >= 2) {
    #pragma unroll
    for (int mt = 0; mt < 4; ++mt)
      #pragma unroll
      for (int ks = 0; ks < 3; ++ks)
        af[mt][ks] = *(const u32x4*)(xu2 + ((wid - 2) * 64 + mt * 16 + m16) * 104 +
                                     ks * 32 + kg * 8);
  }
  __syncthreads();   // FENCE: all xu2 reads drained; uB becomes xsl2
  for (int i = tid; i < 2 * 12 * 64; i += 256) {
    const int b = i / (12 * 64), r = i % (12 * 64);
    *(unsigned short*)(XSLB(b) + (100 + (r >> 6)) * 128 + ((r & 63) * 2)) = 0;
  }

  f32x4 acc2[2][7];
  #pragma unroll
  for (int mt = 0; mt < 2; ++mt)
    #pragma unroll
    for (int nt = 0; nt < 7; ++nt) acc2[mt][nt] = (f32x4)0.f;

  for (int h = 0; h <= HH; ++h) {
    const int pb = h & 1;
    char* xs = XSLB(pb);
    u32x4 a2[2][2];
    #pragma unroll
    for (int mt = 0; mt < 2; ++mt) {
      const int d = wid * 32 + mt * 16 + m16;
      #pragma unroll
      for (int ks = 0; ks < 2; ++ks) {
        const unsigned short* src = (h < HH)
            ? (woF + ((((h * 2 + ks) * 4 + kg) * 128 + d) << 3))
            : (wdF + ((((ks) * 4 + kg) * 128 + d) << 3));
        a2[mt][ks] = *(const u32x4*)src;
      }
    }
    if (h + 1 < HH) { STAGE_ATT(h + 1, (h + 1) & 1); }
    f32x4 a1[4][2];
    if (h < HH) {
      u32x4 bfr[2][3];
      #pragma unroll
      for (int nt = 0; nt < 2; ++nt)
        #pragma unroll
        for (int ks = 0; ks < 3; ++ks)
          bfr[nt][ks] =
              *(const u32x4*)&attB[pb][nt * 16 + m16][ks * 32 + kg * 8];
      #pragma unroll
      for (int mt = 0; mt < 4; ++mt)
        #pragma unroll
        for (int nt = 0; nt < 2; ++nt) {
          a1[mt][nt] = (f32x4)0.f;
          #pragma unroll
          for (int ks = 0; ks < 3; ++ks)
            a1[mt][nt] = mfma_bf16(af[mt][ks], bfr[nt][ks], a1[mt][nt]);
        }
    }
    if (h < HH) {
      #pragma unroll
      for (int mt = 0; mt < 4; ++mt)
        #pragma unroll
        for (int nt = 0; nt < 2; ++nt) {
          const int v = nt * 16 + m16;
          if (v < VV) {
            const int tv = wid * VV + v;
            const int c0 = mt * 16 + kg * 4;
            u32x2 pk;
            pk[0] = pack2(a1[mt][nt][0], a1[mt][nt][1]);
            pk[1] = pack2(a1[mt][nt][2], a1[mt][nt][3]);
            char* p = xs + tv * 128 + ((c0 * 2) ^ ((tv & 7) << 4));
            *(u32x2*)p = pk;
          }
        }
    } else {
      for (int i = tid; i < 6400; i += 256) {
        const int c = i / 100, j = i % 100;
        const float f = x[((size_t)(n * 64 + c) * TT + t0) * VV + j];
        *(unsigned short*)(xs + j * 128 + ((c * 2) ^ ((j & 7) << 4))) =
            f2bu(f);
      }
    }
    __syncthreads();   // single barrier: xs writes(pb) -> reads(pb)
    #pragma unroll
    for (int nt = 0; nt < 7; ++nt) {
      const int tv = nt * 16 + m16;
      const u32x4 b0 = *(const u32x4*)(xs + tv * 128 +
                        (((kg * 8) * 2) ^ ((tv & 7) << 4)));
      const u32x4 b1 = *(const u32x4*)(xs + tv * 128 +
                        (((32 + kg * 8) * 2) ^ ((tv & 7) << 4)));
      #pragma unroll
      for (int mt = 0; mt < 2; ++mt) {
        acc2[mt][nt] = mfma_bf16(a2[mt][0], b0, acc2[mt][nt]);
        acc2[mt][nt] = mfma_bf16(a2[mt][1], b1, acc2[mt][nt]);
      }
    }
  }

  #pragma unroll
  for (int mt = 0; mt < 2; ++mt) {
    float cc[4];
    #pragma unroll
    for (int i = 0; i < 4; ++i) {
      const int d = wid * 32 + mt * 16 + kg * 4 + i;
      const float so2 = g_o[d] * rsqrtf(v_o[d] + 1e-5f);
      const float sd2 = g_d[d] * rsqrtf(v_d[d] + 1e-5f);
      cc[i] = b_o[d] * so2 + be_o[d] - m_o[d] * so2
            + b_d[d] * sd2 + be_d[d] - m_d[d] * sd2;
    }
    #pragma unroll
    for (int nt = 0; nt < 7; ++nt) {
      const int tv = nt * 16 + m16;
      if (tv < 100) {
        const int t = t0 + tv / VV, v = tv % VV;
        #pragma unroll
        for (int i = 0; i < 4; ++i) {
          const int d = wid * 32 + mt * 16 + kg * 4 + i;
          const float z = acc2[mt][nt][i] + cc[i];
          out[((n * DIMD + d) * TT + t) * VV + v] = (z >= 0.f) ? z : 0.1f * z;
        }
      }
    }
  }
  #undef STAGE_XU
  #undef STAGE_ATT
  #undef XSLB
}

// ---------------------------------------------------------------------------
extern "C" void kernel_launch(void* const* d_in, const int* in_sizes, int n_in,
                              void* d_out, int out_size, void* d_ws, size_t ws_size,
                              hipStream_t stream)
{
  (void)in_sizes; (void)n_in; (void)out_size; (void)ws_size;
  const float* x     = (const float*)d_in[0];
  const float* Wq    = (const float*)d_in[1];
  const float* bq    = (const float*)d_in[2];
  const float* Wk    = (const float*)d_in[3];
  const float* bk    = (const float*)d_in[4];
  const float* We    = (const float*)d_in[5];
  const float* be    = (const float*)d_in[6];
  const float* G     = (const float*)d_in[7];
  const float* sepe  = (const float*)d_in[8];
  const float* att0  = (const float*)d_in[9];
  const float* alpha = (const float*)d_in[10];
  const float* beta  = (const float*)d_in[11];
  const float* Wo    = (const float*)d_in[12];
  const float* b_o   = (const float*)d_in[13];
  const float* g_o   = (const float*)d_in[14];
  const float* be_o  = (const float*)d_in[15];
  const float* m_o   = (const float*)d_in[16];
  const float* v_o   = (const float*)d_in[17];
  const float* Wd    = (const float*)d_in[18];
  const float* b_d   = (const float*)d_in[19];
  const float* g_d   = (const float*)d_in[20];
  const float* be_d  = (const float*)d_in[21];
  const float* m_d   = (const float*)d_in[22];
  const float* v_d   = (const float*)d_in[23];
  const int*   dism  = (const int*)d_in[24];
  const float* disg  = (const float*)d_in[25];

  // Workspace: qyT @0 (49.152 MB), kkT @49,152,000, attP @98,304,000 (3.41 MB),
  // packed weights @101,711,872: woF 131072B, wdF/wqF/wkF/weF 16384B each.
  char* ws = (char*)d_ws;
  unsigned short* qyT  = (unsigned short*)(ws);
  unsigned short* kkT  = (unsigned short*)(ws + 49152000);
  unsigned short* attP = (unsigned short*)(ws + 98304000);
  unsigned short* woF  = (unsigned short*)(ws + 101711872);
  unsigned short* wdF  = (unsigned short*)(ws + 101842944);
  unsigned short* wqF  = (unsigned short*)(ws + 101859328);
  unsigned short* wkF  = (unsigned short*)(ws + 101875712);
  unsigned short* weF  = (unsigned short*)(ws + 101892096);

  k_pack_w<<<384, 256, 0, stream>>>(Wo, g_o, v_o, Wd, g_d, v_d,
                                    Wq, Wk, We, beta,
                                    woF, wdF, wqF, wkF, weF);
  k_qke_mfma7t<<<NB * 30, 256, 0, stream>>>(x, wqF, bq, wkF, bk, weF, be,
                                            G, beta, sepe, dism, qyT, kkT);
  k_att_mfma2<<<NB * HH, 256, 0, stream>>>(qyT, kkT, bq, disg, att0, alpha, attP);
  k_out_mfma6<<<NB * 30, 256, 0, stream>>>(x, attP, woF, wdF,
                                           b_o, g_o, be_o, m_o, v_o,
                                           b_d, g_d, be_d, m_d, v_d,
                                           (float*)d_out);
}

// Round 21
// 407.545 us; speedup vs baseline: 1.1754x; 1.0543x over previous
//
#include <hip/hip_runtime.h>
#include <hip/hip_bf16.h>
#include <math.h>

// Problem constants (fixed by the reference)
#define NB   64     // batch
#define CIN  64     // input channels
#define DIMD 128    // q/k/e channels
#define TT   120    // time
#define VV   25     // joints
#define HH   8      // heads
#define DHD  16     // DIM/H
#define WW   3      // temporal window
#define UU   75     // W*V
#define TC2  12     // t-chunk in MFMA attention kernel (120 = 10*12)
#define TCO  4      // t-chunk in output kernel (120 = 4*30)

typedef __hip_bfloat16 bf16;
typedef float        f32x4  __attribute__((ext_vector_type(4)));
typedef unsigned int u32x4  __attribute__((ext_vector_type(4)));
typedef unsigned int u32x2  __attribute__((ext_vector_type(2)));
typedef __bf16       bf16x8 __attribute__((ext_vector_type(8)));

__device__ __forceinline__ float b2f(bf16 v)  { return __bfloat162float(v); }
__device__ __forceinline__ bf16  f2b(float v) { return __float2bfloat16(v); }

__device__ __forceinline__ unsigned short f2bu(float f) {
  unsigned u = __builtin_bit_cast(unsigned, f);
  return (unsigned short)((u + 0x7fffu + ((u >> 16) & 1u)) >> 16);  // RNE
}
__device__ __forceinline__ float bfu(unsigned short s) {
  unsigned u = ((unsigned)s) << 16;
  return __builtin_bit_cast(float, u);
}
__device__ __forceinline__ unsigned pack2(float a, float b) {
  return ((unsigned)f2bu(b) << 16) | (unsigned)f2bu(a);
}

// BUILTIN MFMA (R11 lesson: asm-wrapped MFMA is invisible to the GCN hazard
// recognizer -> missing MFMA->VALU wait-states -> silent corruption).
__device__ __forceinline__ f32x4 mfma_bf16(u32x4 a, u32x4 b, f32x4 d) {
  return __builtin_amdgcn_mfma_f32_16x16x32_bf16(
      __builtin_bit_cast(bf16x8, a), __builtin_bit_cast(bf16x8, b), d, 0, 0, 0);
}

// ---------------------------------------------------------------------------
// Pre-pack kernel: weights -> fragment-ordered bf16 tensors (scales folded).
//   woF[h][ks][kg][d][8] = so[d]*Wo[d][h*64+c]   (65536 u16)
//   wdF[ks][kg][d][8]    = sd[d]*Wd[d][c]        ( 8192 u16)
//   wqF/wkF[ks][kg][d][8]= Wq/Wk[d][c]           ( 8192 each)
//   weF[ks][kg][d][8]    = beta*We[d][c]         ( 8192)
// c = ks*32 + kg*8 + j. Frag load = 1 u32x4, 256B-contig per 16-lane group.
// ---------------------------------------------------------------------------
__global__ __launch_bounds__(256) void k_pack_w(
    const float* __restrict__ Wo, const float* __restrict__ g_o,
    const float* __restrict__ v_o,
    const float* __restrict__ Wd, const float* __restrict__ g_d,
    const float* __restrict__ v_d,
    const float* __restrict__ Wq, const float* __restrict__ Wk,
    const float* __restrict__ We, const float* __restrict__ beta,
    unsigned short* __restrict__ woF, unsigned short* __restrict__ wdF,
    unsigned short* __restrict__ wqF, unsigned short* __restrict__ wkF,
    unsigned short* __restrict__ weF)
{
  const int i = blockIdx.x * 256 + threadIdx.x;   // grid covers 98304
  if (i < 65536) {                                 // woF
    const int j = i & 7, d = (i >> 3) & 127, kg = (i >> 10) & 3;
    const int ks = (i >> 12) & 1, h = (i >> 13) & 7;
    const float sc = g_o[d] * rsqrtf(v_o[d] + 1e-5f);
    woF[i] = f2bu(sc * Wo[d * 512 + h * 64 + ks * 32 + kg * 8 + j]);
  } else {
    const int r = i - 65536;                       // 0..32767
    const int which = r >> 13;                     // 0=wd 1=wq 2=wk 3=we
    const int l = r & 8191;
    const int j = l & 7, d = (l >> 3) & 127, kg = (l >> 10) & 3;
    const int ks = (l >> 12) & 1;
    const int c = ks * 32 + kg * 8 + j;
    if (which == 0) {
      const float sc = g_d[d] * rsqrtf(v_d[d] + 1e-5f);
      wdF[l] = f2bu(sc * Wd[d * 64 + c]);
    } else if (which == 1) {
      wqF[l] = f2bu(Wq[d * 64 + c]);
    } else if (which == 2) {
      wkF[l] = f2bu(Wk[d * 64 + c]);
    } else {
      weF[l] = f2bu(beta[0] * We[d * 64 + c]);
    }
  }
}

// ---------------------------------------------------------------------------
// Fused A+B v7: frag loads from pre-packed tensors (coalesced, no pack VALU).
// ---------------------------------------------------------------------------
__global__ __launch_bounds__(256, 3) void k_qke_mfma7(
    const float* __restrict__ x,
    const unsigned short* __restrict__ wqF, const float* __restrict__ bq,
    const unsigned short* __restrict__ wkF, const float* __restrict__ bk,
    const unsigned short* __restrict__ weF, const float* __restrict__ be,
    const float* __restrict__ G,  const float* __restrict__ beta,
    const float* __restrict__ se_pe, const int* __restrict__ dis,
    bf16* __restrict__ qy, bf16* __restrict__ kkp)
{
  const int n = blockIdx.x / 30, t0 = (blockIdx.x % 30) * 4;
  __shared__ alignas(16) char uA[26624];                 // xl | yTG
  __shared__ alignas(16) unsigned short yT[112][64];     // [tv][c] swz
  __shared__ alignas(16) float spl[5][64];
  __shared__ alignas(16) int   dml[25][25];
  __shared__ alignas(16) float Gl[25][26];
  __shared__ alignas(16) float gsum[32];
  __shared__ alignas(16) float biasb[384];               // bq|bk|be

  float* xl  = (float*)uA;                               // [4][64][26] f32
  char*  yTG = uA;                                       // [112] x 128B swz
  #define XL(t, c, v) xl[(((t) * 64 + (c)) * 26) + (v)]

  const int tid = threadIdx.x;
  {
    const float* xb = x + (size_t)n * 192000 + t0 * 25;  // x[n][c][t0+t][v]
    for (int i = tid; i < 6400; i += 256) {
      const int c = i / 100, j = i % 100, t = j / 25, v = j % 25;
      XL(t, c, v) = xb[c * 3000 + j];
    }
  }
  for (int i = tid; i < 320; i += 256) spl[i / 64][i % 64] = se_pe[i];
  for (int i = tid; i < 625; i += 256) dml[i / 25][i % 25] = dis[i];
  for (int i = tid; i < 625; i += 256) Gl[i / 25][i % 25] = G[i];
  if (tid < 25) {
    float s = 0.f;
    for (int u = 0; u < 25; ++u) s += G[u * 25 + tid];
    gsum[tid] = s;
  }
  for (int i = tid; i < 384; i += 256)
    biasb[i] = (i < 128) ? bq[i] : (i < 256 ? bk[i - 128] : be[i - 256]);
  for (int i = tid; i < 12 * 64; i += 256)               // yT junk rows -> 0
    yT[100 + (i >> 6)][i & 63] = 0;
  __syncthreads();

  const int lane = tid & 63, wid = tid >> 6;
  const int m16 = lane & 15, kg = lane >> 4;

  // coalesced frag load from pre-packed [ks][kg][d][8] tensor
  #define LOAD_PFRAGS(af, Fsrc)                                                \
    _Pragma("unroll")                                                          \
    for (int mt = 0; mt < 2; ++mt) {                                           \
      const int d_ = wid * 32 + mt * 16 + m16;                                 \
      _Pragma("unroll")                                                        \
      for (int ks = 0; ks < 2; ++ks)                                           \
        af[mt][ks] = *(const u32x4*)((Fsrc) +                                  \
                      (((ks * 4 + kg) * 128 + d_) << 3));                      \
    }

  // ---- phase 1: yT = x + pe + struct-enc ----
  for (int idx = tid; idx < 6400; idx += 256) {
    const int c = idx & 63, tv = idx >> 6;
    const int t = tv / 25, v = tv % 25;
    const float dv = expf(-(float)(c & ~1) * (logf(10000.0f) / 64.0f));
    float acc = XL(t, c, v) +
                ((c & 1) ? cosf((float)v * dv) : sinf((float)v * dv));
    #pragma unroll
    for (int u = 0; u < 25; ++u)
      acc = fmaf(XL(t, c, u), spl[dml[u][v]][c], acc);
    *(unsigned short*)((char*)yT + tv * 128 + ((c * 2) ^ ((tv & 7) << 4))) =
        f2bu(acc);
  }
  __syncthreads();   // yT ready; xl DEAD (uA becomes yTG)

  // ---- phase 1b: yTG = y @ G ----
  for (int i = tid; i < 12 * 64; i += 256)
    *(unsigned short*)(yTG + (100 + (i >> 6)) * 128 + ((i & 63) * 2)) = 0;
  for (int idx = tid; idx < 6400; idx += 256) {
    const int c = idx & 63, tv = idx >> 6;
    const int t = tv / 25, v = tv % 25;
    float acc = 0.f;
    #pragma unroll
    for (int u = 0; u < 25; ++u) {
      const int ru = t * 25 + u;
      const float yv = bfu(*(const unsigned short*)((const char*)yT + ru * 128 +
                            ((c * 2) ^ ((ru & 7) << 4))));
      acc = fmaf(yv, Gl[u][v], acc);
    }
    *(unsigned short*)(yTG + tv * 128 + ((c * 2) ^ ((tv & 7) << 4))) =
        f2bu(acc);
  }
  __syncthreads();   // yTG ready — LAST barrier; GEMMs are straight-line

  bf16* qyb = qy  + (size_t)n * 384000 + t0 * 25;
  bf16* kkb = kkp + (size_t)n * 384000 + t0 * 25;
  const float betav = beta[0];

  // ---- q-GEMM ----
  {
    u32x4 aq[2][2];
    LOAD_PFRAGS(aq, wqF);
    for (int nt = 0; nt < 7; ++nt) {
      const int tv = nt * 16 + m16;
      const u32x4 b0 = *(const u32x4*)((const char*)yT + tv * 128 +
                        (((kg * 8) * 2) ^ ((tv & 7) << 4)));
      const u32x4 b1 = *(const u32x4*)((const char*)yT + tv * 128 +
                        (((32 + kg * 8) * 2) ^ ((tv & 7) << 4)));
      #pragma unroll
      for (int mt = 0; mt < 2; ++mt) {
        f32x4 acc = (f32x4)0.f;
        acc = mfma_bf16(aq[mt][0], b0, acc);
        acc = mfma_bf16(aq[mt][1], b1, acc);
        if (tv < 100) {
          const int dr = wid * 32 + mt * 16 + kg * 4;
          #pragma unroll
          for (int i2 = 0; i2 < 4; ++i2)
            qyb[(size_t)(dr + i2) * 3000 + tv] = f2b(acc[i2] + biasb[dr + i2]);
        }
      }
    }
  }

  // ---- k-GEMM into persistent kacc ----
  f32x4 kacc[2][7];
  #pragma unroll
  for (int mt = 0; mt < 2; ++mt)
    #pragma unroll
    for (int nt = 0; nt < 7; ++nt) kacc[mt][nt] = (f32x4)0.f;
  {
    u32x4 ak[2][2];
    LOAD_PFRAGS(ak, wkF);
    for (int nt = 0; nt < 7; ++nt) {
      const int tv = nt * 16 + m16;
      const u32x4 b0 = *(const u32x4*)((const char*)yT + tv * 128 +
                        (((kg * 8) * 2) ^ ((tv & 7) << 4)));
      const u32x4 b1 = *(const u32x4*)((const char*)yT + tv * 128 +
                        (((32 + kg * 8) * 2) ^ ((tv & 7) << 4)));
      #pragma unroll
      for (int mt = 0; mt < 2; ++mt) {
        kacc[mt][nt] = mfma_bf16(ak[mt][0], b0, kacc[mt][nt]);
        kacc[mt][nt] = mfma_bf16(ak[mt][1], b1, kacc[mt][nt]);
      }
    }
  }

  // ---- e-GEMM (beta pre-folded in weF) on yTG, accumulate, store kk ----
  {
    u32x4 ae[2][2];
    LOAD_PFRAGS(ae, weF);
    for (int nt = 0; nt < 7; ++nt) {
      const int tv = nt * 16 + m16;
      const u32x4 b0 = *(const u32x4*)(yTG + tv * 128 +
                        (((kg * 8) * 2) ^ ((tv & 7) << 4)));
      const u32x4 b1 = *(const u32x4*)(yTG + tv * 128 +
                        (((32 + kg * 8) * 2) ^ ((tv & 7) << 4)));
      #pragma unroll
      for (int mt = 0; mt < 2; ++mt) {
        kacc[mt][nt] = mfma_bf16(ae[mt][0], b0, kacc[mt][nt]);
        kacc[mt][nt] = mfma_bf16(ae[mt][1], b1, kacc[mt][nt]);
        if (tv < 100) {
          const int vv = tv % 25;
          const int dr = wid * 32 + mt * 16 + kg * 4;
          #pragma unroll
          for (int i2 = 0; i2 < 4; ++i2)
            kkb[(size_t)(dr + i2) * 3000 + tv] =
                f2b(kacc[mt][nt][i2] + biasb[128 + dr + i2] +
                    betav * biasb[256 + dr + i2] * gsum[vv]);
        }
      }
    }
  }
  #undef LOAD_PFRAGS
  #undef XL
}

// ---------------------------------------------------------------------------
// Kernel C v2 (R16-verbatim, passing): MFMA attention -> padded attP
// ---------------------------------------------------------------------------
__global__ __launch_bounds__(256) void k_att_mfma(
    const bf16* __restrict__ qy, const bf16* __restrict__ kkp,
    const float* __restrict__ bq, const float* __restrict__ disg,
    const float* __restrict__ att0, const float* __restrict__ alpha,
    unsigned short* __restrict__ attP)
{
  const int n = blockIdx.x / HH, h = blockIdx.x % HH;
  __shared__ alignas(16) unsigned short qsA[80][200];  // [u][k] bf16 bits
  __shared__ alignas(16) unsigned short ksB[32][200];  // [v][k] bf16 bits
  __shared__ alignas(16) float att_s[80][28];
  __shared__ float mxv[32], smv[32];
  const int tid = threadIdx.x;
  const int lane = tid & 63, wid = tid >> 6;
  const int m16 = lane & 15, kg = lane >> 4;

  const unsigned short* qyb =
      (const unsigned short*)(qy + ((size_t)(n * DIMD + h * DHD)) * TT * VV);
  const unsigned short* kkb =
      (const unsigned short*)(kkp + ((size_t)(n * DIMD + h * DHD)) * TT * VV);

  f32x4 acc[3];
  #pragma unroll
  for (int s = 0; s < 3; ++s) acc[s] = (f32x4)0.f;

  for (int c = 0; c < 10; ++c) {
    const int t0 = c * TC2;
    __syncthreads();   // prev chunk's frag reads drained
    for (int it = tid; it < 416; it += 256) {
      if (it < 224) {
        const int dh = it / 14, j = it % 14, tq = t0 + j - 1;
        unsigned short vals[25];
        if (tq >= 0 && tq < TT) {
          const unsigned short* src = qyb + ((size_t)dh * TT + tq) * VV;
          #pragma unroll
          for (int u = 0; u < 25; ++u) vals[u] = src[u];
        } else {
          const unsigned short bqv = f2bu(bq[h * DHD + dh]);
          #pragma unroll
          for (int u = 0; u < 25; ++u) vals[u] = bqv;
        }
        #pragma unroll
        for (int w = 0; w < 3; ++w) {
          const int tt = tq - t0 - w + 1;
          if (tt >= 0 && tt < TC2) {
            const int col = tt * 16 + dh;
            #pragma unroll
            for (int u = 0; u < 25; ++u) qsA[w * 25 + u][col] = vals[u];
          }
        }
      } else {
        const int r = it - 224, dh = r / TC2, tt = r % TC2;
        const unsigned short* src = kkb + ((size_t)dh * TT + t0 + tt) * VV;
        const int col = tt * 16 + dh;
        #pragma unroll
        for (int v = 0; v < 25; ++v) ksB[v][col] = src[v];
      }
    }
    __syncthreads();   // tiles ready
    #pragma unroll
    for (int s = 0; s < 3; ++s) {
      const int tidx = wid + 4 * s;
      if (tidx < 10) {
        const int mtile = tidx >> 1, ntile = tidx & 1;
        #pragma unroll
        for (int ks = 0; ks < 6; ++ks) {
          const u32x4 a = *(const u32x4*)&qsA[mtile * 16 + m16][ks * 32 + kg * 8];
          const u32x4 b = *(const u32x4*)&ksB[ntile * 16 + m16][ks * 32 + kg * 8];
          acc[s] = mfma_bf16(a, b, acc[s]);
        }
      }
    }
  }
  __syncthreads();
  #pragma unroll
  for (int s = 0; s < 3; ++s) {
    const int tidx = wid + 4 * s;
    if (tidx < 10) {
      const int mtile = tidx >> 1, ntile = tidx & 1;
      const int v = ntile * 16 + m16;
      if (v < VV) {
        #pragma unroll
        for (int i = 0; i < 4; ++i)
          att_s[mtile * 16 + kg * 4 + i][v] = acc[s][i];
      }
    }
  }
  __syncthreads();
  const float inv = 1.0f / (float)(DHD * TT);
  for (int i = tid; i < UU * VV; i += 256) {
    const int u = i / VV, v = i % VV;
    const bool m = disg[(h * VV + u % VV) * VV + v] > 0.f;
    att_s[u][v] = m ? att_s[u][v] * inv : -9e15f;
  }
  __syncthreads();
  if (tid < VV) {
    float mx = -INFINITY;
    for (int u = 0; u < UU; ++u) mx = fmaxf(mx, att_s[u][tid]);
    float sm = 0.f;
    for (int u = 0; u < UU; ++u) sm += expf(att_s[u][tid] - mx);
    mxv[tid] = mx; smv[tid] = sm;
  }
  __syncthreads();
  const float al = alpha[0];
  unsigned* dst = (unsigned*)(attP + ((size_t)(n * HH + h) * 32) * 104);
  for (int i = tid; i < 1664; i += 256) {     // 32 x 52 u32 (= 104 u16)
    const int vc = i / 52, u0 = (i % 52) * 2;
    unsigned val = 0u;
    if (vc < VV) {
      float f0 = 0.f, f1 = 0.f;
      if (u0 < UU)
        f0 = expf(att_s[u0][vc] - mxv[vc]) / smv[vc] * al
             + att0[(h * VV + u0 % VV) * VV + vc];
      if (u0 + 1 < UU)
        f1 = expf(att_s[u0 + 1][vc] - mxv[vc]) / smv[vc] * al
             + att0[(h * VV + (u0 + 1) % VV) * VV + vc];
      val = pack2(f0, f1);
    }
    dst[i] = val;
  }
}

// ---------------------------------------------------------------------------
// Kernel D v6: a2 frags from pre-packed woF/wdF (coalesced, scales folded).
// ---------------------------------------------------------------------------
__global__ __launch_bounds__(256) void k_out_mfma6(
    const float* __restrict__ x, const unsigned short* __restrict__ attP,
    const unsigned short* __restrict__ woF, const unsigned short* __restrict__ wdF,
    const float* __restrict__ b_o,
    const float* __restrict__ g_o, const float* __restrict__ be_o,
    const float* __restrict__ m_o, const float* __restrict__ v_o,
    const float* __restrict__ b_d,
    const float* __restrict__ g_d, const float* __restrict__ be_d,
    const float* __restrict__ m_d, const float* __restrict__ v_d,
    float* __restrict__ out)
{
  const int n = blockIdx.x / 30, t0 = (blockIdx.x % 30) * TCO;
  __shared__ alignas(16) char uB[28672];                   // xu2 | xsl2[2]
  __shared__ alignas(16) unsigned short attB[2][32][104];  // 13,312 B dbuf
  unsigned short* xu2 = (unsigned short*)uB;               // [(tr*64+c)*104+u]
  const int tid = threadIdx.x;
  const int lane = tid & 63, wid = tid >> 6;
  const int m16 = lane & 15, kg = lane >> 4;

  #define XSLB(b) (uB + (b) * 14336)            // [112] rows x 128B swz

  #define STAGE_XU(tb)                                                         \
    for (int i = tid; i < 2 * 64 * 48; i += 256) {                             \
      const int u0 = (i % 48) * 2, c = (i / 48) & 63, tr = i / (48 * 64);      \
      float f0 = 0.f, f1 = 0.f;                                                \
      if (u0 < UU) {                                                           \
        const int w = u0 / VV, up = u0 % VV, ts = t0 + (tb) + tr + w - 1;      \
        if (ts >= 0 && ts < TT) f0 = x[((n * 64 + c) * TT + ts) * VV + up];    \
      }                                                                        \
      if (u0 + 1 < UU) {                                                       \
        const int u = u0 + 1, w = u / VV, up = u % VV;                         \
        const int ts = t0 + (tb) + tr + w - 1;                                 \
        if (ts >= 0 && ts < TT) f1 = x[((n * 64 + c) * TT + ts) * VV + up];    \
      }                                                                        \
      *(unsigned*)(xu2 + (tr * 64 + c) * 104 + u0) = pack2(f0, f1);            \
    }

  #define STAGE_ATT(hh, buf)                                                   \
    {                                                                          \
      const u32x4* srcv =                                                      \
          (const u32x4*)(attP + ((size_t)(n * HH + (hh)) * 32) * 104);         \
      u32x4* dstv = (u32x4*)&attB[buf][0][0];                                  \
      for (int i = tid; i < 416; i += 256) dstv[i] = srcv[i];                  \
    }

  // ---- prologue: A-frags from xu2 in two 2-t chunks ----
  STAGE_XU(0);
  __syncthreads();
  u32x4 af[4][3];
  if (wid < 2) {
    #pragma unroll
    for (int mt = 0; mt < 4; ++mt)
      #pragma unroll
      for (int ks = 0; ks < 3; ++ks)
        af[mt][ks] = *(const u32x4*)(xu2 + (wid * 64 + mt * 16 + m16) * 104 +
                                     ks * 32 + kg * 8);
  }
  __syncthreads();   // chunk-1 reads drained before overwrite
  STAGE_XU(2);
  STAGE_ATT(0, 0);
  __syncthreads();
  if (wid >= 2) {
    #pragma unroll
    for (int mt = 0; mt < 4; ++mt)
      #pragma unroll
      for (int ks = 0; ks < 3; ++ks)
        af[mt][ks] = *(const u32x4*)(xu2 + ((wid - 2) * 64 + mt * 16 + m16) * 104 +
                                     ks * 32 + kg * 8);
  }
  __syncthreads();   // FENCE: all xu2 reads drained; uB becomes xsl2
  for (int i = tid; i < 2 * 12 * 64; i += 256) {
    const int b = i / (12 * 64), r = i % (12 * 64);
    *(unsigned short*)(XSLB(b) + (100 + (r >> 6)) * 128 + ((r & 63) * 2)) = 0;
  }

  f32x4 acc2[2][7];
  #pragma unroll
  for (int mt = 0; mt < 2; ++mt)
    #pragma unroll
    for (int nt = 0; nt < 7; ++nt) acc2[mt][nt] = (f32x4)0.f;

  for (int h = 0; h <= HH; ++h) {
    const int pb = h & 1;
    char* xs = XSLB(pb);
    // stage2 A-frags from pre-packed tensors (coalesced; scales folded)
    u32x4 a2[2][2];
    #pragma unroll
    for (int mt = 0; mt < 2; ++mt) {
      const int d = wid * 32 + mt * 16 + m16;
      #pragma unroll
      for (int ks = 0; ks < 2; ++ks) {
        const unsigned short* src = (h < HH)
            ? (woF + ((((h * 2 + ks) * 4 + kg) * 128 + d) << 3))
            : (wdF + ((((ks) * 4 + kg) * 128 + d) << 3));
        a2[mt][ks] = *(const u32x4*)src;
      }
    }
    if (h + 1 < HH) { STAGE_ATT(h + 1, (h + 1) & 1); }
    f32x4 a1[4][2];
    if (h < HH) {
      u32x4 bfr[2][3];
      #pragma unroll
      for (int nt = 0; nt < 2; ++nt)
        #pragma unroll
        for (int ks = 0; ks < 3; ++ks)
          bfr[nt][ks] =
              *(const u32x4*)&attB[pb][nt * 16 + m16][ks * 32 + kg * 8];
      #pragma unroll
      for (int mt = 0; mt < 4; ++mt)
        #pragma unroll
        for (int nt = 0; nt < 2; ++nt) {
          a1[mt][nt] = (f32x4)0.f;
          #pragma unroll
          for (int ks = 0; ks < 3; ++ks)
            a1[mt][nt] = mfma_bf16(af[mt][ks], bfr[nt][ks], a1[mt][nt]);
        }
    }
    if (h < HH) {
      #pragma unroll
      for (int mt = 0; mt < 4; ++mt)
        #pragma unroll
        for (int nt = 0; nt < 2; ++nt) {
          const int v = nt * 16 + m16;
          if (v < VV) {
            const int tv = wid * VV + v;
            const int c0 = mt * 16 + kg * 4;
            u32x2 pk;
            pk[0] = pack2(a1[mt][nt][0], a1[mt][nt][1]);
            pk[1] = pack2(a1[mt][nt][2], a1[mt][nt][3]);
            char* p = xs + tv * 128 + ((c0 * 2) ^ ((tv & 7) << 4));
            *(u32x2*)p = pk;
          }
        }
    } else {
      for (int i = tid; i < 6400; i += 256) {
        const int c = i / 100, j = i % 100;
        const float f = x[((size_t)(n * 64 + c) * TT + t0) * VV + j];
        *(unsigned short*)(xs + j * 128 + ((c * 2) ^ ((j & 7) << 4))) =
            f2bu(f);
      }
    }
    __syncthreads();   // single barrier: xs writes(pb) -> reads(pb)
    #pragma unroll
    for (int nt = 0; nt < 7; ++nt) {
      const int tv = nt * 16 + m16;
      const u32x4 b0 = *(const u32x4*)(xs + tv * 128 +
                        (((kg * 8) * 2) ^ ((tv & 7) << 4)));
      const u32x4 b1 = *(const u32x4*)(xs + tv * 128 +
                        (((32 + kg * 8) * 2) ^ ((tv & 7) << 4)));
      #pragma unroll
      for (int mt = 0; mt < 2; ++mt) {
        acc2[mt][nt] = mfma_bf16(a2[mt][0], b0, acc2[mt][nt]);
        acc2[mt][nt] = mfma_bf16(a2[mt][1], b1, acc2[mt][nt]);
      }
    }
  }

  #pragma unroll
  for (int mt = 0; mt < 2; ++mt) {
    float cc[4];
    #pragma unroll
    for (int i = 0; i < 4; ++i) {
      const int d = wid * 32 + mt * 16 + kg * 4 + i;
      const float so2 = g_o[d] * rsqrtf(v_o[d] + 1e-5f);
      const float sd2 = g_d[d] * rsqrtf(v_d[d] + 1e-5f);
      cc[i] = b_o[d] * so2 + be_o[d] - m_o[d] * so2
            + b_d[d] * sd2 + be_d[d] - m_d[d] * sd2;
    }
    #pragma unroll
    for (int nt = 0; nt < 7; ++nt) {
      const int tv = nt * 16 + m16;
      if (tv < 100) {
        const int t = t0 + tv / VV, v = tv % VV;
        #pragma unroll
        for (int i = 0; i < 4; ++i) {
          const int d = wid * 32 + mt * 16 + kg * 4 + i;
          const float z = acc2[mt][nt][i] + cc[i];
          out[((n * DIMD + d) * TT + t) * VV + v] = (z >= 0.f) ? z : 0.1f * z;
        }
      }
    }
  }
  #undef STAGE_XU
  #undef STAGE_ATT
  #undef XSLB
}

// ---------------------------------------------------------------------------
extern "C" void kernel_launch(void* const* d_in, const int* in_sizes, int n_in,
                              void* d_out, int out_size, void* d_ws, size_t ws_size,
                              hipStream_t stream)
{
  (void)in_sizes; (void)n_in; (void)out_size; (void)ws_size;
  const float* x     = (const float*)d_in[0];
  const float* Wq    = (const float*)d_in[1];
  const float* bq    = (const float*)d_in[2];
  const float* Wk    = (const float*)d_in[3];
  const float* bk    = (const float*)d_in[4];
  const float* We    = (const float*)d_in[5];
  const float* be    = (const float*)d_in[6];
  const float* G     = (const float*)d_in[7];
  const float* sepe  = (const float*)d_in[8];
  const float* att0  = (const float*)d_in[9];
  const float* alpha = (const float*)d_in[10];
  const float* beta  = (const float*)d_in[11];
  const float* Wo    = (const float*)d_in[12];
  const float* b_o   = (const float*)d_in[13];
  const float* g_o   = (const float*)d_in[14];
  const float* be_o  = (const float*)d_in[15];
  const float* m_o   = (const float*)d_in[16];
  const float* v_o   = (const float*)d_in[17];
  const float* Wd    = (const float*)d_in[18];
  const float* b_d   = (const float*)d_in[19];
  const float* g_d   = (const float*)d_in[20];
  const float* be_d  = (const float*)d_in[21];
  const float* m_d   = (const float*)d_in[22];
  const float* v_d   = (const float*)d_in[23];
  const int*   dism  = (const int*)d_in[24];
  const float* disg  = (const float*)d_in[25];

  // Workspace: qy @0 (49.152 MB), kk @49,152,000, attP @98,304,000 (3.41 MB),
  // packed weights @101,711,872: woF 131072B, wdF/wqF/wkF/weF 16384B each.
  char* ws = (char*)d_ws;
  bf16* qy   = (bf16*)(ws);
  bf16* kkp  = (bf16*)(ws + 49152000);
  unsigned short* attP = (unsigned short*)(ws + 98304000);
  unsigned short* woF  = (unsigned short*)(ws + 101711872);
  unsigned short* wdF  = (unsigned short*)(ws + 101842944);
  unsigned short* wqF  = (unsigned short*)(ws + 101859328);
  unsigned short* wkF  = (unsigned short*)(ws + 101875712);
  unsigned short* weF  = (unsigned short*)(ws + 101892096);

  k_pack_w<<<384, 256, 0, stream>>>(Wo, g_o, v_o, Wd, g_d, v_d,
                                    Wq, Wk, We, beta,
                                    woF, wdF, wqF, wkF, weF);
  k_qke_mfma7<<<NB * 30, 256, 0, stream>>>(x, wqF, bq, wkF, bk, weF, be,
                                           G, beta, sepe, dism, qy, kkp);
  k_att_mfma<<<NB * HH, 256, 0, stream>>>(qy, kkp, bq, disg, att0, alpha, attP);
  k_out_mfma6<<<NB * 30, 256, 0, stream>>>(x, attP, woF, wdF,
                                           b_o, g_o, be_o, m_o, v_o,
                                           b_d, g_d, be_d, m_d, v_d,
                                           (float*)d_out);
}

// Round 22
// 403.356 us; speedup vs baseline: 1.1876x; 1.0104x over previous
//
#include <hip/hip_runtime.h>
#include <hip/hip_bf16.h>
#include <math.h>

// Problem constants (fixed by the reference)
#define NB   64     // batch
#define CIN  64     // input channels
#define DIMD 128    // q/k/e channels
#define TT   120    // time
#define VV   25     // joints
#define HH   8      // heads
#define DHD  16     // DIM/H
#define WW   3      // temporal window
#define UU   75     // W*V
#define TC2  12     // t-chunk in MFMA attention kernel (120 = 10*12)
#define TCO8 8      // t-chunk in output kernel v7 (120 = 15*8)

typedef __hip_bfloat16 bf16;
typedef float        f32x4  __attribute__((ext_vector_type(4)));
typedef unsigned int u32x4  __attribute__((ext_vector_type(4)));
typedef unsigned int u32x2  __attribute__((ext_vector_type(2)));
typedef __bf16       bf16x8 __attribute__((ext_vector_type(8)));

__device__ __forceinline__ float b2f(bf16 v)  { return __bfloat162float(v); }
__device__ __forceinline__ bf16  f2b(float v) { return __float2bfloat16(v); }

__device__ __forceinline__ unsigned short f2bu(float f) {
  unsigned u = __builtin_bit_cast(unsigned, f);
  return (unsigned short)((u + 0x7fffu + ((u >> 16) & 1u)) >> 16);  // RNE
}
__device__ __forceinline__ float bfu(unsigned short s) {
  unsigned u = ((unsigned)s) << 16;
  return __builtin_bit_cast(float, u);
}
__device__ __forceinline__ unsigned pack2(float a, float b) {
  return ((unsigned)f2bu(b) << 16) | (unsigned)f2bu(a);
}

// BUILTIN MFMA (R11 lesson: asm-wrapped MFMA is invisible to the GCN hazard
// recognizer -> missing MFMA->VALU wait-states -> silent corruption).
__device__ __forceinline__ f32x4 mfma_bf16(u32x4 a, u32x4 b, f32x4 d) {
  return __builtin_amdgcn_mfma_f32_16x16x32_bf16(
      __builtin_bit_cast(bf16x8, a), __builtin_bit_cast(bf16x8, b), d, 0, 0, 0);
}

// ---------------------------------------------------------------------------
// Pre-pack kernel (R17-verbatim): weights -> fragment-ordered bf16 tensors.
// ---------------------------------------------------------------------------
__global__ __launch_bounds__(256) void k_pack_w(
    const float* __restrict__ Wo, const float* __restrict__ g_o,
    const float* __restrict__ v_o,
    const float* __restrict__ Wd, const float* __restrict__ g_d,
    const float* __restrict__ v_d,
    const float* __restrict__ Wq, const float* __restrict__ Wk,
    const float* __restrict__ We, const float* __restrict__ beta,
    unsigned short* __restrict__ woF, unsigned short* __restrict__ wdF,
    unsigned short* __restrict__ wqF, unsigned short* __restrict__ wkF,
    unsigned short* __restrict__ weF)
{
  const int i = blockIdx.x * 256 + threadIdx.x;   // grid covers 98304
  if (i < 65536) {                                 // woF
    const int j = i & 7, d = (i >> 3) & 127, kg = (i >> 10) & 3;
    const int ks = (i >> 12) & 1, h = (i >> 13) & 7;
    const float sc = g_o[d] * rsqrtf(v_o[d] + 1e-5f);
    woF[i] = f2bu(sc * Wo[d * 512 + h * 64 + ks * 32 + kg * 8 + j]);
  } else {
    const int r = i - 65536;                       // 0..32767
    const int which = r >> 13;                     // 0=wd 1=wq 2=wk 3=we
    const int l = r & 8191;
    const int j = l & 7, d = (l >> 3) & 127, kg = (l >> 10) & 3;
    const int ks = (l >> 12) & 1;
    const int c = ks * 32 + kg * 8 + j;
    if (which == 0) {
      const float sc = g_d[d] * rsqrtf(v_d[d] + 1e-5f);
      wdF[l] = f2bu(sc * Wd[d * 64 + c]);
    } else if (which == 1) {
      wqF[l] = f2bu(Wq[d * 64 + c]);
    } else if (which == 2) {
      wkF[l] = f2bu(Wk[d * 64 + c]);
    } else {
      weF[l] = f2bu(beta[0] * We[d * 64 + c]);
    }
  }
}

// ---------------------------------------------------------------------------
// Fused A+B v7 (R17-verbatim, passing)
// ---------------------------------------------------------------------------
__global__ __launch_bounds__(256, 3) void k_qke_mfma7(
    const float* __restrict__ x,
    const unsigned short* __restrict__ wqF, const float* __restrict__ bq,
    const unsigned short* __restrict__ wkF, const float* __restrict__ bk,
    const unsigned short* __restrict__ weF, const float* __restrict__ be,
    const float* __restrict__ G,  const float* __restrict__ beta,
    const float* __restrict__ se_pe, const int* __restrict__ dis,
    bf16* __restrict__ qy, bf16* __restrict__ kkp)
{
  const int n = blockIdx.x / 30, t0 = (blockIdx.x % 30) * 4;
  __shared__ alignas(16) char uA[26624];                 // xl | yTG
  __shared__ alignas(16) unsigned short yT[112][64];     // [tv][c] swz
  __shared__ alignas(16) float spl[5][64];
  __shared__ alignas(16) int   dml[25][25];
  __shared__ alignas(16) float Gl[25][26];
  __shared__ alignas(16) float gsum[32];
  __shared__ alignas(16) float biasb[384];               // bq|bk|be

  float* xl  = (float*)uA;                               // [4][64][26] f32
  char*  yTG = uA;                                       // [112] x 128B swz
  #define XL(t, c, v) xl[(((t) * 64 + (c)) * 26) + (v)]

  const int tid = threadIdx.x;
  {
    const float* xb = x + (size_t)n * 192000 + t0 * 25;  // x[n][c][t0+t][v]
    for (int i = tid; i < 6400; i += 256) {
      const int c = i / 100, j = i % 100, t = j / 25, v = j % 25;
      XL(t, c, v) = xb[c * 3000 + j];
    }
  }
  for (int i = tid; i < 320; i += 256) spl[i / 64][i % 64] = se_pe[i];
  for (int i = tid; i < 625; i += 256) dml[i / 25][i % 25] = dis[i];
  for (int i = tid; i < 625; i += 256) Gl[i / 25][i % 25] = G[i];
  if (tid < 25) {
    float s = 0.f;
    for (int u = 0; u < 25; ++u) s += G[u * 25 + tid];
    gsum[tid] = s;
  }
  for (int i = tid; i < 384; i += 256)
    biasb[i] = (i < 128) ? bq[i] : (i < 256 ? bk[i - 128] : be[i - 256]);
  for (int i = tid; i < 12 * 64; i += 256)               // yT junk rows -> 0
    yT[100 + (i >> 6)][i & 63] = 0;
  __syncthreads();

  const int lane = tid & 63, wid = tid >> 6;
  const int m16 = lane & 15, kg = lane >> 4;

  #define LOAD_PFRAGS(af, Fsrc)                                                \
    _Pragma("unroll")                                                          \
    for (int mt = 0; mt < 2; ++mt) {                                           \
      const int d_ = wid * 32 + mt * 16 + m16;                                 \
      _Pragma("unroll")                                                        \
      for (int ks = 0; ks < 2; ++ks)                                           \
        af[mt][ks] = *(const u32x4*)((Fsrc) +                                  \
                      (((ks * 4 + kg) * 128 + d_) << 3));                      \
    }

  // ---- phase 1: yT = x + pe + struct-enc ----
  for (int idx = tid; idx < 6400; idx += 256) {
    const int c = idx & 63, tv = idx >> 6;
    const int t = tv / 25, v = tv % 25;
    const float dv = expf(-(float)(c & ~1) * (logf(10000.0f) / 64.0f));
    float acc = XL(t, c, v) +
                ((c & 1) ? cosf((float)v * dv) : sinf((float)v * dv));
    #pragma unroll
    for (int u = 0; u < 25; ++u)
      acc = fmaf(XL(t, c, u), spl[dml[u][v]][c], acc);
    *(unsigned short*)((char*)yT + tv * 128 + ((c * 2) ^ ((tv & 7) << 4))) =
        f2bu(acc);
  }
  __syncthreads();   // yT ready; xl DEAD (uA becomes yTG)

  // ---- phase 1b: yTG = y @ G ----
  for (int i = tid; i < 12 * 64; i += 256)
    *(unsigned short*)(yTG + (100 + (i >> 6)) * 128 + ((i & 63) * 2)) = 0;
  for (int idx = tid; idx < 6400; idx += 256) {
    const int c = idx & 63, tv = idx >> 6;
    const int t = tv / 25, v = tv % 25;
    float acc = 0.f;
    #pragma unroll
    for (int u = 0; u < 25; ++u) {
      const int ru = t * 25 + u;
      const float yv = bfu(*(const unsigned short*)((const char*)yT + ru * 128 +
                            ((c * 2) ^ ((ru & 7) << 4))));
      acc = fmaf(yv, Gl[u][v], acc);
    }
    *(unsigned short*)(yTG + tv * 128 + ((c * 2) ^ ((tv & 7) << 4))) =
        f2bu(acc);
  }
  __syncthreads();   // yTG ready — LAST barrier; GEMMs are straight-line

  bf16* qyb = qy  + (size_t)n * 384000 + t0 * 25;
  bf16* kkb = kkp + (size_t)n * 384000 + t0 * 25;
  const float betav = beta[0];

  // ---- q-GEMM ----
  {
    u32x4 aq[2][2];
    LOAD_PFRAGS(aq, wqF);
    for (int nt = 0; nt < 7; ++nt) {
      const int tv = nt * 16 + m16;
      const u32x4 b0 = *(const u32x4*)((const char*)yT + tv * 128 +
                        (((kg * 8) * 2) ^ ((tv & 7) << 4)));
      const u32x4 b1 = *(const u32x4*)((const char*)yT + tv * 128 +
                        (((32 + kg * 8) * 2) ^ ((tv & 7) << 4)));
      #pragma unroll
      for (int mt = 0; mt < 2; ++mt) {
        f32x4 acc = (f32x4)0.f;
        acc = mfma_bf16(aq[mt][0], b0, acc);
        acc = mfma_bf16(aq[mt][1], b1, acc);
        if (tv < 100) {
          const int dr = wid * 32 + mt * 16 + kg * 4;
          #pragma unroll
          for (int i2 = 0; i2 < 4; ++i2)
            qyb[(size_t)(dr + i2) * 3000 + tv] = f2b(acc[i2] + biasb[dr + i2]);
        }
      }
    }
  }

  // ---- k-GEMM into persistent kacc ----
  f32x4 kacc[2][7];
  #pragma unroll
  for (int mt = 0; mt < 2; ++mt)
    #pragma unroll
    for (int nt = 0; nt < 7; ++nt) kacc[mt][nt] = (f32x4)0.f;
  {
    u32x4 ak[2][2];
    LOAD_PFRAGS(ak, wkF);
    for (int nt = 0; nt < 7; ++nt) {
      const int tv = nt * 16 + m16;
      const u32x4 b0 = *(const u32x4*)((const char*)yT + tv * 128 +
                        (((kg * 8) * 2) ^ ((tv & 7) << 4)));
      const u32x4 b1 = *(const u32x4*)((const char*)yT + tv * 128 +
                        (((32 + kg * 8) * 2) ^ ((tv & 7) << 4)));
      #pragma unroll
      for (int mt = 0; mt < 2; ++mt) {
        kacc[mt][nt] = mfma_bf16(ak[mt][0], b0, kacc[mt][nt]);
        kacc[mt][nt] = mfma_bf16(ak[mt][1], b1, kacc[mt][nt]);
      }
    }
  }

  // ---- e-GEMM (beta pre-folded in weF) on yTG, accumulate, store kk ----
  {
    u32x4 ae[2][2];
    LOAD_PFRAGS(ae, weF);
    for (int nt = 0; nt < 7; ++nt) {
      const int tv = nt * 16 + m16;
      const u32x4 b0 = *(const u32x4*)(yTG + tv * 128 +
                        (((kg * 8) * 2) ^ ((tv & 7) << 4)));
      const u32x4 b1 = *(const u32x4*)(yTG + tv * 128 +
                        (((32 + kg * 8) * 2) ^ ((tv & 7) << 4)));
      #pragma unroll
      for (int mt = 0; mt < 2; ++mt) {
        kacc[mt][nt] = mfma_bf16(ae[mt][0], b0, kacc[mt][nt]);
        kacc[mt][nt] = mfma_bf16(ae[mt][1], b1, kacc[mt][nt]);
        if (tv < 100) {
          const int vv = tv % 25;
          const int dr = wid * 32 + mt * 16 + kg * 4;
          #pragma unroll
          for (int i2 = 0; i2 < 4; ++i2)
            kkb[(size_t)(dr + i2) * 3000 + tv] =
                f2b(kacc[mt][nt][i2] + biasb[128 + dr + i2] +
                    betav * biasb[256 + dr + i2] * gsum[vv]);
        }
      }
    }
  }
  #undef LOAD_PFRAGS
  #undef XL
}

// ---------------------------------------------------------------------------
// Kernel C v2 (R16-verbatim, passing): MFMA attention -> padded attP
// ---------------------------------------------------------------------------
__global__ __launch_bounds__(256) void k_att_mfma(
    const bf16* __restrict__ qy, const bf16* __restrict__ kkp,
    const float* __restrict__ bq, const float* __restrict__ disg,
    const float* __restrict__ att0, const float* __restrict__ alpha,
    unsigned short* __restrict__ attP)
{
  const int n = blockIdx.x / HH, h = blockIdx.x % HH;
  __shared__ alignas(16) unsigned short qsA[80][200];  // [u][k] bf16 bits
  __shared__ alignas(16) unsigned short ksB[32][200];  // [v][k] bf16 bits
  __shared__ alignas(16) float att_s[80][28];
  __shared__ float mxv[32], smv[32];
  const int tid = threadIdx.x;
  const int lane = tid & 63, wid = tid >> 6;
  const int m16 = lane & 15, kg = lane >> 4;

  const unsigned short* qyb =
      (const unsigned short*)(qy + ((size_t)(n * DIMD + h * DHD)) * TT * VV);
  const unsigned short* kkb =
      (const unsigned short*)(kkp + ((size_t)(n * DIMD + h * DHD)) * TT * VV);

  f32x4 acc[3];
  #pragma unroll
  for (int s = 0; s < 3; ++s) acc[s] = (f32x4)0.f;

  for (int c = 0; c < 10; ++c) {
    const int t0 = c * TC2;
    __syncthreads();   // prev chunk's frag reads drained
    for (int it = tid; it < 416; it += 256) {
      if (it < 224) {
        const int dh = it / 14, j = it % 14, tq = t0 + j - 1;
        unsigned short vals[25];
        if (tq >= 0 && tq < TT) {
          const unsigned short* src = qyb + ((size_t)dh * TT + tq) * VV;
          #pragma unroll
          for (int u = 0; u < 25; ++u) vals[u] = src[u];
        } else {
          const unsigned short bqv = f2bu(bq[h * DHD + dh]);
          #pragma unroll
          for (int u = 0; u < 25; ++u) vals[u] = bqv;
        }
        #pragma unroll
        for (int w = 0; w < 3; ++w) {
          const int tt = tq - t0 - w + 1;
          if (tt >= 0 && tt < TC2) {
            const int col = tt * 16 + dh;
            #pragma unroll
            for (int u = 0; u < 25; ++u) qsA[w * 25 + u][col] = vals[u];
          }
        }
      } else {
        const int r = it - 224, dh = r / TC2, tt = r % TC2;
        const unsigned short* src = kkb + ((size_t)dh * TT + t0 + tt) * VV;
        const int col = tt * 16 + dh;
        #pragma unroll
        for (int v = 0; v < 25; ++v) ksB[v][col] = src[v];
      }
    }
    __syncthreads();   // tiles ready
    #pragma unroll
    for (int s = 0; s < 3; ++s) {
      const int tidx = wid + 4 * s;
      if (tidx < 10) {
        const int mtile = tidx >> 1, ntile = tidx & 1;
        #pragma unroll
        for (int ks = 0; ks < 6; ++ks) {
          const u32x4 a = *(const u32x4*)&qsA[mtile * 16 + m16][ks * 32 + kg * 8];
          const u32x4 b = *(const u32x4*)&ksB[ntile * 16 + m16][ks * 32 + kg * 8];
          acc[s] = mfma_bf16(a, b, acc[s]);
        }
      }
    }
  }
  __syncthreads();
  #pragma unroll
  for (int s = 0; s < 3; ++s) {
    const int tidx = wid + 4 * s;
    if (tidx < 10) {
      const int mtile = tidx >> 1, ntile = tidx & 1;
      const int v = ntile * 16 + m16;
      if (v < VV) {
        #pragma unroll
        for (int i = 0; i < 4; ++i)
          att_s[mtile * 16 + kg * 4 + i][v] = acc[s][i];
      }
    }
  }
  __syncthreads();
  const float inv = 1.0f / (float)(DHD * TT);
  for (int i = tid; i < UU * VV; i += 256) {
    const int u = i / VV, v = i % VV;
    const bool m = disg[(h * VV + u % VV) * VV + v] > 0.f;
    att_s[u][v] = m ? att_s[u][v] * inv : -9e15f;
  }
  __syncthreads();
  if (tid < VV) {
    float mx = -INFINITY;
    for (int u = 0; u < UU; ++u) mx = fmaxf(mx, att_s[u][tid]);
    float sm = 0.f;
    for (int u = 0; u < UU; ++u) sm += expf(att_s[u][tid] - mx);
    mxv[tid] = mx; smv[tid] = sm;
  }
  __syncthreads();
  const float al = alpha[0];
  unsigned* dst = (unsigned*)(attP + ((size_t)(n * HH + h) * 32) * 104);
  for (int i = tid; i < 1664; i += 256) {     // 32 x 52 u32 (= 104 u16)
    const int vc = i / 52, u0 = (i % 52) * 2;
    unsigned val = 0u;
    if (vc < VV) {
      float f0 = 0.f, f1 = 0.f;
      if (u0 < UU)
        f0 = expf(att_s[u0][vc] - mxv[vc]) / smv[vc] * al
             + att0[(h * VV + u0 % VV) * VV + vc];
      if (u0 + 1 < UU)
        f1 = expf(att_s[u0 + 1][vc] - mxv[vc]) / smv[vc] * al
             + att0[(h * VV + (u0 + 1) % VV) * VV + vc];
      val = pack2(f0, f1);
    }
    dst[i] = val;
  }
}

// ---------------------------------------------------------------------------
// Kernel D v7: 8-t blocks (512 thr, 8 waves). Wave w: stage1 t=w; stage2
// (d-quarter = w&3, t-half = w>>2). Same frag/swizzle math as R17; xsl rows
// 0..199 valid + 200..211 junk-zero. Half the blocks -> half the barrier
// events; att tile staged once per 8 t's.
// ---------------------------------------------------------------------------
__global__ __launch_bounds__(512) void k_out_mfma7(
    const float* __restrict__ x, const unsigned short* __restrict__ attP,
    const unsigned short* __restrict__ woF, const unsigned short* __restrict__ wdF,
    const float* __restrict__ b_o,
    const float* __restrict__ g_o, const float* __restrict__ be_o,
    const float* __restrict__ m_o, const float* __restrict__ v_o,
    const float* __restrict__ b_d,
    const float* __restrict__ g_d, const float* __restrict__ be_d,
    const float* __restrict__ m_d, const float* __restrict__ v_d,
    float* __restrict__ out)
{
  const int n = blockIdx.x / 15, t0 = (blockIdx.x % 15) * TCO8;
  __shared__ alignas(16) char uB[54272];                   // xu4 | xsl2[2](212r)
  __shared__ alignas(16) unsigned short attB[2][32][104];  // 13,312 B dbuf
  unsigned short* xu4 = (unsigned short*)uB;               // [(tr*64+c)*104+u], tr<4
  const int tid = threadIdx.x;
  const int lane = tid & 63, wid = tid >> 6;               // wid 0..7
  const int m16 = lane & 15, kg = lane >> 4;

  #define XSLB(b) (uB + (b) * 27136)            // [212] rows x 128B swz

  // stage 4 t's of x-unfold: t = t0+tb+tr, tr 0..3
  #define STAGE_XU4(tb)                                                        \
    for (int i = tid; i < 4 * 64 * 48; i += 512) {                             \
      const int u0 = (i % 48) * 2, c = (i / 48) & 63, tr = i / (48 * 64);      \
      float f0 = 0.f, f1 = 0.f;                                                \
      if (u0 < UU) {                                                           \
        const int w = u0 / VV, up = u0 % VV, ts = t0 + (tb) + tr + w - 1;      \
        if (ts >= 0 && ts < TT) f0 = x[((n * 64 + c) * TT + ts) * VV + up];    \
      }                                                                        \
      if (u0 + 1 < UU) {                                                       \
        const int u = u0 + 1, w = u / VV, up = u % VV;                         \
        const int ts = t0 + (tb) + tr + w - 1;                                 \
        if (ts >= 0 && ts < TT) f1 = x[((n * 64 + c) * TT + ts) * VV + up];    \
      }                                                                        \
      *(unsigned*)(xu4 + (tr * 64 + c) * 104 + u0) = pack2(f0, f1);            \
    }

  #define STAGE_ATT(hh, buf)                                                   \
    {                                                                          \
      const u32x4* srcv =                                                      \
          (const u32x4*)(attP + ((size_t)(n * HH + (hh)) * 32) * 104);         \
      u32x4* dstv = (u32x4*)&attB[buf][0][0];                                  \
      for (int i = tid; i < 416; i += 512) dstv[i] = srcv[i];                  \
    }

  // ---- prologue: A-frags (per-wave t = wid) from xu4 in two 4-t chunks ----
  STAGE_XU4(0);
  __syncthreads();
  u32x4 af[4][3];
  if (wid < 4) {
    #pragma unroll
    for (int mt = 0; mt < 4; ++mt)
      #pragma unroll
      for (int ks = 0; ks < 3; ++ks)
        af[mt][ks] = *(const u32x4*)(xu4 + (wid * 64 + mt * 16 + m16) * 104 +
                                     ks * 32 + kg * 8);
  }
  __syncthreads();   // chunk-1 reads drained before overwrite
  STAGE_XU4(4);
  STAGE_ATT(0, 0);
  __syncthreads();
  if (wid >= 4) {
    #pragma unroll
    for (int mt = 0; mt < 4; ++mt)
      #pragma unroll
      for (int ks = 0; ks < 3; ++ks)
        af[mt][ks] = *(const u32x4*)(xu4 + ((wid - 4) * 64 + mt * 16 + m16) * 104 +
                                     ks * 32 + kg * 8);
  }
  __syncthreads();   // FENCE: all xu4 reads drained; uB becomes xsl2
  // zero junk rows (tv 200..211) of BOTH xsl buffers (never rewritten)
  for (int i = tid; i < 2 * 12 * 64; i += 512) {
    const int b = i / (12 * 64), r = i % (12 * 64);
    *(unsigned short*)(XSLB(b) + (200 + (r >> 6)) * 128 + ((r & 63) * 2)) = 0;
  }

  const int th = wid >> 2, dq = wid & 3;     // stage2 split: t-half, d-quarter

  f32x4 acc2[2][7];
  #pragma unroll
  for (int mt = 0; mt < 2; ++mt)
    #pragma unroll
    for (int nt = 0; nt < 7; ++nt) acc2[mt][nt] = (f32x4)0.f;

  for (int h = 0; h <= HH; ++h) {
    const int pb = h & 1;
    char* xs = XSLB(pb);
    // stage2 A-frags from pre-packed tensors (coalesced; scales folded)
    u32x4 a2[2][2];
    #pragma unroll
    for (int mt = 0; mt < 2; ++mt) {
      const int d = dq * 32 + mt * 16 + m16;
      #pragma unroll
      for (int ks = 0; ks < 2; ++ks) {
        const unsigned short* src = (h < HH)
            ? (woF + ((((h * 2 + ks) * 4 + kg) * 128 + d) << 3))
            : (wdF + ((((ks) * 4 + kg) * 128 + d) << 3));
        a2[mt][ks] = *(const u32x4*)src;
      }
    }
    if (h + 1 < HH) { STAGE_ATT(h + 1, (h + 1) & 1); }
    f32x4 a1[4][2];
    if (h < HH) {
      u32x4 bfr[2][3];
      #pragma unroll
      for (int nt = 0; nt < 2; ++nt)
        #pragma unroll
        for (int ks = 0; ks < 3; ++ks)
          bfr[nt][ks] =
              *(const u32x4*)&attB[pb][nt * 16 + m16][ks * 32 + kg * 8];
      #pragma unroll
      for (int mt = 0; mt < 4; ++mt)
        #pragma unroll
        for (int nt = 0; nt < 2; ++nt) {
          a1[mt][nt] = (f32x4)0.f;
          #pragma unroll
          for (int ks = 0; ks < 3; ++ks)
            a1[mt][nt] = mfma_bf16(af[mt][ks], bfr[nt][ks], a1[mt][nt]);
        }
    }
    // write this h's xs buffer (parity pb; h-1 used 1-pb -> no hazard)
    if (h < HH) {
      #pragma unroll
      for (int mt = 0; mt < 4; ++mt)
        #pragma unroll
        for (int nt = 0; nt < 2; ++nt) {
          const int v = nt * 16 + m16;
          if (v < VV) {
            const int tv = wid * VV + v;      // wave's t = wid, rows 0..199
            const int c0 = mt * 16 + kg * 4;
            u32x2 pk;
            pk[0] = pack2(a1[mt][nt][0], a1[mt][nt][1]);
            pk[1] = pack2(a1[mt][nt][2], a1[mt][nt][3]);
            char* p = xs + tv * 128 + ((c0 * 2) ^ ((tv & 7) << 4));
            *(u32x2*)p = pk;
          }
        }
    } else {
      // residual: xs <- x^T (bf16) for 8 t's (200 tv rows x 64 c)
      for (int i = tid; i < 12800; i += 512) {
        const int c = i / 200, j = i % 200;   // j = tl*25 + v
        const float f = x[((size_t)(n * 64 + c) * TT + t0 + j / 25) * VV + j % 25];
        *(unsigned short*)(xs + j * 128 + ((c * 2) ^ ((j & 7) << 4))) =
            f2bu(f);
      }
    }
    __syncthreads();   // single barrier: xs writes(pb) -> reads(pb)
    #pragma unroll
    for (int nt = 0; nt < 7; ++nt) {
      const int tv = th * 100 + nt * 16 + m16;
      const u32x4 b0 = *(const u32x4*)(xs + tv * 128 +
                        (((kg * 8) * 2) ^ ((tv & 7) << 4)));
      const u32x4 b1 = *(const u32x4*)(xs + tv * 128 +
                        (((32 + kg * 8) * 2) ^ ((tv & 7) << 4)));
      #pragma unroll
      for (int mt = 0; mt < 2; ++mt) {
        acc2[mt][nt] = mfma_bf16(a2[mt][0], b0, acc2[mt][nt]);
        acc2[mt][nt] = mfma_bf16(a2[mt][1], b1, acc2[mt][nt]);
      }
    }
  }

  #pragma unroll
  for (int mt = 0; mt < 2; ++mt) {
    float cc[4];
    #pragma unroll
    for (int i = 0; i < 4; ++i) {
      const int d = dq * 32 + mt * 16 + kg * 4 + i;
      const float so2 = g_o[d] * rsqrtf(v_o[d] + 1e-5f);
      const float sd2 = g_d[d] * rsqrtf(v_d[d] + 1e-5f);
      cc[i] = b_o[d] * so2 + be_o[d] - m_o[d] * so2
            + b_d[d] * sd2 + be_d[d] - m_d[d] * sd2;
    }
    #pragma unroll
    for (int nt = 0; nt < 7; ++nt) {
      const int tvl = nt * 16 + m16;
      if (tvl < 100) {
        const int tv = th * 100 + tvl;
        const int t = t0 + tv / VV, v = tv % VV;
        #pragma unroll
        for (int i = 0; i < 4; ++i) {
          const int d = dq * 32 + mt * 16 + kg * 4 + i;
          const float z = acc2[mt][nt][i] + cc[i];
          out[((n * DIMD + d) * TT + t) * VV + v] = (z >= 0.f) ? z : 0.1f * z;
        }
      }
    }
  }
  #undef STAGE_XU4
  #undef STAGE_ATT
  #undef XSLB
}

// ---------------------------------------------------------------------------
extern "C" void kernel_launch(void* const* d_in, const int* in_sizes, int n_in,
                              void* d_out, int out_size, void* d_ws, size_t ws_size,
                              hipStream_t stream)
{
  (void)in_sizes; (void)n_in; (void)out_size; (void)ws_size;
  const float* x     = (const float*)d_in[0];
  const float* Wq    = (const float*)d_in[1];
  const float* bq    = (const float*)d_in[2];
  const float* Wk    = (const float*)d_in[3];
  const float* bk    = (const float*)d_in[4];
  const float* We    = (const float*)d_in[5];
  const float* be    = (const float*)d_in[6];
  const float* G     = (const float*)d_in[7];
  const float* sepe  = (const float*)d_in[8];
  const float* att0  = (const float*)d_in[9];
  const float* alpha = (const float*)d_in[10];
  const float* beta  = (const float*)d_in[11];
  const float* Wo    = (const float*)d_in[12];
  const float* b_o   = (const float*)d_in[13];
  const float* g_o   = (const float*)d_in[14];
  const float* be_o  = (const float*)d_in[15];
  const float* m_o   = (const float*)d_in[16];
  const float* v_o   = (const float*)d_in[17];
  const float* Wd    = (const float*)d_in[18];
  const float* b_d   = (const float*)d_in[19];
  const float* g_d   = (const float*)d_in[20];
  const float* be_d  = (const float*)d_in[21];
  const float* m_d   = (const float*)d_in[22];
  const float* v_d   = (const float*)d_in[23];
  const int*   dism  = (const int*)d_in[24];
  const float* disg  = (const float*)d_in[25];

  // Workspace: qy @0 (49.152 MB), kk @49,152,000, attP @98,304,000 (3.41 MB),
  // packed weights @101,711,872: woF 131072B, wdF/wqF/wkF/weF 16384B each.
  char* ws = (char*)d_ws;
  bf16* qy   = (bf16*)(ws);
  bf16* kkp  = (bf16*)(ws + 49152000);
  unsigned short* attP = (unsigned short*)(ws + 98304000);
  unsigned short* woF  = (unsigned short*)(ws + 101711872);
  unsigned short* wdF  = (unsigned short*)(ws + 101842944);
  unsigned short* wqF  = (unsigned short*)(ws + 101859328);
  unsigned short* wkF  = (unsigned short*)(ws + 101875712);
  unsigned short* weF  = (unsigned short*)(ws + 101892096);

  k_pack_w<<<384, 256, 0, stream>>>(Wo, g_o, v_o, Wd, g_d, v_d,
                                    Wq, Wk, We, beta,
                                    woF, wdF, wqF, wkF, weF);
  k_qke_mfma7<<<NB * 30, 256, 0, stream>>>(x, wqF, bq, wkF, bk, weF, be,
                                           G, beta, sepe, dism, qy, kkp);
  k_att_mfma<<<NB * HH, 256, 0, stream>>>(qy, kkp, bq, disg, att0, alpha, attP);
  k_out_mfma7<<<NB * 15, 512, 0, stream>>>(x, attP, woF, wdF,
                                           b_o, g_o, be_o, m_o, v_o,
                                           b_d, g_d, be_d, m_d, v_d,
                                           (float*)d_out);
}

// Round 23
// 322.201 us; speedup vs baseline: 1.4867x; 1.2519x over previous
//
#include <hip/hip_runtime.h>
#include <hip/hip_bf16.h>
#include <math.h>

// Problem constants (fixed by the reference)
#define NB   64     // batch
#define CIN  64     // input channels
#define DIMD 128    // q/k/e channels
#define TT   120    // time
#define VV   25     // joints
#define HH   8      // heads
#define DHD  16     // DIM/H
#define WW   3      // temporal window
#define UU   75     // W*V
#define TC2  12     // t-chunk in MFMA attention kernel (120 = 10*12)
#define TCO8 8      // t-chunk in output kernel v7 (120 = 15*8)

typedef __hip_bfloat16 bf16;
typedef float        f32x4  __attribute__((ext_vector_type(4)));
typedef unsigned int u32x4  __attribute__((ext_vector_type(4)));
typedef unsigned int u32x2  __attribute__((ext_vector_type(2)));
typedef __bf16       bf16x8 __attribute__((ext_vector_type(8)));

__device__ __forceinline__ float b2f(bf16 v)  { return __bfloat162float(v); }
__device__ __forceinline__ bf16  f2b(float v) { return __float2bfloat16(v); }

__device__ __forceinline__ unsigned short f2bu(float f) {
  unsigned u = __builtin_bit_cast(unsigned, f);
  return (unsigned short)((u + 0x7fffu + ((u >> 16) & 1u)) >> 16);  // RNE
}
__device__ __forceinline__ float bfu(unsigned short s) {
  unsigned u = ((unsigned)s) << 16;
  return __builtin_bit_cast(float, u);
}
__device__ __forceinline__ unsigned pack2(float a, float b) {
  return ((unsigned)f2bu(b) << 16) | (unsigned)f2bu(a);
}

// BUILTIN MFMA (R11 lesson: asm-wrapped MFMA is invisible to the GCN hazard
// recognizer -> missing MFMA->VALU wait-states -> silent corruption).
__device__ __forceinline__ f32x4 mfma_bf16(u32x4 a, u32x4 b, f32x4 d) {
  return __builtin_amdgcn_mfma_f32_16x16x32_bf16(
      __builtin_bit_cast(bf16x8, a), __builtin_bit_cast(bf16x8, b), d, 0, 0, 0);
}

// ---------------------------------------------------------------------------
// Pre-pack kernel (R17-verbatim): weights -> fragment-ordered bf16 tensors.
// ---------------------------------------------------------------------------
__global__ __launch_bounds__(256) void k_pack_w(
    const float* __restrict__ Wo, const float* __restrict__ g_o,
    const float* __restrict__ v_o,
    const float* __restrict__ Wd, const float* __restrict__ g_d,
    const float* __restrict__ v_d,
    const float* __restrict__ Wq, const float* __restrict__ Wk,
    const float* __restrict__ We, const float* __restrict__ beta,
    unsigned short* __restrict__ woF, unsigned short* __restrict__ wdF,
    unsigned short* __restrict__ wqF, unsigned short* __restrict__ wkF,
    unsigned short* __restrict__ weF)
{
  const int i = blockIdx.x * 256 + threadIdx.x;   // grid covers 98304
  if (i < 65536) {                                 // woF
    const int j = i & 7, d = (i >> 3) & 127, kg = (i >> 10) & 3;
    const int ks = (i >> 12) & 1, h = (i >> 13) & 7;
    const float sc = g_o[d] * rsqrtf(v_o[d] + 1e-5f);
    woF[i] = f2bu(sc * Wo[d * 512 + h * 64 + ks * 32 + kg * 8 + j]);
  } else {
    const int r = i - 65536;                       // 0..32767
    const int which = r >> 13;                     // 0=wd 1=wq 2=wk 3=we
    const int l = r & 8191;
    const int j = l & 7, d = (l >> 3) & 127, kg = (l >> 10) & 3;
    const int ks = (l >> 12) & 1;
    const int c = ks * 32 + kg * 8 + j;
    if (which == 0) {
      const float sc = g_d[d] * rsqrtf(v_d[d] + 1e-5f);
      wdF[l] = f2bu(sc * Wd[d * 64 + c]);
    } else if (which == 1) {
      wqF[l] = f2bu(Wq[d * 64 + c]);
    } else if (which == 2) {
      wkF[l] = f2bu(Wk[d * 64 + c]);
    } else {
      weF[l] = f2bu(beta[0] * We[d * 64 + c]);
    }
  }
}

// ---------------------------------------------------------------------------
// Fused A+B v9: phase-1 struct-enc via 5-hop indicator MFMAs (builtin, safe):
//   y[r=c*4+t][v] = x + pe + sum_hop spl[hop][c] * (X @ M_hop)[r][v]
// phase-1b = R18/19-verified yC+GlT MFMA. GEMMs R17-verbatim.
// LDS: uA(xf 16K -> yTG 14K) | yCM(MhT 10.2K -> yC 16K) | yT | GlT | tables.
// ---------------------------------------------------------------------------
__global__ __launch_bounds__(256, 3) void k_qke_mfma9(
    const float* __restrict__ x,
    const unsigned short* __restrict__ wqF, const float* __restrict__ bq,
    const unsigned short* __restrict__ wkF, const float* __restrict__ bk,
    const unsigned short* __restrict__ weF, const float* __restrict__ be,
    const float* __restrict__ G,  const float* __restrict__ beta,
    const float* __restrict__ se_pe, const int* __restrict__ dis,
    bf16* __restrict__ qy, bf16* __restrict__ kkp)
{
  const int n = blockIdx.x / 30, t0 = (blockIdx.x % 30) * 4;
  __shared__ alignas(16) char uA[16384];                 // xf | yTG
  __shared__ alignas(16) char yCM[16384];                // MhT | yC
  __shared__ alignas(16) unsigned short yT[112][64];     // [tv][c] swz
  __shared__ alignas(16) unsigned short GlT[32][32];     // [v][u] swz (R18)
  __shared__ alignas(16) float spl[5][64];
  __shared__ alignas(16) float gsum[32];
  __shared__ alignas(16) float biasb[384];               // bq|bk|be

  unsigned short* xf  = (unsigned short*)uA;             // [r=c*4+t][32] pad0
  char*           yTG = uA;                              // [112] x 128B swz
  unsigned short* MhT = (unsigned short*)yCM;            // [5][32][32]
  char*           yC  = yCM;                             // [4][64][32] u16 swz

  const int tid = threadIdx.x;
  // ---- phase 0: stage ----
  {
    const float* xb = x + (size_t)n * 192000 + t0 * 25;  // x[n][c][t0+t][v]
    for (int i = tid; i < 8192; i += 256) {              // xf: 256 rows x 32
      const int u = i & 31, r = i >> 5;                  // r = c*4+t
      const int c = r >> 2, t = r & 3;
      xf[i] = (u < VV) ? f2bu(xb[c * 3000 + t * 25 + u]) : 0;
    }
  }
  for (int i = tid; i < 5120; i += 256) {                // MhT[hop][v][u]
    const int hop = i / 1024, r = i % 1024, v = r >> 5, u = r & 31;
    MhT[i] = (u < VV && v < VV && dis[u * 25 + v] == hop) ? 0x3f80 : 0;
  }
  for (int i = tid; i < 320; i += 256) spl[i / 64][i % 64] = se_pe[i];
  for (int i = tid; i < 1024; i += 256) {                // GlT[v][u]=G[u][v], swz
    const int v = i >> 5, u = i & 31;
    const float g = (v < 25 && u < 25) ? G[u * 25 + v] : 0.f;
    *(unsigned short*)((char*)GlT + v * 64 + ((u * 2) ^ ((v & 7) << 4))) =
        f2bu(g);
  }
  if (tid < 25) {
    float s = 0.f;
    for (int u = 0; u < 25; ++u) s += G[u * 25 + tid];
    gsum[tid] = s;
  }
  for (int i = tid; i < 384; i += 256)
    biasb[i] = (i < 128) ? bq[i] : (i < 256 ? bk[i - 128] : be[i - 256]);
  for (int i = tid; i < 12 * 64; i += 256)               // yT junk rows -> 0
    yT[100 + (i >> 6)][i & 63] = 0;
  __syncthreads();

  const int lane = tid & 63, wid = tid >> 6;
  const int m16 = lane & 15, kg = lane >> 4;

  #define LOAD_PFRAGS(af, Fsrc)                                                \
    _Pragma("unroll")                                                          \
    for (int mt = 0; mt < 2; ++mt) {                                           \
      const int d_ = wid * 32 + mt * 16 + m16;                                 \
      _Pragma("unroll")                                                        \
      for (int ks = 0; ks < 2; ++ks)                                           \
        af[mt][ks] = *(const u32x4*)((Fsrc) +                                  \
                      (((ks * 4 + kg) * 128 + d_) << 3));                      \
    }

  // ---- phase 1: indicator-MFMA struct-enc; writes yT + yC ----
  {
    u32x4 bh[2][5];
    #pragma unroll
    for (int ntv = 0; ntv < 2; ++ntv)
      #pragma unroll
      for (int hop = 0; hop < 5; ++hop)
        bh[ntv][hop] = *(const u32x4*)&MhT[hop * 1024 +
                                          (ntv * 16 + m16) * 32 + kg * 8];
    __syncthreads();   // all B-frag preloads done before yC overwrites MhT

    #pragma unroll
    for (int mt4 = 0; mt4 < 4; ++mt4) {
      const int r0 = (wid * 4 + mt4) * 16;
      const u32x4 a = *(const u32x4*)&xf[(r0 + m16) * 32 + kg * 8];
      const int c = (r0 + kg * 4) >> 2;     // constant over i (= (wid*4+mt4)*4+kg)
      float spc[5];
      #pragma unroll
      for (int hop = 0; hop < 5; ++hop) spc[hop] = spl[hop][c];
      const float dv = expf(-(float)(c & ~1) * (logf(10000.0f) / 64.0f));
      #pragma unroll
      for (int ntv = 0; ntv < 2; ++ntv) {
        f32x4 zh[5];
        #pragma unroll
        for (int hop = 0; hop < 5; ++hop) {
          zh[hop] = (f32x4)0.f;
          zh[hop] = mfma_bf16(a, bh[ntv][hop], zh[hop]);
        }
        const int v = ntv * 16 + m16;
        if (v < VV) {
          const float pe = (c & 1) ? cosf((float)v * dv) : sinf((float)v * dv);
          #pragma unroll
          for (int i = 0; i < 4; ++i) {      // t = i, row r = r0+kg*4+i
            const int r = r0 + kg * 4 + i;
            float yv = bfu(xf[r * 32 + v]) + pe;
            #pragma unroll
            for (int hop = 0; hop < 5; ++hop)
              yv = fmaf(spc[hop], zh[hop][i], yv);
            const unsigned short yb = f2bu(yv);
            const int tv = i * 25 + v;
            *(unsigned short*)((char*)yT + tv * 128 +
                               ((c * 2) ^ ((tv & 7) << 4))) = yb;
            *(unsigned short*)(yC + (i * 64 + c) * 64 +
                               ((v * 2) ^ ((c & 7) << 4))) = yb;
          }
        } else {                             // v 25..31: zero yC pad cols
          #pragma unroll
          for (int i = 0; i < 4; ++i) {
            const int c2 = c;
            *(unsigned short*)(yC + (i * 64 + c2) * 64 +
                               ((v * 2) ^ ((c2 & 7) << 4))) = 0;
          }
        }
      }
    }
  }
  __syncthreads();   // yT + yC ready; xf DEAD (uA becomes yTG)

  // ---- phase 1b (R18/19-verified MFMA): yTG = y @ G (wave t = wid) ----
  for (int i = tid; i < 12 * 64; i += 256)
    *(unsigned short*)(yTG + (100 + (i >> 6)) * 128 + ((i & 63) * 2)) = 0;
  {
    const int t = wid;
    u32x4 bg[2];
    #pragma unroll
    for (int ntv = 0; ntv < 2; ++ntv) {
      const int v = ntv * 16 + m16;
      bg[ntv] = *(const u32x4*)((const char*)GlT + v * 64 +
                                ((kg * 16) ^ ((v & 7) << 4)));
    }
    #pragma unroll
    for (int mtile = 0; mtile < 4; ++mtile) {
      const int cr = mtile * 16 + m16;
      const u32x4 a = *(const u32x4*)(yC + (t * 64 + cr) * 64 +
                                      ((kg * 16) ^ ((cr & 7) << 4)));
      #pragma unroll
      for (int ntv = 0; ntv < 2; ++ntv) {
        f32x4 d = (f32x4)0.f;
        d = mfma_bf16(a, bg[ntv], d);
        const int v = ntv * 16 + m16;
        if (v < 25) {
          const int tv = t * 25 + v;
          #pragma unroll
          for (int i = 0; i < 4; ++i) {
            const int cc = mtile * 16 + kg * 4 + i;
            *(unsigned short*)(yTG + tv * 128 + ((cc * 2) ^ ((tv & 7) << 4))) =
                f2bu(d[i]);
          }
        }
      }
    }
  }
  __syncthreads();   // yTG ready — GEMMs are straight-line

  bf16* qyb = qy  + (size_t)n * 384000 + t0 * 25;
  bf16* kkb = kkp + (size_t)n * 384000 + t0 * 25;
  const float betav = beta[0];

  // ---- q-GEMM ----
  {
    u32x4 aq[2][2];
    LOAD_PFRAGS(aq, wqF);
    for (int nt = 0; nt < 7; ++nt) {
      const int tv = nt * 16 + m16;
      const u32x4 b0 = *(const u32x4*)((const char*)yT + tv * 128 +
                        (((kg * 8) * 2) ^ ((tv & 7) << 4)));
      const u32x4 b1 = *(const u32x4*)((const char*)yT + tv * 128 +
                        (((32 + kg * 8) * 2) ^ ((tv & 7) << 4)));
      #pragma unroll
      for (int mt = 0; mt < 2; ++mt) {
        f32x4 acc = (f32x4)0.f;
        acc = mfma_bf16(aq[mt][0], b0, acc);
        acc = mfma_bf16(aq[mt][1], b1, acc);
        if (tv < 100) {
          const int dr = wid * 32 + mt * 16 + kg * 4;
          #pragma unroll
          for (int i2 = 0; i2 < 4; ++i2)
            qyb[(size_t)(dr + i2) * 3000 + tv] = f2b(acc[i2] + biasb[dr + i2]);
        }
      }
    }
  }

  // ---- k-GEMM into persistent kacc ----
  f32x4 kacc[2][7];
  #pragma unroll
  for (int mt = 0; mt < 2; ++mt)
    #pragma unroll
    for (int nt = 0; nt < 7; ++nt) kacc[mt][nt] = (f32x4)0.f;
  {
    u32x4 ak[2][2];
    LOAD_PFRAGS(ak, wkF);
    for (int nt = 0; nt < 7; ++nt) {
      const int tv = nt * 16 + m16;
      const u32x4 b0 = *(const u32x4*)((const char*)yT + tv * 128 +
                        (((kg * 8) * 2) ^ ((tv & 7) << 4)));
      const u32x4 b1 = *(const u32x4*)((const char*)yT + tv * 128 +
                        (((32 + kg * 8) * 2) ^ ((tv & 7) << 4)));
      #pragma unroll
      for (int mt = 0; mt < 2; ++mt) {
        kacc[mt][nt] = mfma_bf16(ak[mt][0], b0, kacc[mt][nt]);
        kacc[mt][nt] = mfma_bf16(ak[mt][1], b1, kacc[mt][nt]);
      }
    }
  }

  // ---- e-GEMM (beta pre-folded in weF) on yTG, accumulate, store kk ----
  {
    u32x4 ae[2][2];
    LOAD_PFRAGS(ae, weF);
    for (int nt = 0; nt < 7; ++nt) {
      const int tv = nt * 16 + m16;
      const u32x4 b0 = *(const u32x4*)(yTG + tv * 128 +
                        (((kg * 8) * 2) ^ ((tv & 7) << 4)));
      const u32x4 b1 = *(const u32x4*)(yTG + tv * 128 +
                        (((32 + kg * 8) * 2) ^ ((tv & 7) << 4)));
      #pragma unroll
      for (int mt = 0; mt < 2; ++mt) {
        kacc[mt][nt] = mfma_bf16(ae[mt][0], b0, kacc[mt][nt]);
        kacc[mt][nt] = mfma_bf16(ae[mt][1], b1, kacc[mt][nt]);
        if (tv < 100) {
          const int vv = tv % 25;
          const int dr = wid * 32 + mt * 16 + kg * 4;
          #pragma unroll
          for (int i2 = 0; i2 < 4; ++i2)
            kkb[(size_t)(dr + i2) * 3000 + tv] =
                f2b(kacc[mt][nt][i2] + biasb[128 + dr + i2] +
                    betav * biasb[256 + dr + i2] * gsum[vv]);
        }
      }
    }
  }
  #undef LOAD_PFRAGS
}

// ---------------------------------------------------------------------------
// Kernel C v2 (R16-verbatim, passing): MFMA attention -> padded attP
// ---------------------------------------------------------------------------
__global__ __launch_bounds__(256) void k_att_mfma(
    const bf16* __restrict__ qy, const bf16* __restrict__ kkp,
    const float* __restrict__ bq, const float* __restrict__ disg,
    const float* __restrict__ att0, const float* __restrict__ alpha,
    unsigned short* __restrict__ attP)
{
  const int n = blockIdx.x / HH, h = blockIdx.x % HH;
  __shared__ alignas(16) unsigned short qsA[80][200];  // [u][k] bf16 bits
  __shared__ alignas(16) unsigned short ksB[32][200];  // [v][k] bf16 bits
  __shared__ alignas(16) float att_s[80][28];
  __shared__ float mxv[32], smv[32];
  const int tid = threadIdx.x;
  const int lane = tid & 63, wid = tid >> 6;
  const int m16 = lane & 15, kg = lane >> 4;

  const unsigned short* qyb =
      (const unsigned short*)(qy + ((size_t)(n * DIMD + h * DHD)) * TT * VV);
  const unsigned short* kkb =
      (const unsigned short*)(kkp + ((size_t)(n * DIMD + h * DHD)) * TT * VV);

  f32x4 acc[3];
  #pragma unroll
  for (int s = 0; s < 3; ++s) acc[s] = (f32x4)0.f;

  for (int c = 0; c < 10; ++c) {
    const int t0 = c * TC2;
    __syncthreads();   // prev chunk's frag reads drained
    for (int it = tid; it < 416; it += 256) {
      if (it < 224) {
        const int dh = it / 14, j = it % 14, tq = t0 + j - 1;
        unsigned short vals[25];
        if (tq >= 0 && tq < TT) {
          const unsigned short* src = qyb + ((size_t)dh * TT + tq) * VV;
          #pragma unroll
          for (int u = 0; u < 25; ++u) vals[u] = src[u];
        } else {
          const unsigned short bqv = f2bu(bq[h * DHD + dh]);
          #pragma unroll
          for (int u = 0; u < 25; ++u) vals[u] = bqv;
        }
        #pragma unroll
        for (int w = 0; w < 3; ++w) {
          const int tt = tq - t0 - w + 1;
          if (tt >= 0 && tt < TC2) {
            const int col = tt * 16 + dh;
            #pragma unroll
            for (int u = 0; u < 25; ++u) qsA[w * 25 + u][col] = vals[u];
          }
        }
      } else {
        const int r = it - 224, dh = r / TC2, tt = r % TC2;
        const unsigned short* src = kkb + ((size_t)dh * TT + t0 + tt) * VV;
        const int col = tt * 16 + dh;
        #pragma unroll
        for (int v = 0; v < 25; ++v) ksB[v][col] = src[v];
      }
    }
    __syncthreads();   // tiles ready
    #pragma unroll
    for (int s = 0; s < 3; ++s) {
      const int tidx = wid + 4 * s;
      if (tidx < 10) {
        const int mtile = tidx >> 1, ntile = tidx & 1;
        #pragma unroll
        for (int ks = 0; ks < 6; ++ks) {
          const u32x4 a = *(const u32x4*)&qsA[mtile * 16 + m16][ks * 32 + kg * 8];
          const u32x4 b = *(const u32x4*)&ksB[ntile * 16 + m16][ks * 32 + kg * 8];
          acc[s] = mfma_bf16(a, b, acc[s]);
        }
      }
    }
  }
  __syncthreads();
  #pragma unroll
  for (int s = 0; s < 3; ++s) {
    const int tidx = wid + 4 * s;
    if (tidx < 10) {
      const int mtile = tidx >> 1, ntile = tidx & 1;
      const int v = ntile * 16 + m16;
      if (v < VV) {
        #pragma unroll
        for (int i = 0; i < 4; ++i)
          att_s[mtile * 16 + kg * 4 + i][v] = acc[s][i];
      }
    }
  }
  __syncthreads();
  const float inv = 1.0f / (float)(DHD * TT);
  for (int i = tid; i < UU * VV; i += 256) {
    const int u = i / VV, v = i % VV;
    const bool m = disg[(h * VV + u % VV) * VV + v] > 0.f;
    att_s[u][v] = m ? att_s[u][v] * inv : -9e15f;
  }
  __syncthreads();
  if (tid < VV) {
    float mx = -INFINITY;
    for (int u = 0; u < UU; ++u) mx = fmaxf(mx, att_s[u][tid]);
    float sm = 0.f;
    for (int u = 0; u < UU; ++u) sm += expf(att_s[u][tid] - mx);
    mxv[tid] = mx; smv[tid] = sm;
  }
  __syncthreads();
  const float al = alpha[0];
  unsigned* dst = (unsigned*)(attP + ((size_t)(n * HH + h) * 32) * 104);
  for (int i = tid; i < 1664; i += 256) {     // 32 x 52 u32 (= 104 u16)
    const int vc = i / 52, u0 = (i % 52) * 2;
    unsigned val = 0u;
    if (vc < VV) {
      float f0 = 0.f, f1 = 0.f;
      if (u0 < UU)
        f0 = expf(att_s[u0][vc] - mxv[vc]) / smv[vc] * al
             + att0[(h * VV + u0 % VV) * VV + vc];
      if (u0 + 1 < UU)
        f1 = expf(att_s[u0 + 1][vc] - mxv[vc]) / smv[vc] * al
             + att0[(h * VV + (u0 + 1) % VV) * VV + vc];
      val = pack2(f0, f1);
    }
    dst[i] = val;
  }
}

// ---------------------------------------------------------------------------
// Kernel D v7 (R22-verbatim, passing): 8-t blocks, 512 threads.
// ---------------------------------------------------------------------------
__global__ __launch_bounds__(512) void k_out_mfma7(
    const float* __restrict__ x, const unsigned short* __restrict__ attP,
    const unsigned short* __restrict__ woF, const unsigned short* __restrict__ wdF,
    const float* __restrict__ b_o,
    const float* __restrict__ g_o, const float* __restrict__ be_o,
    const float* __restrict__ m_o, const float* __restrict__ v_o,
    const float* __restrict__ b_d,
    const float* __restrict__ g_d, const float* __restrict__ be_d,
    const float* __restrict__ m_d, const float* __restrict__ v_d,
    float* __restrict__ out)
{
  const int n = blockIdx.x / 15, t0 = (blockIdx.x % 15) * TCO8;
  __shared__ alignas(16) char uB[54272];                   // xu4 | xsl2[2](212r)
  __shared__ alignas(16) unsigned short attB[2][32][104];  // 13,312 B dbuf
  unsigned short* xu4 = (unsigned short*)uB;               // [(tr*64+c)*104+u], tr<4
  const int tid = threadIdx.x;
  const int lane = tid & 63, wid = tid >> 6;               // wid 0..7
  const int m16 = lane & 15, kg = lane >> 4;

  #define XSLB(b) (uB + (b) * 27136)            // [212] rows x 128B swz

  #define STAGE_XU4(tb)                                                        \
    for (int i = tid; i < 4 * 64 * 48; i += 512) {                             \
      const int u0 = (i % 48) * 2, c = (i / 48) & 63, tr = i / (48 * 64);      \
      float f0 = 0.f, f1 = 0.f;                                                \
      if (u0 < UU) {                                                           \
        const int w = u0 / VV, up = u0 % VV, ts = t0 + (tb) + tr + w - 1;      \
        if (ts >= 0 && ts < TT) f0 = x[((n * 64 + c) * TT + ts) * VV + up];    \
      }                                                                        \
      if (u0 + 1 < UU) {                                                       \
        const int u = u0 + 1, w = u / VV, up = u % VV;                         \
        const int ts = t0 + (tb) + tr + w - 1;                                 \
        if (ts >= 0 && ts < TT) f1 = x[((n * 64 + c) * TT + ts) * VV + up];    \
      }                                                                        \
      *(unsigned*)(xu4 + (tr * 64 + c) * 104 + u0) = pack2(f0, f1);            \
    }

  #define STAGE_ATT(hh, buf)                                                   \
    {                                                                          \
      const u32x4* srcv =                                                      \
          (const u32x4*)(attP + ((size_t)(n * HH + (hh)) * 32) * 104);         \
      u32x4* dstv = (u32x4*)&attB[buf][0][0];                                  \
      for (int i = tid; i < 416; i += 512) dstv[i] = srcv[i];                  \
    }

  STAGE_XU4(0);
  __syncthreads();
  u32x4 af[4][3];
  if (wid < 4) {
    #pragma unroll
    for (int mt = 0; mt < 4; ++mt)
      #pragma unroll
      for (int ks = 0; ks < 3; ++ks)
        af[mt][ks] = *(const u32x4*)(xu4 + (wid * 64 + mt * 16 + m16) * 104 +
                                     ks * 32 + kg * 8);
  }
  __syncthreads();
  STAGE_XU4(4);
  STAGE_ATT(0, 0);
  __syncthreads();
  if (wid >= 4) {
    #pragma unroll
    for (int mt = 0; mt < 4; ++mt)
      #pragma unroll
      for (int ks = 0; ks < 3; ++ks)
        af[mt][ks] = *(const u32x4*)(xu4 + ((wid - 4) * 64 + mt * 16 + m16) * 104 +
                                     ks * 32 + kg * 8);
  }
  __syncthreads();
  for (int i = tid; i < 2 * 12 * 64; i += 512) {
    const int b = i / (12 * 64), r = i % (12 * 64);
    *(unsigned short*)(XSLB(b) + (200 + (r >> 6)) * 128 + ((r & 63) * 2)) = 0;
  }

  const int th = wid >> 2, dq = wid & 3;

  f32x4 acc2[2][7];
  #pragma unroll
  for (int mt = 0; mt < 2; ++mt)
    #pragma unroll
    for (int nt = 0; nt < 7; ++nt) acc2[mt][nt] = (f32x4)0.f;

  for (int h = 0; h <= HH; ++h) {
    const int pb = h & 1;
    char* xs = XSLB(pb);
    u32x4 a2[2][2];
    #pragma unroll
    for (int mt = 0; mt < 2; ++mt) {
      const int d = dq * 32 + mt * 16 + m16;
      #pragma unroll
      for (int ks = 0; ks < 2; ++ks) {
        const unsigned short* src = (h < HH)
            ? (woF + ((((h * 2 + ks) * 4 + kg) * 128 + d) << 3))
            : (wdF + ((((ks) * 4 + kg) * 128 + d) << 3));
        a2[mt][ks] = *(const u32x4*)src;
      }
    }
    if (h + 1 < HH) { STAGE_ATT(h + 1, (h + 1) & 1); }
    f32x4 a1[4][2];
    if (h < HH) {
      u32x4 bfr[2][3];
      #pragma unroll
      for (int nt = 0; nt < 2; ++nt)
        #pragma unroll
        for (int ks = 0; ks < 3; ++ks)
          bfr[nt][ks] =
              *(const u32x4*)&attB[pb][nt * 16 + m16][ks * 32 + kg * 8];
      #pragma unroll
      for (int mt = 0; mt < 4; ++mt)
        #pragma unroll
        for (int nt = 0; nt < 2; ++nt) {
          a1[mt][nt] = (f32x4)0.f;
          #pragma unroll
          for (int ks = 0; ks < 3; ++ks)
            a1[mt][nt] = mfma_bf16(af[mt][ks], bfr[nt][ks], a1[mt][nt]);
        }
    }
    if (h < HH) {
      #pragma unroll
      for (int mt = 0; mt < 4; ++mt)
        #pragma unroll
        for (int nt = 0; nt < 2; ++nt) {
          const int v = nt * 16 + m16;
          if (v < VV) {
            const int tv = wid * VV + v;
            const int c0 = mt * 16 + kg * 4;
            u32x2 pk;
            pk[0] = pack2(a1[mt][nt][0], a1[mt][nt][1]);
            pk[1] = pack2(a1[mt][nt][2], a1[mt][nt][3]);
            char* p = xs + tv * 128 + ((c0 * 2) ^ ((tv & 7) << 4));
            *(u32x2*)p = pk;
          }
        }
    } else {
      for (int i = tid; i < 12800; i += 512) {
        const int c = i / 200, j = i % 200;
        const float f = x[((size_t)(n * 64 + c) * TT + t0 + j / 25) * VV + j % 25];
        *(unsigned short*)(xs + j * 128 + ((c * 2) ^ ((j & 7) << 4))) =
            f2bu(f);
      }
    }
    __syncthreads();
    #pragma unroll
    for (int nt = 0; nt < 7; ++nt) {
      const int tv = th * 100 + nt * 16 + m16;
      const u32x4 b0 = *(const u32x4*)(xs + tv * 128 +
                        (((kg * 8) * 2) ^ ((tv & 7) << 4)));
      const u32x4 b1 = *(const u32x4*)(xs + tv * 128 +
                        (((32 + kg * 8) * 2) ^ ((tv & 7) << 4)));
      #pragma unroll
      for (int mt = 0; mt < 2; ++mt) {
        acc2[mt][nt] = mfma_bf16(a2[mt][0], b0, acc2[mt][nt]);
        acc2[mt][nt] = mfma_bf16(a2[mt][1], b1, acc2[mt][nt]);
      }
    }
  }

  #pragma unroll
  for (int mt = 0; mt < 2; ++mt) {
    float cc[4];
    #pragma unroll
    for (int i = 0; i < 4; ++i) {
      const int d = dq * 32 + mt * 16 + kg * 4 + i;
      const float so2 = g_o[d] * rsqrtf(v_o[d] + 1e-5f);
      const float sd2 = g_d[d] * rsqrtf(v_d[d] + 1e-5f);
      cc[i] = b_o[d] * so2 + be_o[d] - m_o[d] * so2
            + b_d[d] * sd2 + be_d[d] - m_d[d] * sd2;
    }
    #pragma unroll
    for (int nt = 0; nt < 7; ++nt) {
      const int tvl = nt * 16 + m16;
      if (tvl < 100) {
        const int tv = th * 100 + tvl;
        const int t = t0 + tv / VV, v = tv % VV;
        #pragma unroll
        for (int i = 0; i < 4; ++i) {
          const int d = dq * 32 + mt * 16 + kg * 4 + i;
          const float z = acc2[mt][nt][i] + cc[i];
          out[((n * DIMD + d) * TT + t) * VV + v] = (z >= 0.f) ? z : 0.1f * z;
        }
      }
    }
  }
  #undef STAGE_XU4
  #undef STAGE_ATT
  #undef XSLB
}

// ---------------------------------------------------------------------------
extern "C" void kernel_launch(void* const* d_in, const int* in_sizes, int n_in,
                              void* d_out, int out_size, void* d_ws, size_t ws_size,
                              hipStream_t stream)
{
  (void)in_sizes; (void)n_in; (void)out_size; (void)ws_size;
  const float* x     = (const float*)d_in[0];
  const float* Wq    = (const float*)d_in[1];
  const float* bq    = (const float*)d_in[2];
  const float* Wk    = (const float*)d_in[3];
  const float* bk    = (const float*)d_in[4];
  const float* We    = (const float*)d_in[5];
  const float* be    = (const float*)d_in[6];
  const float* G     = (const float*)d_in[7];
  const float* sepe  = (const float*)d_in[8];
  const float* att0  = (const float*)d_in[9];
  const float* alpha = (const float*)d_in[10];
  const float* beta  = (const float*)d_in[11];
  const float* Wo    = (const float*)d_in[12];
  const float* b_o   = (const float*)d_in[13];
  const float* g_o   = (const float*)d_in[14];
  const float* be_o  = (const float*)d_in[15];
  const float* m_o   = (const float*)d_in[16];
  const float* v_o   = (const float*)d_in[17];
  const float* Wd    = (const float*)d_in[18];
  const float* b_d   = (const float*)d_in[19];
  const float* g_d   = (const float*)d_in[20];
  const float* be_d  = (const float*)d_in[21];
  const float* m_d   = (const float*)d_in[22];
  const float* v_d   = (const float*)d_in[23];
  const int*   dism  = (const int*)d_in[24];
  const float* disg  = (const float*)d_in[25];

  // Workspace: qy @0 (49.152 MB), kk @49,152,000, attP @98,304,000 (3.41 MB),
  // packed weights @101,711,872: woF 131072B, wdF/wqF/wkF/weF 16384B each.
  char* ws = (char*)d_ws;
  bf16* qy   = (bf16*)(ws);
  bf16* kkp  = (bf16*)(ws + 49152000);
  unsigned short* attP = (unsigned short*)(ws + 98304000);
  unsigned short* woF  = (unsigned short*)(ws + 101711872);
  unsigned short* wdF  = (unsigned short*)(ws + 101842944);
  unsigned short* wqF  = (unsigned short*)(ws + 101859328);
  unsigned short* wkF  = (unsigned short*)(ws + 101875712);
  unsigned short* weF  = (unsigned short*)(ws + 101892096);

  k_pack_w<<<384, 256, 0, stream>>>(Wo, g_o, v_o, Wd, g_d, v_d,
                                    Wq, Wk, We, beta,
                                    woF, wdF, wqF, wkF, weF);
  k_qke_mfma9<<<NB * 30, 256, 0, stream>>>(x, wqF, bq, wkF, bk, weF, be,
                                           G, beta, sepe, dism, qy, kkp);
  k_att_mfma<<<NB * HH, 256, 0, stream>>>(qy, kkp, bq, disg, att0, alpha, attP);
  k_out_mfma7<<<NB * 15, 512, 0, stream>>>(x, attP, woF, wdF,
                                           b_o, g_o, be_o, m_o, v_o,
                                           b_d, g_d, be_d, m_d, v_d,
                                           (float*)d_out);
}

// Round 24
// 319.120 us; speedup vs baseline: 1.5010x; 1.0097x over previous
//
#include <hip/hip_runtime.h>
#include <hip/hip_bf16.h>
#include <math.h>

// Problem constants (fixed by the reference)
#define NB   64     // batch
#define CIN  64     // input channels
#define DIMD 128    // q/k/e channels
#define TT   120    // time
#define VV   25     // joints
#define HH   8      // heads
#define DHD  16     // DIM/H
#define WW   3      // temporal window
#define UU   75     // W*V
#define TC2  12     // t-chunk in MFMA attention kernel (120 = 10*12)
#define TCO8 8      // t-chunk in output kernel v7 (120 = 15*8)

typedef __hip_bfloat16 bf16;
typedef float        f32x4  __attribute__((ext_vector_type(4)));
typedef unsigned int u32x4  __attribute__((ext_vector_type(4)));
typedef unsigned int u32x2  __attribute__((ext_vector_type(2)));
typedef __bf16       bf16x8 __attribute__((ext_vector_type(8)));

__device__ __forceinline__ float b2f(bf16 v)  { return __bfloat162float(v); }
__device__ __forceinline__ bf16  f2b(float v) { return __float2bfloat16(v); }

__device__ __forceinline__ unsigned short f2bu(float f) {
  unsigned u = __builtin_bit_cast(unsigned, f);
  return (unsigned short)((u + 0x7fffu + ((u >> 16) & 1u)) >> 16);  // RNE
}
__device__ __forceinline__ float bfu(unsigned short s) {
  unsigned u = ((unsigned)s) << 16;
  return __builtin_bit_cast(float, u);
}
__device__ __forceinline__ unsigned pack2(float a, float b) {
  return ((unsigned)f2bu(b) << 16) | (unsigned)f2bu(a);
}

// BUILTIN MFMA (R11 lesson: asm-wrapped MFMA is invisible to the GCN hazard
// recognizer -> missing MFMA->VALU wait-states -> silent corruption).
__device__ __forceinline__ f32x4 mfma_bf16(u32x4 a, u32x4 b, f32x4 d) {
  return __builtin_amdgcn_mfma_f32_16x16x32_bf16(
      __builtin_bit_cast(bf16x8, a), __builtin_bit_cast(bf16x8, b), d, 0, 0, 0);
}

#define PRIO_HI() __builtin_amdgcn_s_setprio(1)
#define PRIO_LO() __builtin_amdgcn_s_setprio(0)

// ---------------------------------------------------------------------------
// Pre-pack kernel (R17-verbatim): weights -> fragment-ordered bf16 tensors.
// ---------------------------------------------------------------------------
__global__ __launch_bounds__(256) void k_pack_w(
    const float* __restrict__ Wo, const float* __restrict__ g_o,
    const float* __restrict__ v_o,
    const float* __restrict__ Wd, const float* __restrict__ g_d,
    const float* __restrict__ v_d,
    const float* __restrict__ Wq, const float* __restrict__ Wk,
    const float* __restrict__ We, const float* __restrict__ beta,
    unsigned short* __restrict__ woF, unsigned short* __restrict__ wdF,
    unsigned short* __restrict__ wqF, unsigned short* __restrict__ wkF,
    unsigned short* __restrict__ weF)
{
  const int i = blockIdx.x * 256 + threadIdx.x;   // grid covers 98304
  if (i < 65536) {                                 // woF
    const int j = i & 7, d = (i >> 3) & 127, kg = (i >> 10) & 3;
    const int ks = (i >> 12) & 1, h = (i >> 13) & 7;
    const float sc = g_o[d] * rsqrtf(v_o[d] + 1e-5f);
    woF[i] = f2bu(sc * Wo[d * 512 + h * 64 + ks * 32 + kg * 8 + j]);
  } else {
    const int r = i - 65536;                       // 0..32767
    const int which = r >> 13;                     // 0=wd 1=wq 2=wk 3=we
    const int l = r & 8191;
    const int j = l & 7, d = (l >> 3) & 127, kg = (l >> 10) & 3;
    const int ks = (l >> 12) & 1;
    const int c = ks * 32 + kg * 8 + j;
    if (which == 0) {
      const float sc = g_d[d] * rsqrtf(v_d[d] + 1e-5f);
      wdF[l] = f2bu(sc * Wd[d * 64 + c]);
    } else if (which == 1) {
      wqF[l] = f2bu(Wq[d * 64 + c]);
    } else if (which == 2) {
      wkF[l] = f2bu(Wk[d * 64 + c]);
    } else {
      weF[l] = f2bu(beta[0] * We[d * 64 + c]);
    }
  }
}

// ---------------------------------------------------------------------------
// Fused A+B v9 (R23-verbatim + setprio around MFMA clusters)
// ---------------------------------------------------------------------------
__global__ __launch_bounds__(256, 3) void k_qke_mfma9(
    const float* __restrict__ x,
    const unsigned short* __restrict__ wqF, const float* __restrict__ bq,
    const unsigned short* __restrict__ wkF, const float* __restrict__ bk,
    const unsigned short* __restrict__ weF, const float* __restrict__ be,
    const float* __restrict__ G,  const float* __restrict__ beta,
    const float* __restrict__ se_pe, const int* __restrict__ dis,
    bf16* __restrict__ qy, bf16* __restrict__ kkp)
{
  const int n = blockIdx.x / 30, t0 = (blockIdx.x % 30) * 4;
  __shared__ alignas(16) char uA[16384];                 // xf | yTG
  __shared__ alignas(16) char yCM[16384];                // MhT | yC
  __shared__ alignas(16) unsigned short yT[112][64];     // [tv][c] swz
  __shared__ alignas(16) unsigned short GlT[32][32];     // [v][u] swz (R18)
  __shared__ alignas(16) float spl[5][64];
  __shared__ alignas(16) float gsum[32];
  __shared__ alignas(16) float biasb[384];               // bq|bk|be

  unsigned short* xf  = (unsigned short*)uA;             // [r=c*4+t][32] pad0
  char*           yTG = uA;                              // [112] x 128B swz
  unsigned short* MhT = (unsigned short*)yCM;            // [5][32][32]
  char*           yC  = yCM;                             // [4][64][32] u16 swz

  const int tid = threadIdx.x;
  // ---- phase 0: stage ----
  {
    const float* xb = x + (size_t)n * 192000 + t0 * 25;  // x[n][c][t0+t][v]
    for (int i = tid; i < 8192; i += 256) {              // xf: 256 rows x 32
      const int u = i & 31, r = i >> 5;                  // r = c*4+t
      const int c = r >> 2, t = r & 3;
      xf[i] = (u < VV) ? f2bu(xb[c * 3000 + t * 25 + u]) : 0;
    }
  }
  for (int i = tid; i < 5120; i += 256) {                // MhT[hop][v][u]
    const int hop = i / 1024, r = i % 1024, v = r >> 5, u = r & 31;
    MhT[i] = (u < VV && v < VV && dis[u * 25 + v] == hop) ? 0x3f80 : 0;
  }
  for (int i = tid; i < 320; i += 256) spl[i / 64][i % 64] = se_pe[i];
  for (int i = tid; i < 1024; i += 256) {                // GlT[v][u]=G[u][v], swz
    const int v = i >> 5, u = i & 31;
    const float g = (v < 25 && u < 25) ? G[u * 25 + v] : 0.f;
    *(unsigned short*)((char*)GlT + v * 64 + ((u * 2) ^ ((v & 7) << 4))) =
        f2bu(g);
  }
  if (tid < 25) {
    float s = 0.f;
    for (int u = 0; u < 25; ++u) s += G[u * 25 + tid];
    gsum[tid] = s;
  }
  for (int i = tid; i < 384; i += 256)
    biasb[i] = (i < 128) ? bq[i] : (i < 256 ? bk[i - 128] : be[i - 256]);
  for (int i = tid; i < 12 * 64; i += 256)               // yT junk rows -> 0
    yT[100 + (i >> 6)][i & 63] = 0;
  __syncthreads();

  const int lane = tid & 63, wid = tid >> 6;
  const int m16 = lane & 15, kg = lane >> 4;

  #define LOAD_PFRAGS(af, Fsrc)                                                \
    _Pragma("unroll")                                                          \
    for (int mt = 0; mt < 2; ++mt) {                                           \
      const int d_ = wid * 32 + mt * 16 + m16;                                 \
      _Pragma("unroll")                                                        \
      for (int ks = 0; ks < 2; ++ks)                                           \
        af[mt][ks] = *(const u32x4*)((Fsrc) +                                  \
                      (((ks * 4 + kg) * 128 + d_) << 3));                      \
    }

  // ---- phase 1: indicator-MFMA struct-enc; writes yT + yC ----
  {
    u32x4 bh[2][5];
    #pragma unroll
    for (int ntv = 0; ntv < 2; ++ntv)
      #pragma unroll
      for (int hop = 0; hop < 5; ++hop)
        bh[ntv][hop] = *(const u32x4*)&MhT[hop * 1024 +
                                          (ntv * 16 + m16) * 32 + kg * 8];
    __syncthreads();   // all B-frag preloads done before yC overwrites MhT

    #pragma unroll
    for (int mt4 = 0; mt4 < 4; ++mt4) {
      const int r0 = (wid * 4 + mt4) * 16;
      const u32x4 a = *(const u32x4*)&xf[(r0 + m16) * 32 + kg * 8];
      const int c = (r0 + kg * 4) >> 2;     // constant over i (= (wid*4+mt4)*4+kg)
      float spc[5];
      #pragma unroll
      for (int hop = 0; hop < 5; ++hop) spc[hop] = spl[hop][c];
      const float dv = expf(-(float)(c & ~1) * (logf(10000.0f) / 64.0f));
      #pragma unroll
      for (int ntv = 0; ntv < 2; ++ntv) {
        f32x4 zh[5];
        PRIO_HI();
        #pragma unroll
        for (int hop = 0; hop < 5; ++hop) {
          zh[hop] = (f32x4)0.f;
          zh[hop] = mfma_bf16(a, bh[ntv][hop], zh[hop]);
        }
        PRIO_LO();
        const int v = ntv * 16 + m16;
        if (v < VV) {
          const float pe = (c & 1) ? cosf((float)v * dv) : sinf((float)v * dv);
          #pragma unroll
          for (int i = 0; i < 4; ++i) {      // t = i, row r = r0+kg*4+i
            const int r = r0 + kg * 4 + i;
            float yv = bfu(xf[r * 32 + v]) + pe;
            #pragma unroll
            for (int hop = 0; hop < 5; ++hop)
              yv = fmaf(spc[hop], zh[hop][i], yv);
            const unsigned short yb = f2bu(yv);
            const int tv = i * 25 + v;
            *(unsigned short*)((char*)yT + tv * 128 +
                               ((c * 2) ^ ((tv & 7) << 4))) = yb;
            *(unsigned short*)(yC + (i * 64 + c) * 64 +
                               ((v * 2) ^ ((c & 7) << 4))) = yb;
          }
        } else {                             // v 25..31: zero yC pad cols
          #pragma unroll
          for (int i = 0; i < 4; ++i) {
            const int c2 = c;
            *(unsigned short*)(yC + (i * 64 + c2) * 64 +
                               ((v * 2) ^ ((c2 & 7) << 4))) = 0;
          }
        }
      }
    }
  }
  __syncthreads();   // yT + yC ready; xf DEAD (uA becomes yTG)

  // ---- phase 1b (R18/19-verified MFMA): yTG = y @ G (wave t = wid) ----
  for (int i = tid; i < 12 * 64; i += 256)
    *(unsigned short*)(yTG + (100 + (i >> 6)) * 128 + ((i & 63) * 2)) = 0;
  {
    const int t = wid;
    u32x4 bg[2];
    #pragma unroll
    for (int ntv = 0; ntv < 2; ++ntv) {
      const int v = ntv * 16 + m16;
      bg[ntv] = *(const u32x4*)((const char*)GlT + v * 64 +
                                ((kg * 16) ^ ((v & 7) << 4)));
    }
    #pragma unroll
    for (int mtile = 0; mtile < 4; ++mtile) {
      const int cr = mtile * 16 + m16;
      const u32x4 a = *(const u32x4*)(yC + (t * 64 + cr) * 64 +
                                      ((kg * 16) ^ ((cr & 7) << 4)));
      #pragma unroll
      for (int ntv = 0; ntv < 2; ++ntv) {
        f32x4 d = (f32x4)0.f;
        d = mfma_bf16(a, bg[ntv], d);
        const int v = ntv * 16 + m16;
        if (v < 25) {
          const int tv = t * 25 + v;
          #pragma unroll
          for (int i = 0; i < 4; ++i) {
            const int cc = mtile * 16 + kg * 4 + i;
            *(unsigned short*)(yTG + tv * 128 + ((cc * 2) ^ ((tv & 7) << 4))) =
                f2bu(d[i]);
          }
        }
      }
    }
  }
  __syncthreads();   // yTG ready — GEMMs are straight-line

  bf16* qyb = qy  + (size_t)n * 384000 + t0 * 25;
  bf16* kkb = kkp + (size_t)n * 384000 + t0 * 25;
  const float betav = beta[0];

  // ---- q-GEMM ----
  {
    u32x4 aq[2][2];
    LOAD_PFRAGS(aq, wqF);
    for (int nt = 0; nt < 7; ++nt) {
      const int tv = nt * 16 + m16;
      const u32x4 b0 = *(const u32x4*)((const char*)yT + tv * 128 +
                        (((kg * 8) * 2) ^ ((tv & 7) << 4)));
      const u32x4 b1 = *(const u32x4*)((const char*)yT + tv * 128 +
                        (((32 + kg * 8) * 2) ^ ((tv & 7) << 4)));
      PRIO_HI();
      f32x4 acc0 = (f32x4)0.f, acc1 = (f32x4)0.f;
      acc0 = mfma_bf16(aq[0][0], b0, acc0);
      acc0 = mfma_bf16(aq[0][1], b1, acc0);
      acc1 = mfma_bf16(aq[1][0], b0, acc1);
      acc1 = mfma_bf16(aq[1][1], b1, acc1);
      PRIO_LO();
      if (tv < 100) {
        #pragma unroll
        for (int mt = 0; mt < 2; ++mt) {
          const f32x4 acc = mt ? acc1 : acc0;
          const int dr = wid * 32 + mt * 16 + kg * 4;
          #pragma unroll
          for (int i2 = 0; i2 < 4; ++i2)
            qyb[(size_t)(dr + i2) * 3000 + tv] = f2b(acc[i2] + biasb[dr + i2]);
        }
      }
    }
  }

  // ---- k-GEMM into persistent kacc ----
  f32x4 kacc[2][7];
  #pragma unroll
  for (int mt = 0; mt < 2; ++mt)
    #pragma unroll
    for (int nt = 0; nt < 7; ++nt) kacc[mt][nt] = (f32x4)0.f;
  {
    u32x4 ak[2][2];
    LOAD_PFRAGS(ak, wkF);
    for (int nt = 0; nt < 7; ++nt) {
      const int tv = nt * 16 + m16;
      const u32x4 b0 = *(const u32x4*)((const char*)yT + tv * 128 +
                        (((kg * 8) * 2) ^ ((tv & 7) << 4)));
      const u32x4 b1 = *(const u32x4*)((const char*)yT + tv * 128 +
                        (((32 + kg * 8) * 2) ^ ((tv & 7) << 4)));
      PRIO_HI();
      #pragma unroll
      for (int mt = 0; mt < 2; ++mt) {
        kacc[mt][nt] = mfma_bf16(ak[mt][0], b0, kacc[mt][nt]);
        kacc[mt][nt] = mfma_bf16(ak[mt][1], b1, kacc[mt][nt]);
      }
      PRIO_LO();
    }
  }

  // ---- e-GEMM (beta pre-folded in weF) on yTG, accumulate, store kk ----
  {
    u32x4 ae[2][2];
    LOAD_PFRAGS(ae, weF);
    for (int nt = 0; nt < 7; ++nt) {
      const int tv = nt * 16 + m16;
      const u32x4 b0 = *(const u32x4*)(yTG + tv * 128 +
                        (((kg * 8) * 2) ^ ((tv & 7) << 4)));
      const u32x4 b1 = *(const u32x4*)(yTG + tv * 128 +
                        (((32 + kg * 8) * 2) ^ ((tv & 7) << 4)));
      PRIO_HI();
      #pragma unroll
      for (int mt = 0; mt < 2; ++mt) {
        kacc[mt][nt] = mfma_bf16(ae[mt][0], b0, kacc[mt][nt]);
        kacc[mt][nt] = mfma_bf16(ae[mt][1], b1, kacc[mt][nt]);
      }
      PRIO_LO();
      if (tv < 100) {
        const int vv = tv % 25;
        #pragma unroll
        for (int mt = 0; mt < 2; ++mt) {
          const int dr = wid * 32 + mt * 16 + kg * 4;
          #pragma unroll
          for (int i2 = 0; i2 < 4; ++i2)
            kkb[(size_t)(dr + i2) * 3000 + tv] =
                f2b(kacc[mt][nt][i2] + biasb[128 + dr + i2] +
                    betav * biasb[256 + dr + i2] * gsum[vv]);
        }
      }
    }
  }
  #undef LOAD_PFRAGS
}

// ---------------------------------------------------------------------------
// Kernel C v2 (R16-verbatim + setprio): MFMA attention -> padded attP
// ---------------------------------------------------------------------------
__global__ __launch_bounds__(256) void k_att_mfma(
    const bf16* __restrict__ qy, const bf16* __restrict__ kkp,
    const float* __restrict__ bq, const float* __restrict__ disg,
    const float* __restrict__ att0, const float* __restrict__ alpha,
    unsigned short* __restrict__ attP)
{
  const int n = blockIdx.x / HH, h = blockIdx.x % HH;
  __shared__ alignas(16) unsigned short qsA[80][200];  // [u][k] bf16 bits
  __shared__ alignas(16) unsigned short ksB[32][200];  // [v][k] bf16 bits
  __shared__ alignas(16) float att_s[80][28];
  __shared__ float mxv[32], smv[32];
  const int tid = threadIdx.x;
  const int lane = tid & 63, wid = tid >> 6;
  const int m16 = lane & 15, kg = lane >> 4;

  const unsigned short* qyb =
      (const unsigned short*)(qy + ((size_t)(n * DIMD + h * DHD)) * TT * VV);
  const unsigned short* kkb =
      (const unsigned short*)(kkp + ((size_t)(n * DIMD + h * DHD)) * TT * VV);

  f32x4 acc[3];
  #pragma unroll
  for (int s = 0; s < 3; ++s) acc[s] = (f32x4)0.f;

  for (int c = 0; c < 10; ++c) {
    const int t0 = c * TC2;
    __syncthreads();   // prev chunk's frag reads drained
    for (int it = tid; it < 416; it += 256) {
      if (it < 224) {
        const int dh = it / 14, j = it % 14, tq = t0 + j - 1;
        unsigned short vals[25];
        if (tq >= 0 && tq < TT) {
          const unsigned short* src = qyb + ((size_t)dh * TT + tq) * VV;
          #pragma unroll
          for (int u = 0; u < 25; ++u) vals[u] = src[u];
        } else {
          const unsigned short bqv = f2bu(bq[h * DHD + dh]);
          #pragma unroll
          for (int u = 0; u < 25; ++u) vals[u] = bqv;
        }
        #pragma unroll
        for (int w = 0; w < 3; ++w) {
          const int tt = tq - t0 - w + 1;
          if (tt >= 0 && tt < TC2) {
            const int col = tt * 16 + dh;
            #pragma unroll
            for (int u = 0; u < 25; ++u) qsA[w * 25 + u][col] = vals[u];
          }
        }
      } else {
        const int r = it - 224, dh = r / TC2, tt = r % TC2;
        const unsigned short* src = kkb + ((size_t)dh * TT + t0 + tt) * VV;
        const int col = tt * 16 + dh;
        #pragma unroll
        for (int v = 0; v < 25; ++v) ksB[v][col] = src[v];
      }
    }
    __syncthreads();   // tiles ready
    PRIO_HI();
    #pragma unroll
    for (int s = 0; s < 3; ++s) {
      const int tidx = wid + 4 * s;
      if (tidx < 10) {
        const int mtile = tidx >> 1, ntile = tidx & 1;
        #pragma unroll
        for (int ks = 0; ks < 6; ++ks) {
          const u32x4 a = *(const u32x4*)&qsA[mtile * 16 + m16][ks * 32 + kg * 8];
          const u32x4 b = *(const u32x4*)&ksB[ntile * 16 + m16][ks * 32 + kg * 8];
          acc[s] = mfma_bf16(a, b, acc[s]);
        }
      }
    }
    PRIO_LO();
  }
  __syncthreads();
  #pragma unroll
  for (int s = 0; s < 3; ++s) {
    const int tidx = wid + 4 * s;
    if (tidx < 10) {
      const int mtile = tidx >> 1, ntile = tidx & 1;
      const int v = ntile * 16 + m16;
      if (v < VV) {
        #pragma unroll
        for (int i = 0; i < 4; ++i)
          att_s[mtile * 16 + kg * 4 + i][v] = acc[s][i];
      }
    }
  }
  __syncthreads();
  const float inv = 1.0f / (float)(DHD * TT);
  for (int i = tid; i < UU * VV; i += 256) {
    const int u = i / VV, v = i % VV;
    const bool m = disg[(h * VV + u % VV) * VV + v] > 0.f;
    att_s[u][v] = m ? att_s[u][v] * inv : -9e15f;
  }
  __syncthreads();
  if (tid < VV) {
    float mx = -INFINITY;
    for (int u = 0; u < UU; ++u) mx = fmaxf(mx, att_s[u][tid]);
    float sm = 0.f;
    for (int u = 0; u < UU; ++u) sm += expf(att_s[u][tid] - mx);
    mxv[tid] = mx; smv[tid] = sm;
  }
  __syncthreads();
  const float al = alpha[0];
  unsigned* dst = (unsigned*)(attP + ((size_t)(n * HH + h) * 32) * 104);
  for (int i = tid; i < 1664; i += 256) {     // 32 x 52 u32 (= 104 u16)
    const int vc = i / 52, u0 = (i % 52) * 2;
    unsigned val = 0u;
    if (vc < VV) {
      float f0 = 0.f, f1 = 0.f;
      if (u0 < UU)
        f0 = expf(att_s[u0][vc] - mxv[vc]) / smv[vc] * al
             + att0[(h * VV + u0 % VV) * VV + vc];
      if (u0 + 1 < UU)
        f1 = expf(att_s[u0 + 1][vc] - mxv[vc]) / smv[vc] * al
             + att0[(h * VV + (u0 + 1) % VV) * VV + vc];
      val = pack2(f0, f1);
    }
    dst[i] = val;
  }
}

// ---------------------------------------------------------------------------
// Kernel D v7 (R22-verbatim + setprio): 8-t blocks, 512 threads.
// ---------------------------------------------------------------------------
__global__ __launch_bounds__(512) void k_out_mfma7(
    const float* __restrict__ x, const unsigned short* __restrict__ attP,
    const unsigned short* __restrict__ woF, const unsigned short* __restrict__ wdF,
    const float* __restrict__ b_o,
    const float* __restrict__ g_o, const float* __restrict__ be_o,
    const float* __restrict__ m_o, const float* __restrict__ v_o,
    const float* __restrict__ b_d,
    const float* __restrict__ g_d, const float* __restrict__ be_d,
    const float* __restrict__ m_d, const float* __restrict__ v_d,
    float* __restrict__ out)
{
  const int n = blockIdx.x / 15, t0 = (blockIdx.x % 15) * TCO8;
  __shared__ alignas(16) char uB[54272];                   // xu4 | xsl2[2](212r)
  __shared__ alignas(16) unsigned short attB[2][32][104];  // 13,312 B dbuf
  unsigned short* xu4 = (unsigned short*)uB;               // [(tr*64+c)*104+u], tr<4
  const int tid = threadIdx.x;
  const int lane = tid & 63, wid = tid >> 6;               // wid 0..7
  const int m16 = lane & 15, kg = lane >> 4;

  #define XSLB(b) (uB + (b) * 27136)            // [212] rows x 128B swz

  #define STAGE_XU4(tb)                                                        \
    for (int i = tid; i < 4 * 64 * 48; i += 512) {                             \
      const int u0 = (i % 48) * 2, c = (i / 48) & 63, tr = i / (48 * 64);      \
      float f0 = 0.f, f1 = 0.f;                                                \
      if (u0 < UU) {                                                           \
        const int w = u0 / VV, up = u0 % VV, ts = t0 + (tb) + tr + w - 1;      \
        if (ts >= 0 && ts < TT) f0 = x[((n * 64 + c) * TT + ts) * VV + up];    \
      }                                                                        \
      if (u0 + 1 < UU) {                                                       \
        const int u = u0 + 1, w = u / VV, up = u % VV;                         \
        const int ts = t0 + (tb) + tr + w - 1;                                 \
        if (ts >= 0 && ts < TT) f1 = x[((n * 64 + c) * TT + ts) * VV + up];    \
      }                                                                        \
      *(unsigned*)(xu4 + (tr * 64 + c) * 104 + u0) = pack2(f0, f1);            \
    }

  #define STAGE_ATT(hh, buf)                                                   \
    {                                                                          \
      const u32x4* srcv =                                                      \
          (const u32x4*)(attP + ((size_t)(n * HH + (hh)) * 32) * 104);         \
      u32x4* dstv = (u32x4*)&attB[buf][0][0];                                  \
      for (int i = tid; i < 416; i += 512) dstv[i] = srcv[i];                  \
    }

  STAGE_XU4(0);
  __syncthreads();
  u32x4 af[4][3];
  if (wid < 4) {
    #pragma unroll
    for (int mt = 0; mt < 4; ++mt)
      #pragma unroll
      for (int ks = 0; ks < 3; ++ks)
        af[mt][ks] = *(const u32x4*)(xu4 + (wid * 64 + mt * 16 + m16) * 104 +
                                     ks * 32 + kg * 8);
  }
  __syncthreads();
  STAGE_XU4(4);
  STAGE_ATT(0, 0);
  __syncthreads();
  if (wid >= 4) {
    #pragma unroll
    for (int mt = 0; mt < 4; ++mt)
      #pragma unroll
      for (int ks = 0; ks < 3; ++ks)
        af[mt][ks] = *(const u32x4*)(xu4 + ((wid - 4) * 64 + mt * 16 + m16) * 104 +
                                     ks * 32 + kg * 8);
  }
  __syncthreads();
  for (int i = tid; i < 2 * 12 * 64; i += 512) {
    const int b = i / (12 * 64), r = i % (12 * 64);
    *(unsigned short*)(XSLB(b) + (200 + (r >> 6)) * 128 + ((r & 63) * 2)) = 0;
  }

  const int th = wid >> 2, dq = wid & 3;

  f32x4 acc2[2][7];
  #pragma unroll
  for (int mt = 0; mt < 2; ++mt)
    #pragma unroll
    for (int nt = 0; nt < 7; ++nt) acc2[mt][nt] = (f32x4)0.f;

  for (int h = 0; h <= HH; ++h) {
    const int pb = h & 1;
    char* xs = XSLB(pb);
    u32x4 a2[2][2];
    #pragma unroll
    for (int mt = 0; mt < 2; ++mt) {
      const int d = dq * 32 + mt * 16 + m16;
      #pragma unroll
      for (int ks = 0; ks < 2; ++ks) {
        const unsigned short* src = (h < HH)
            ? (woF + ((((h * 2 + ks) * 4 + kg) * 128 + d) << 3))
            : (wdF + ((((ks) * 4 + kg) * 128 + d) << 3));
        a2[mt][ks] = *(const u32x4*)src;
      }
    }
    if (h + 1 < HH) { STAGE_ATT(h + 1, (h + 1) & 1); }
    f32x4 a1[4][2];
    if (h < HH) {
      u32x4 bfr[2][3];
      #pragma unroll
      for (int nt = 0; nt < 2; ++nt)
        #pragma unroll
        for (int ks = 0; ks < 3; ++ks)
          bfr[nt][ks] =
              *(const u32x4*)&attB[pb][nt * 16 + m16][ks * 32 + kg * 8];
      PRIO_HI();
      #pragma unroll
      for (int mt = 0; mt < 4; ++mt)
        #pragma unroll
        for (int nt = 0; nt < 2; ++nt) {
          a1[mt][nt] = (f32x4)0.f;
          #pragma unroll
          for (int ks = 0; ks < 3; ++ks)
            a1[mt][nt] = mfma_bf16(af[mt][ks], bfr[nt][ks], a1[mt][nt]);
        }
      PRIO_LO();
    }
    if (h < HH) {
      #pragma unroll
      for (int mt = 0; mt < 4; ++mt)
        #pragma unroll
        for (int nt = 0; nt < 2; ++nt) {
          const int v = nt * 16 + m16;
          if (v < VV) {
            const int tv = wid * VV + v;
            const int c0 = mt * 16 + kg * 4;
            u32x2 pk;
            pk[0] = pack2(a1[mt][nt][0], a1[mt][nt][1]);
            pk[1] = pack2(a1[mt][nt][2], a1[mt][nt][3]);
            char* p = xs + tv * 128 + ((c0 * 2) ^ ((tv & 7) << 4));
            *(u32x2*)p = pk;
          }
        }
    } else {
      for (int i = tid; i < 12800; i += 512) {
        const int c = i / 200, j = i % 200;
        const float f = x[((size_t)(n * 64 + c) * TT + t0 + j / 25) * VV + j % 25];
        *(unsigned short*)(xs + j * 128 + ((c * 2) ^ ((j & 7) << 4))) =
            f2bu(f);
      }
    }
    __syncthreads();
    PRIO_HI();
    #pragma unroll
    for (int nt = 0; nt < 7; ++nt) {
      const int tv = th * 100 + nt * 16 + m16;
      const u32x4 b0 = *(const u32x4*)(xs + tv * 128 +
                        (((kg * 8) * 2) ^ ((tv & 7) << 4)));
      const u32x4 b1 = *(const u32x4*)(xs + tv * 128 +
                        (((32 + kg * 8) * 2) ^ ((tv & 7) << 4)));
      #pragma unroll
      for (int mt = 0; mt < 2; ++mt) {
        acc2[mt][nt] = mfma_bf16(a2[mt][0], b0, acc2[mt][nt]);
        acc2[mt][nt] = mfma_bf16(a2[mt][1], b1, acc2[mt][nt]);
      }
    }
    PRIO_LO();
  }

  #pragma unroll
  for (int mt = 0; mt < 2; ++mt) {
    float cc[4];
    #pragma unroll
    for (int i = 0; i < 4; ++i) {
      const int d = dq * 32 + mt * 16 + kg * 4 + i;
      const float so2 = g_o[d] * rsqrtf(v_o[d] + 1e-5f);
      const float sd2 = g_d[d] * rsqrtf(v_d[d] + 1e-5f);
      cc[i] = b_o[d] * so2 + be_o[d] - m_o[d] * so2
            + b_d[d] * sd2 + be_d[d] - m_d[d] * sd2;
    }
    #pragma unroll
    for (int nt = 0; nt < 7; ++nt) {
      const int tvl = nt * 16 + m16;
      if (tvl < 100) {
        const int tv = th * 100 + tvl;
        const int t = t0 + tv / VV, v = tv % VV;
        #pragma unroll
        for (int i = 0; i < 4; ++i) {
          const int d = dq * 32 + mt * 16 + kg * 4 + i;
          const float z = acc2[mt][nt][i] + cc[i];
          out[((n * DIMD + d) * TT + t) * VV + v] = (z >= 0.f) ? z : 0.1f * z;
        }
      }
    }
  }
  #undef STAGE_XU4
  #undef STAGE_ATT
  #undef XSLB
}

// ---------------------------------------------------------------------------
extern "C" void kernel_launch(void* const* d_in, const int* in_sizes, int n_in,
                              void* d_out, int out_size, void* d_ws, size_t ws_size,
                              hipStream_t stream)
{
  (void)in_sizes; (void)n_in; (void)out_size; (void)ws_size;
  const float* x     = (const float*)d_in[0];
  const float* Wq    = (const float*)d_in[1];
  const float* bq    = (const float*)d_in[2];
  const float* Wk    = (const float*)d_in[3];
  const float* bk    = (const float*)d_in[4];
  const float* We    = (const float*)d_in[5];
  const float* be    = (const float*)d_in[6];
  const float* G     = (const float*)d_in[7];
  const float* sepe  = (const float*)d_in[8];
  const float* att0  = (const float*)d_in[9];
  const float* alpha = (const float*)d_in[10];
  const float* beta  = (const float*)d_in[11];
  const float* Wo    = (const float*)d_in[12];
  const float* b_o   = (const float*)d_in[13];
  const float* g_o   = (const float*)d_in[14];
  const float* be_o  = (const float*)d_in[15];
  const float* m_o   = (const float*)d_in[16];
  const float* v_o   = (const float*)d_in[17];
  const float* Wd    = (const float*)d_in[18];
  const float* b_d   = (const float*)d_in[19];
  const float* g_d   = (const float*)d_in[20];
  const float* be_d  = (const float*)d_in[21];
  const float* m_d   = (const float*)d_in[22];
  const float* v_d   = (const float*)d_in[23];
  const int*   dism  = (const int*)d_in[24];
  const float* disg  = (const float*)d_in[25];

  // Workspace: qy @0 (49.152 MB), kk @49,152,000, attP @98,304,000 (3.41 MB),
  // packed weights @101,711,872: woF 131072B, wdF/wqF/wkF/weF 16384B each.
  char* ws = (char*)d_ws;
  bf16* qy   = (bf16*)(ws);
  bf16* kkp  = (bf16*)(ws + 49152000);
  unsigned short* attP = (unsigned short*)(ws + 98304000);
  unsigned short* woF  = (unsigned short*)(ws + 101711872);
  unsigned short* wdF  = (unsigned short*)(ws + 101842944);
  unsigned short* wqF  = (unsigned short*)(ws + 101859328);
  unsigned short* wkF  = (unsigned short*)(ws + 101875712);
  unsigned short* weF  = (unsigned short*)(ws + 101892096);

  k_pack_w<<<384, 256, 0, stream>>>(Wo, g_o, v_o, Wd, g_d, v_d,
                                    Wq, Wk, We, beta,
                                    woF, wdF, wqF, wkF, weF);
  k_qke_mfma9<<<NB * 30, 256, 0, stream>>>(x, wqF, bq, wkF, bk, weF, be,
                                           G, beta, sepe, dism, qy, kkp);
  k_att_mfma<<<NB * HH, 256, 0, stream>>>(qy, kkp, bq, disg, att0, alpha, attP);
  k_out_mfma7<<<NB * 15, 512, 0, stream>>>(x, attP, woF, wdF,
                                           b_o, g_o, be_o, m_o, v_o,
                                           b_d, g_d, be_d, m_d, v_d,
                                           (float*)d_out);
}